// Round 2
// baseline (3554.447 us; speedup 1.0000x reference)
//
#include <hip/hip_runtime.h>
#include <math.h>

#define EPSBN 1e-5f

// ---------------------------------------------------------------------------
// Generic tiled GEMM: C[b] (MxN) = A[b] (MxK) * B[b] (KxN)  [+bias per-row]
// A indexing generalized: elem(m,k) = A[b*sA + aOff + m*aRow + k*aCol]
// SHIFT mode: B column n maps to spatial (y,x) in IWxIH with shift (dy,dx),
// zero outside -> used for 3x3 SAME conv as 9 accumulated shifted GEMMs.
// ---------------------------------------------------------------------------
template<bool SHIFT, bool ACC>
__global__ __launch_bounds__(256)
void gemm_k(const float* __restrict__ A, const float* __restrict__ B,
            float* __restrict__ C, const float* __restrict__ bias,
            int M, int K, int N,
            long sA, long aRow, int aCol, long aOff,
            long sB, long sC,
            int IW, int IH, int dy, int dx)
{
    const int b = blockIdx.z;
    const float* Ab = A + (long)b * sA + aOff;
    const float* Bb = B + (long)b * sB;
    float* Cb = C + (long)b * sC;
    const int m0 = blockIdx.y * 64, n0 = blockIdx.x * 64;
    __shared__ float As[16][65];
    __shared__ float Bs[16][64];
    const int tid = threadIdx.x;
    const int tx = tid & 15, ty = tid >> 4;
    float acc[4][4] = {};
    for (int k0 = 0; k0 < K; k0 += 16) {
#pragma unroll
        for (int i = 0; i < 4; i++) {
            int idx = tid + i * 256;
            int kk = idx & 15, mm = idx >> 4;
            float v = 0.f;
            int mg = m0 + mm, kg = k0 + kk;
            if (mg < M) v = Ab[(long)mg * aRow + (long)kg * aCol];
            As[kk][mm] = v;
        }
#pragma unroll
        for (int i = 0; i < 4; i++) {
            int idx = tid + i * 256;
            int nn = idx & 63, kk = idx >> 6;
            float v = 0.f;
            int kg = k0 + kk, ng = n0 + nn;
            if (ng < N) {
                if (SHIFT) {
                    int yy = ng / IW + dy, xx = ng % IW + dx;
                    if (yy >= 0 && yy < IH && xx >= 0 && xx < IW)
                        v = Bb[(long)kg * N + yy * IW + xx];
                } else {
                    v = Bb[(long)kg * N + ng];
                }
            }
            Bs[kk][nn] = v;
        }
        __syncthreads();
#pragma unroll
        for (int kk = 0; kk < 16; kk++) {
            float a[4], bb[4];
#pragma unroll
            for (int i = 0; i < 4; i++) a[i] = As[kk][ty + i * 16];
#pragma unroll
            for (int j = 0; j < 4; j++) bb[j] = Bs[kk][tx + j * 16];
#pragma unroll
            for (int i = 0; i < 4; i++)
#pragma unroll
                for (int j = 0; j < 4; j++)
                    acc[i][j] = fmaf(a[i], bb[j], acc[i][j]);
        }
        __syncthreads();
    }
#pragma unroll
    for (int i = 0; i < 4; i++) {
        int m = m0 + ty + i * 16;
        if (m >= M) continue;
        float bs = bias ? bias[m] : 0.f;
#pragma unroll
        for (int j = 0; j < 4; j++) {
            int n = n0 + tx + j * 16;
            if (n >= N) continue;
            float v = acc[i][j] + bs;
            long o = (long)m * N + n;
            if (ACC) Cb[o] += v; else Cb[o] = v;
        }
    }
}

// Per-channel batch-norm statistics over (n, spatial): mv[2c]=mean, mv[2c+1]=var
__global__ __launch_bounds__(256)
void bn_stats_k(const float* __restrict__ x, float* __restrict__ mv,
                int HW, int Nb, long strideN)
{
    int c = blockIdx.x;
    long total = (long)Nb * HW;
    float s = 0.f, s2 = 0.f;
    for (long i = threadIdx.x; i < total; i += 256) {
        int n = (int)(i / HW); int l = (int)(i % HW);
        float v = x[(long)n * strideN + (long)c * HW + l];
        s += v; s2 += v * v;
    }
    __shared__ float sh0[256], sh1[256];
    sh0[threadIdx.x] = s; sh1[threadIdx.x] = s2;
    __syncthreads();
    for (int o = 128; o > 0; o >>= 1) {
        if (threadIdx.x < o) { sh0[threadIdx.x] += sh0[threadIdx.x + o]; sh1[threadIdx.x] += sh1[threadIdx.x + o]; }
        __syncthreads();
    }
    if (threadIdx.x == 0) {
        float inv = 1.f / (float)total;
        float m = sh0[0] * inv;
        mv[2 * c] = m;
        mv[2 * c + 1] = sh1[0] * inv - m * m;
    }
}

__global__ __launch_bounds__(256)
void bn_apply_k(const float* __restrict__ x, float* __restrict__ y,
                const float* __restrict__ mv, const float* __restrict__ g,
                const float* __restrict__ bta, int C, int HW, long total, int dorelu)
{
    for (long i = blockIdx.x * 256L + threadIdx.x; i < total; i += (long)gridDim.x * 256) {
        int c = (int)((i / HW) % C);
        float m = mv[2 * c], v = mv[2 * c + 1];
        float r = (x[i] - m) * rsqrtf(v + EPSBN) * g[c] + bta[c];
        if (dorelu) r = fmaxf(r, 0.f);
        y[i] = r;
    }
}

// bilinear upsample, align_corners=True
__global__ __launch_bounds__(256)
void upsample_k(const float* __restrict__ in, float* __restrict__ out,
                int C, int H, int W, int OH, int OW, int Nb)
{
    long total = (long)Nb * C * OH * OW;
    float ry = (float)(H - 1) / (float)(OH - 1);
    float rx = (float)(W - 1) / (float)(OW - 1);
    for (long i = blockIdx.x * 256L + threadIdx.x; i < total; i += (long)gridDim.x * 256) {
        int ox = (int)(i % OW); long t = i / OW;
        int oy = (int)(t % OH); t /= OH;                 // t = n*C + c
        float fy = oy * ry, fx = ox * rx;
        int y0 = (int)fy, x0 = (int)fx;
        int y1 = min(y0 + 1, H - 1), x1 = min(x0 + 1, W - 1);
        float wy = fy - y0, wx = fx - x0;
        const float* p = in + t * (long)H * W;
        float v00 = p[y0 * W + x0], v01 = p[y0 * W + x1];
        float v10 = p[y1 * W + x0], v11 = p[y1 * W + x1];
        out[i] = (v00 * (1.f - wx) + v01 * wx) * (1.f - wy) +
                 (v10 * (1.f - wx) + v11 * wx) * wy;
    }
}

// energy (q . unfold(k)) over 9 dilated-2 neighbors + softmax -> att (n,l,9)
__global__ __launch_bounds__(256)
void att_k(const float* __restrict__ q, const float* __restrict__ k,
           float* __restrict__ att, int C, int H, int W)
{
    int HW = H * W;
    int l = blockIdx.x * 256 + threadIdx.x;
    int n = blockIdx.y;
    if (l >= HW) return;
    int y = l / W, x = l % W;
    int offs[9]; bool val[9];
#pragma unroll
    for (int a = 0; a < 3; a++)
#pragma unroll
        for (int bj = 0; bj < 3; bj++) {
            int id = a * 3 + bj;
            int yy = y + 2 * a - 2, xx = x + 2 * bj - 2;
            val[id] = (yy >= 0 && yy < H && xx >= 0 && xx < W);
            offs[id] = val[id] ? yy * W + xx : 0;
        }
    float e[9] = {0.f,0.f,0.f,0.f,0.f,0.f,0.f,0.f,0.f};
    const float* qb = q + (long)n * C * HW;
    const float* kb = k + (long)n * C * HW;
    for (int c = 0; c < C; c++) {
        float qv = qb[(long)c * HW + l];
        const float* kp = kb + (long)c * HW;
#pragma unroll
        for (int t = 0; t < 9; t++) if (val[t]) e[t] += qv * kp[offs[t]];
    }
    float mx = e[0];
#pragma unroll
    for (int t = 1; t < 9; t++) mx = fmaxf(mx, e[t]);
    float s = 0.f; float ex[9];
#pragma unroll
    for (int t = 0; t < 9; t++) { ex[t] = expf(e[t] - mx); s += ex[t]; }
    float inv = 1.f / s;
    long base = ((long)n * HW + l) * 9;
#pragma unroll
    for (int t = 0; t < 9; t++) att[base + t] = ex[t] * inv;
}

// out[n,c,l] = sum_t att[n,l,t] * v[n,c,neighbor_t(l)]   (zero outside)
__global__ __launch_bounds__(256)
void attout_k(const float* __restrict__ att, const float* __restrict__ v,
              float* __restrict__ out, int C, int H, int W, int CC)
{
    int HW = H * W;
    int l = blockIdx.x * 256 + threadIdx.x;
    int n = blockIdx.z;
    if (l >= HW) return;
    int y = l / W, x = l % W;
    int offs[9]; float a[9];
    long abase = ((long)n * HW + l) * 9;
#pragma unroll
    for (int t = 0; t < 9; t++) {
        int aa = t / 3, bj = t % 3;
        int yy = y + 2 * aa - 2, xx = x + 2 * bj - 2;
        bool ok = (yy >= 0 && yy < H && xx >= 0 && xx < W);
        offs[t] = ok ? yy * W + xx : 0;
        a[t] = ok ? att[abase + t] : 0.f;
    }
    int c0 = blockIdx.y * CC;
    for (int c = c0; c < c0 + CC; c++) {
        const float* vp = v + ((long)n * C + c) * HW;
        float s = 0.f;
#pragma unroll
        for (int t = 0; t < 9; t++) s += a[t] * vp[offs[t]];
        out[((long)n * C + c) * HW + l] = s;
    }
}

// codeword squared norms
__global__ void cc_k(const float* __restrict__ cw, float* __restrict__ cc, int D)
{
    int k = threadIdx.x;
    if (k < 32) {
        float s = 0.f;
        for (int d = 0; d < D; d++) { float v = cw[(long)k * D + d]; s += v * v; }
        cc[k] = s;
    }
}

// soft-assign A[b,l,k] = softmax_k(-scale_k*(||x_l||^2 + ||c_k||^2 - 2 x_l.c_k))
__global__ __launch_bounds__(256)
void assign_k(const float* __restrict__ x, const float* __restrict__ xc,
              const float* __restrict__ cc, const float* __restrict__ scale,
              float* __restrict__ A, int D, int HW)
{
    int l = blockIdx.x * 256 + threadIdx.x;
    int b = blockIdx.y;
    if (l >= HW) return;
    const float* xb = x + (long)b * D * HW;
    float xx = 0.f;
    for (int d = 0; d < D; d++) { float v = xb[(long)d * HW + l]; xx += v * v; }
    float e[32]; float mx = -1e30f;
#pragma unroll
    for (int k2 = 0; k2 < 32; k2++) {
        float dist = xx + cc[k2] - 2.f * xc[((long)b * 32 + k2) * HW + l];
        float en = -scale[k2] * dist;
        e[k2] = en; mx = fmaxf(mx, en);
    }
    float s = 0.f;
#pragma unroll
    for (int k2 = 0; k2 < 32; k2++) { e[k2] = expf(e[k2] - mx); s += e[k2]; }
    float inv = 1.f / s;
    long base = ((long)b * HW + l) * 32;
#pragma unroll
    for (int k2 = 0; k2 < 32; k2++) A[base + k2] = e[k2] * inv;
}

__global__ __launch_bounds__(256)
void asum_k(const float* __restrict__ A, float* __restrict__ Asum, int HW)
{
    int k2 = blockIdx.x, b = blockIdx.y;
    float s = 0.f;
    for (int l = threadIdx.x; l < HW; l += 256) s += A[((long)b * HW + l) * 32 + k2];
    __shared__ float sh[256];
    sh[threadIdx.x] = s;
    __syncthreads();
    for (int o = 128; o > 0; o >>= 1) {
        if (threadIdx.x < o) sh[threadIdx.x] += sh[threadIdx.x + o];
        __syncthreads();
    }
    if (threadIdx.x == 0) Asum[b * 32 + k2] = sh[0];
}

// E[b,k,d] = Et[b,d,k] - Asum[b,k]*cw[k,d]
__global__ __launch_bounds__(256)
void efix_k(const float* __restrict__ Et, const float* __restrict__ Asum,
            const float* __restrict__ cw, float* __restrict__ E, int D)
{
    long i = blockIdx.x * 256L + threadIdx.x;
    long total = 2L * 32 * D;
    if (i >= total) return;
    int d = (int)(i % D); long t = i / D;
    int k2 = (int)(t % 32); int b = (int)(t / 32);
    E[i] = Et[((long)b * D + d) * 32 + k2] - Asum[b * 32 + k2] * cw[(long)k2 * D + d];
}

// en[b,d] = mean_k relu(BN1d(E[b,k,d]))
__global__ __launch_bounds__(256)
void en_k(const float* __restrict__ E, const float* __restrict__ mv,
          const float* __restrict__ gK, const float* __restrict__ bK,
          float* __restrict__ en, int D)
{
    int i = blockIdx.x * 256 + threadIdx.x;
    if (i >= 2 * D) return;
    int b = i / D, d = i % D;
    float s = 0.f;
#pragma unroll
    for (int k2 = 0; k2 < 32; k2++) {
        float m = mv[2 * k2], vv = mv[2 * k2 + 1];
        float r = (E[((long)b * 32 + k2) * D + d] - m) * rsqrtf(vv + EPSBN) * gK[k2] + bK[k2];
        s += fmaxf(r, 0.f);
    }
    en[i] = s * (1.f / 32.f);
}

// small FC: out[b,o] = act(W[o,:].in[b,:] + bias[o]); mode 1 = sigmoid
__global__ __launch_bounds__(256)
void fc_k(const float* __restrict__ W, const float* __restrict__ bias,
          const float* __restrict__ in, float* __restrict__ out,
          int O, int D, int mode)
{
    int o = blockIdx.x * 256 + threadIdx.x;
    int b = blockIdx.y;
    if (o >= O) return;
    const float* ib = in + (long)b * D;
    float s = bias[o];
    for (int d = 0; d < D; d++) s += W[(long)o * D + d] * ib[d];
    if (mode == 1) s = 1.f / (1.f + expf(-s));
    out[(long)b * O + o] = s;
}

// y = relu(feat * (1 + gamma[b,c]))
__global__ __launch_bounds__(256)
void ymul_k(const float* __restrict__ feat, const float* __restrict__ gamma,
            float* __restrict__ y, int C, int HW)
{
    long total = 2L * C * HW;
    for (long i = blockIdx.x * 256L + threadIdx.x; i < total; i += (long)gridDim.x * 256) {
        int c = (int)((i / HW) % C);
        int b = (int)(i / ((long)C * HW));
        y[i] = fmaxf(feat[i] * (1.f + gamma[b * C + c]), 0.f);
    }
}

static inline dim3 ggrid(int M, int N, int B) { return dim3((N + 63) / 64, (M + 63) / 64, B); }

extern "C" void kernel_launch(void* const* d_in, const int* in_sizes, int n_in,
                              void* d_out, int out_size, void* d_ws, size_t ws_size,
                              hipStream_t stream)
{
    (void)in_sizes; (void)n_in; (void)out_size; (void)ws_size;
    const float* c2  = (const float*)d_in[1];   // (2,512,64,64)
    const float* c3  = (const float*)d_in[2];   // (2,1024,32,32)
    const float* c4  = (const float*)d_in[3];   // (2,2048,16,16)
    const float* wq4 = (const float*)d_in[7];   // (128,1024)
    const float* gq4 = (const float*)d_in[8];
    const float* bq4 = (const float*)d_in[9];
    const float* wk4 = (const float*)d_in[10];  // (128,2048)
    const float* gk4 = (const float*)d_in[11];
    const float* bk4 = (const float*)d_in[12];
    const float* wv4 = (const float*)d_in[13];  // (1024,2048)
    const float* wq3 = (const float*)d_in[14];  // (64,512)
    const float* gq3 = (const float*)d_in[15];
    const float* bq3 = (const float*)d_in[16];
    const float* wk3 = (const float*)d_in[17];  // (64,1024)
    const float* gk3 = (const float*)d_in[18];
    const float* bk3 = (const float*)d_in[19];
    const float* wv3 = (const float*)d_in[20];  // (512,1024)
    const float* w5  = (const float*)d_in[21];  // (512,512,3,3)
    const float* g5  = (const float*)d_in[22];
    const float* b5  = (const float*)d_in[23];
    const float* we  = (const float*)d_in[24];  // (512,512)
    const float* ge  = (const float*)d_in[25];
    const float* be  = (const float*)d_in[26];
    const float* cw  = (const float*)d_in[27];  // (32,512)
    const float* scl = (const float*)d_in[28];
    const float* gK  = (const float*)d_in[29];
    const float* bK  = (const float*)d_in[30];
    const float* wfc = (const float*)d_in[31];  // (512,512)
    const float* bfc = (const float*)d_in[32];
    const float* wse = (const float*)d_in[33];  // (150,512)
    const float* bse = (const float*)d_in[34];
    const float* w6  = (const float*)d_in[35];  // (150,512)
    const float* b6  = (const float*)d_in[36];
    float* outp = (float*)d_out;
    float* ws = (float*)d_ws;

    // workspace layout (floats) — lifetimes verified for overlap safety
    const long OFF_Q4   = 0;         // 2*128*1024
    const long OFF_K4   = 262144;
    const long OFF_CKU4 = 524288;    // 2*2048*1024
    const long OFF_V4   = 4718592;   // 2*1024*1024
    const long OFF_ATT4 = 6815744;   // 2*1024*9
    const long OFF_OUT4 = 6834176;   // 2*1024*1024 -> ends 8931328
    const long OFF_CKU3 = 8931328;   // 2*1024*4096 -> ends 17319936
    const long OFF_Q3   = 0;         // reuse (stage-A scratch dead)
    const long OFF_K3   = 524288;
    const long OFF_V3   = 1048576;   // 2*512*4096
    const long OFF_ATT3 = 5242880;   // 2*4096*9
    const long OFF_OUT3 = 5316608;   // 2*512*4096 -> ends 9510912 (cku3 dead by then)
    const long OFF_FEAT = 9510912;   // 2*512*4096 -> ends 13705216
    const long OFF_X    = 0;         // reuse
    const long OFF_XC   = 4194304;   // 2*32*4096
    const long OFF_A    = 4456448;   // 2*4096*32
    const long OFF_ET   = 4718592;   // 2*512*32
    const long OFF_E    = 4751360;   // 2*32*512
    const long OFF_ASUM = 4784128;   // 64
    const long OFF_CC   = 4784192;   // 32
    const long OFF_EN   = 4784224;   // 1024
    const long OFF_GAM  = 4785248;   // 1024
    const long OFF_MV   = 4786272;   // up to 1024 used
    const long OFF_Y    = 13705216;  // 2*512*4096 -> ends 17899520 (~71.6 MB)

    float* mv = ws + OFF_MV;

    // ---------------- Stage A: local_up(c3, c4) -> out4 (2,1024,32,32)
    // q4 = BN(wq4 @ c3): c3 has 1024 channels, HW=1024
    gemm_k<false,false><<<ggrid(128,1024,2),256,0,stream>>>(wq4, c3, ws+OFF_Q4, nullptr,
        128, 1024, 1024, 0, 1024, 1, 0, 1024L*1024, 128L*1024, 0,0,0,0);
    bn_stats_k<<<128,256,0,stream>>>(ws+OFF_Q4, mv, 1024, 2, 128L*1024);
    bn_apply_k<<<1024,256,0,stream>>>(ws+OFF_Q4, ws+OFF_Q4, mv, gq4, bq4, 128, 1024, 2L*128*1024, 0);
    // cku4 = bilinear_up(c4, 32,32)
    upsample_k<<<16384,256,0,stream>>>(c4, ws+OFF_CKU4, 2048, 16,16, 32,32, 2);
    // k4 = BN(wk4 @ cku4)
    gemm_k<false,false><<<ggrid(128,1024,2),256,0,stream>>>(wk4, ws+OFF_CKU4, ws+OFF_K4, nullptr,
        128, 2048, 1024, 0, 2048, 1, 0, 2048L*1024, 128L*1024, 0,0,0,0);
    bn_stats_k<<<128,256,0,stream>>>(ws+OFF_K4, mv, 1024, 2, 128L*1024);
    bn_apply_k<<<1024,256,0,stream>>>(ws+OFF_K4, ws+OFF_K4, mv, gk4, bk4, 128, 1024, 2L*128*1024, 0);
    // v4 = wv4 @ cku4
    gemm_k<false,false><<<ggrid(1024,1024,2),256,0,stream>>>(wv4, ws+OFF_CKU4, ws+OFF_V4, nullptr,
        1024, 2048, 1024, 0, 2048, 1, 0, 2048L*1024, 1024L*1024, 0,0,0,0);
    // att + apply
    att_k<<<dim3(4,2),256,0,stream>>>(ws+OFF_Q4, ws+OFF_K4, ws+OFF_ATT4, 128, 32, 32);
    attout_k<<<dim3(4,64,2),256,0,stream>>>(ws+OFF_ATT4, ws+OFF_V4, ws+OFF_OUT4, 1024, 32, 32, 16);

    // ---------------- Stage B: local_up(c2, out4) -> out3 (2,512,64,64)
    gemm_k<false,false><<<ggrid(64,4096,2),256,0,stream>>>(wq3, c2, ws+OFF_Q3, nullptr,
        64, 512, 4096, 0, 512, 1, 0, 512L*4096, 64L*4096, 0,0,0,0);
    bn_stats_k<<<64,256,0,stream>>>(ws+OFF_Q3, mv, 4096, 2, 64L*4096);
    bn_apply_k<<<2048,256,0,stream>>>(ws+OFF_Q3, ws+OFF_Q3, mv, gq3, bq3, 64, 4096, 2L*64*4096, 0);
    upsample_k<<<32768,256,0,stream>>>(ws+OFF_OUT4, ws+OFF_CKU3, 1024, 32,32, 64,64, 2);
    gemm_k<false,false><<<ggrid(64,4096,2),256,0,stream>>>(wk3, ws+OFF_CKU3, ws+OFF_K3, nullptr,
        64, 1024, 4096, 0, 1024, 1, 0, 1024L*4096, 64L*4096, 0,0,0,0);
    bn_stats_k<<<64,256,0,stream>>>(ws+OFF_K3, mv, 4096, 2, 64L*4096);
    bn_apply_k<<<2048,256,0,stream>>>(ws+OFF_K3, ws+OFF_K3, mv, gk3, bk3, 64, 4096, 2L*64*4096, 0);
    gemm_k<false,false><<<ggrid(512,4096,2),256,0,stream>>>(wv3, ws+OFF_CKU3, ws+OFF_V3, nullptr,
        512, 1024, 4096, 0, 1024, 1, 0, 1024L*4096, 512L*4096, 0,0,0,0);
    att_k<<<dim3(16,2),256,0,stream>>>(ws+OFF_Q3, ws+OFF_K3, ws+OFF_ATT3, 64, 64, 64);
    attout_k<<<dim3(16,32,2),256,0,stream>>>(ws+OFF_ATT3, ws+OFF_V3, ws+OFF_OUT3, 512, 64, 64, 16);

    // ---------------- Stage C: feat = relu(BN(conv3x3(out3, w5)))
    for (int t = 0; t < 9; t++) {
        int ky = t / 3, kx = t % 3;
        if (t == 0)
            gemm_k<true,false><<<ggrid(512,4096,2),256,0,stream>>>(w5, ws+OFF_OUT3, ws+OFF_FEAT, nullptr,
                512, 512, 4096, 0, 512L*9, 9, (long)(ky*3+kx), 512L*4096, 512L*4096, 64, 64, ky-1, kx-1);
        else
            gemm_k<true,true><<<ggrid(512,4096,2),256,0,stream>>>(w5, ws+OFF_OUT3, ws+OFF_FEAT, nullptr,
                512, 512, 4096, 0, 512L*9, 9, (long)(ky*3+kx), 512L*4096, 512L*4096, 64, 64, ky-1, kx-1);
    }
    bn_stats_k<<<512,256,0,stream>>>(ws+OFF_FEAT, mv, 4096, 2, 512L*4096);
    bn_apply_k<<<16384,256,0,stream>>>(ws+OFF_FEAT, ws+OFF_FEAT, mv, g5, b5, 512, 4096, 2L*512*4096, 1);

    // ---------------- Stage D: enc_module
    gemm_k<false,false><<<ggrid(512,4096,2),256,0,stream>>>(we, ws+OFF_FEAT, ws+OFF_X, nullptr,
        512, 512, 4096, 0, 512, 1, 0, 512L*4096, 512L*4096, 0,0,0,0);
    bn_stats_k<<<512,256,0,stream>>>(ws+OFF_X, mv, 4096, 2, 512L*4096);
    bn_apply_k<<<16384,256,0,stream>>>(ws+OFF_X, ws+OFF_X, mv, ge, be, 512, 4096, 2L*512*4096, 1);
    gemm_k<false,false><<<ggrid(32,4096,2),256,0,stream>>>(cw, ws+OFF_X, ws+OFF_XC, nullptr,
        32, 512, 4096, 0, 512, 1, 0, 512L*4096, 32L*4096, 0,0,0,0);
    cc_k<<<1,32,0,stream>>>(cw, ws+OFF_CC, 512);
    assign_k<<<dim3(16,2),256,0,stream>>>(ws+OFF_X, ws+OFF_XC, ws+OFF_CC, scl, ws+OFF_A, 512, 4096);
    asum_k<<<dim3(32,2),256,0,stream>>>(ws+OFF_A, ws+OFF_ASUM, 4096);
    // Et[b] (512x32) = x[b] (512x4096) @ A[b] (4096x32)
    gemm_k<false,false><<<ggrid(512,32,2),256,0,stream>>>(ws+OFF_X, ws+OFF_A, ws+OFF_ET, nullptr,
        512, 4096, 32, 512L*4096, 4096, 1, 0, 4096L*32, 512L*32, 0,0,0,0);
    efix_k<<<128,256,0,stream>>>(ws+OFF_ET, ws+OFF_ASUM, cw, ws+OFF_E, 512);
    bn_stats_k<<<32,256,0,stream>>>(ws+OFF_E, mv, 512, 2, 32L*512);
    en_k<<<4,256,0,stream>>>(ws+OFF_E, mv, gK, bK, ws+OFF_EN, 512);
    fc_k<<<dim3(2,2),256,0,stream>>>(wfc, bfc, ws+OFF_EN, ws+OFF_GAM, 512, 512, 1);
    fc_k<<<dim3(1,2),256,0,stream>>>(wse, bse, ws+OFF_EN, outp + 1228800, 150, 512, 0);
    ymul_k<<<16384,256,0,stream>>>(ws+OFF_FEAT, ws+OFF_GAM, ws+OFF_Y, 512, 4096);

    // ---------------- Stage E: seg = w6 @ y + b6 -> d_out
    gemm_k<false,false><<<ggrid(150,4096,2),256,0,stream>>>(w6, ws+OFF_Y, outp, b6,
        150, 512, 4096, 0, 512, 1, 0, 512L*4096, 150L*4096, 0,0,0,0);
}

// Round 4
// 975.358 us; speedup vs baseline: 3.6442x; 3.6442x over previous
//
#include <hip/hip_runtime.h>
#include <math.h>

#define EPSBN 1e-5f

typedef _Float16 f16;
typedef _Float16 f16x8 __attribute__((ext_vector_type(8)));
typedef _Float16 f16x4 __attribute__((ext_vector_type(4)));
typedef float f32x4 __attribute__((ext_vector_type(4)));

static __device__ inline f16x8 h8zero() {
    f16x8 v;
#pragma unroll
    for (int j = 0; j < 8; j++) v[j] = (f16)0.f;
    return v;
}

// ---------------------------------------------------------------------------
// MFMA f16 GEMM, NHWC activations. D[m][n] = sum_k W[m][k] * act[n][k].
// MODE 0: out f16 NHWC ([n][M]); MODE 1: conv3x3-d1 tap-shifted B (K=Cact*9,
// weight layout [O][tap][C]), out f16 NHWC; MODE 2: out f32 CHW ([m][N]) + bias.
// Tile 128x128, BK=32, 4 waves (2x2), wave = 64x64 = 4x4 frags of 16x16.
// ---------------------------------------------------------------------------
template<int MODE>
__global__ __launch_bounds__(256)
void hgemm_k(const f16* __restrict__ Wh, const f16* __restrict__ act,
             void* __restrict__ outv, const float* __restrict__ bias,
             int M, int K, int N, int Cact, long actStride, long outStride,
             int IW, int IH)
{
    const int b = blockIdx.z;
    const int n0 = blockIdx.x * 128, m0 = blockIdx.y * 128;
    const f16* actb = act + (long)b * actStride;
    __shared__ __align__(16) f16 As[128 * 40];
    __shared__ __align__(16) f16 Bs[128 * 40];
    const int tid = threadIdx.x;
    const int wave = tid >> 6, lane = tid & 63;
    const int wm = (wave >> 1) * 64, wn = (wave & 1) * 64;
    const int lr = lane & 15, lg = lane >> 4;
    const int srow = tid >> 2, scol = (tid & 3) * 8;
    f32x4 acc[4][4];
#pragma unroll
    for (int i = 0; i < 4; i++)
#pragma unroll
        for (int j = 0; j < 4; j++)
#pragma unroll
            for (int r = 0; r < 4; r++) acc[i][j][r] = 0.f;

    for (int k0 = 0; k0 < K; k0 += 32) {
        __syncthreads();
#pragma unroll
        for (int i = 0; i < 2; i++) {
            int r = srow + i * 64;
            int m = m0 + r;
            f16x8 av = h8zero();
            if (m < M) av = *(const f16x8*)&Wh[(long)m * K + k0 + scol];
            *(f16x8*)&As[r * 40 + scol] = av;
            int n = n0 + r;
            f16x8 bv;
            if (MODE == 1) {
                int tap = k0 >> 9;                 // K = 512*9, taps outer
                int kc = (k0 & 511) + scol;
                int dy = tap / 3 - 1, dx = tap % 3 - 1;
                int yy = n / IW + dy, xx = n % IW + dx;
                if (yy >= 0 && yy < IH && xx >= 0 && xx < IW)
                    bv = *(const f16x8*)&actb[(long)(yy * IW + xx) * Cact + kc];
                else bv = h8zero();
            } else {
                bv = *(const f16x8*)&actb[(long)n * Cact + k0 + scol];
            }
            *(f16x8*)&Bs[r * 40 + scol] = bv;
        }
        __syncthreads();
        f16x8 af[4], bf[4];
#pragma unroll
        for (int i = 0; i < 4; i++)
            af[i] = *(const f16x8*)&As[(wm + i * 16 + lr) * 40 + lg * 8];
#pragma unroll
        for (int j = 0; j < 4; j++)
            bf[j] = *(const f16x8*)&Bs[(wn + j * 16 + lr) * 40 + lg * 8];
#pragma unroll
        for (int i = 0; i < 4; i++)
#pragma unroll
            for (int j = 0; j < 4; j++)
                acc[i][j] = __builtin_amdgcn_mfma_f32_16x16x32_f16(af[i], bf[j], acc[i][j], 0, 0, 0);
    }

    if (MODE == 2) {
        float* outp = (float*)outv + (long)b * outStride;
#pragma unroll
        for (int i = 0; i < 4; i++)
#pragma unroll
            for (int j = 0; j < 4; j++) {
                int n = n0 + wn + j * 16 + lr;
#pragma unroll
                for (int r = 0; r < 4; r++) {
                    int m = m0 + wm + i * 16 + lg * 4 + r;
                    if (m < M) outp[(long)m * N + n] = acc[i][j][r] + bias[m];
                }
            }
    } else {
        f16* outp = (f16*)outv + (long)b * outStride;
#pragma unroll
        for (int i = 0; i < 4; i++)
#pragma unroll
            for (int j = 0; j < 4; j++) {
                int n = n0 + wn + j * 16 + lr;
                int mb = m0 + wm + i * 16 + lg * 4;
                if (mb < M) {
                    f16x4 hv;
#pragma unroll
                    for (int r = 0; r < 4; r++) hv[r] = (f16)acc[i][j][r];
                    *(f16x4*)&outp[(long)n * M + mb] = hv;
                }
            }
    }
}

// CHW f32 -> NHWC f16 tiled transpose (C, HW multiples of 32)
__global__ __launch_bounds__(256)
void chw2nhwc_k(const float* __restrict__ in, f16* __restrict__ out, int C, int HW)
{
    int b = blockIdx.z;
    int l0 = blockIdx.x * 32, c0 = blockIdx.y * 32;
    __shared__ float t[32][33];
    int tx = threadIdx.x & 31, ty = threadIdx.x >> 5;
    const float* ib = in + (long)b * C * HW;
#pragma unroll
    for (int j = 0; j < 4; j++) {
        int c = c0 + ty + j * 8;
        t[ty + j * 8][tx] = ib[(long)c * HW + l0 + tx];
    }
    __syncthreads();
    f16* ob = out + (long)b * HW * C;
#pragma unroll
    for (int j = 0; j < 4; j++) {
        int l = l0 + ty + j * 8;
        ob[(long)l * C + c0 + tx] = (f16)t[tx][ty + j * 8];
    }
}

// flat f32 -> f16
__global__ void f2h_k(const float* __restrict__ src, f16* __restrict__ dst, long n)
{
    long i = blockIdx.x * 256L + threadIdx.x;
    if (i < n) dst[i] = (f16)src[i];
}

// w5 (O,C,3,3) f32 -> w5r[O][tap][C] f16  (K ordered taps-outer, c-inner)
__global__ void w5r_k(const float* __restrict__ src, f16* __restrict__ dst)
{
    long i = blockIdx.x * 256L + threadIdx.x;
    if (i >= 9L * 512 * 512) return;
    int c = (int)(i % 512); long t2 = i / 512;
    int t = (int)(t2 % 9); int o = (int)(t2 / 9);
    dst[i] = (f16)src[(long)o * 4608 + c * 9 + t];
}

__global__ void zero_k(float* __restrict__ p, int n)
{
    int i = blockIdx.x * 256 + threadIdx.x;
    if (i < n) p[i] = 0.f;
}

// atomic column sums over NHWC rows: sums[2c] += x, sums[2c+1] += x^2
__global__ __launch_bounds__(256)
void bnsum_k(const f16* __restrict__ x, float* __restrict__ sums, int C, long rows)
{
    int CB = C < 256 ? C : 256;
    int RT = 256 / CB;
    int c = blockIdx.x * 256 + (threadIdx.x % CB);
    int rg = threadIdx.x / CB;
    float s = 0.f, s2 = 0.f;
    for (long r = (long)blockIdx.y * RT + rg; r < rows; r += 64L * RT) {
        float v = (float)x[r * C + c];
        s += v; s2 += v * v;
    }
    atomicAdd(&sums[2 * c], s);
    atomicAdd(&sums[2 * c + 1], s2);
}

// apply BN (from raw sums) elementwise, f16 in/out, 8 elems/thread
__global__ __launch_bounds__(256)
void bnapply_k(f16* __restrict__ x, const float* __restrict__ mv,
               const float* __restrict__ g, const float* __restrict__ bta,
               int C, long total, float inv, int dorelu)
{
    long i8 = (blockIdx.x * 256L + threadIdx.x) * 8;
    if (i8 >= total) return;
    int c0 = (int)(i8 % C);
    f16x8 v = *(f16x8*)&x[i8];
#pragma unroll
    for (int j = 0; j < 8; j++) {
        int c = c0 + j;
        float m = mv[2 * c] * inv;
        float var = mv[2 * c + 1] * inv - m * m;
        float r = ((float)v[j] - m) * rsqrtf(var + EPSBN) * g[c] + bta[c];
        if (dorelu) r = fmaxf(r, 0.f);
        v[j] = (f16)r;
    }
    *(f16x8*)&x[i8] = v;
}

// bilinear upsample align_corners=True, NHWC f16
__global__ __launch_bounds__(256)
void upsample_h(const f16* __restrict__ in, f16* __restrict__ out,
                int C, int H, int W, int OH, int OW)
{
    long total = 2L * C * OH * OW;
    float ry = (float)(H - 1) / (float)(OH - 1);
    float rx = (float)(W - 1) / (float)(OW - 1);
    for (long i = blockIdx.x * 256L + threadIdx.x; i < total; i += (long)gridDim.x * 256) {
        int c = (int)(i % C); long t = i / C;
        int l = (int)(t % (OH * OW)); int bb = (int)(t / (OH * OW));
        int oy = l / OW, ox = l % OW;
        float fy = oy * ry, fx = ox * rx;
        int y0 = (int)fy, x0 = (int)fx;
        int y1 = min(y0 + 1, H - 1), x1 = min(x0 + 1, W - 1);
        float wy = fy - y0, wx = fx - x0;
        const f16* p = in + (long)bb * H * W * C + c;
        float v00 = (float)p[(long)(y0 * W + x0) * C];
        float v01 = (float)p[(long)(y0 * W + x1) * C];
        float v10 = (float)p[(long)(y1 * W + x0) * C];
        float v11 = (float)p[(long)(y1 * W + x1) * C];
        out[i] = (f16)((v00 * (1.f - wx) + v01 * wx) * (1.f - wy) +
                       (v10 * (1.f - wx) + v11 * wx) * wy);
    }
}

// energy + softmax over 9 dilated-2 taps (NHWC f16 q/k) -> att f32 (n,l,9)
__global__ __launch_bounds__(256)
void att_h(const f16* __restrict__ q, const f16* __restrict__ k,
           float* __restrict__ att, int C, int H, int W)
{
    int HW = H * W;
    int l = blockIdx.x * 256 + threadIdx.x;
    int n = blockIdx.y;
    if (l >= HW) return;
    int y = l / W, x = l % W;
    int offs[9]; bool val[9];
#pragma unroll
    for (int t = 0; t < 9; t++) {
        int a = t / 3, bj = t % 3;
        int yy = y + 2 * a - 2, xx = x + 2 * bj - 2;
        val[t] = (yy >= 0 && yy < H && xx >= 0 && xx < W);
        offs[t] = val[t] ? yy * W + xx : 0;
    }
    float e[9] = {0.f, 0.f, 0.f, 0.f, 0.f, 0.f, 0.f, 0.f, 0.f};
    const f16* qr = q + ((long)n * HW + l) * C;
    const f16* kb = k + (long)n * HW * C;
    for (int c = 0; c < C; c += 8) {
        f16x8 qv = *(const f16x8*)&qr[c];
        float qf[8];
#pragma unroll
        for (int j = 0; j < 8; j++) qf[j] = (float)qv[j];
#pragma unroll
        for (int t = 0; t < 9; t++) {
            if (!val[t]) continue;
            f16x8 kv = *(const f16x8*)&kb[(long)offs[t] * C + c];
#pragma unroll
            for (int j = 0; j < 8; j++) e[t] = fmaf(qf[j], (float)kv[j], e[t]);
        }
    }
    float mx = e[0];
#pragma unroll
    for (int t = 1; t < 9; t++) mx = fmaxf(mx, e[t]);
    float s = 0.f; float ex[9];
#pragma unroll
    for (int t = 0; t < 9; t++) { ex[t] = expf(e[t] - mx); s += ex[t]; }
    float inv = 1.f / s;
    long base = ((long)n * HW + l) * 9;
#pragma unroll
    for (int t = 0; t < 9; t++) att[base + t] = ex[t] * inv;
}

// out[b,l,c] = sum_t att * v[neigh] (NHWC f16)
__global__ __launch_bounds__(256)
void attout_h(const float* __restrict__ att, const f16* __restrict__ v,
              f16* __restrict__ out, int C, int H, int W)
{
    int HW = H * W;
    long total = 2L * HW * C;
    for (long i = blockIdx.x * 256L + threadIdx.x; i < total; i += (long)gridDim.x * 256) {
        int c = (int)(i % C); long t2 = i / C;
        int l = (int)(t2 % HW); int bb = (int)(t2 / HW);
        int y = l / W, x = l % W;
        long abase = ((long)bb * HW + l) * 9;
        const f16* vb = v + (long)bb * HW * C + c;
        float s = 0.f;
#pragma unroll
        for (int t = 0; t < 9; t++) {
            int aa = t / 3, bj = t % 3;
            int yy = y + 2 * aa - 2, xx = x + 2 * bj - 2;
            if (yy >= 0 && yy < H && xx >= 0 && xx < W)
                s = fmaf(att[abase + t], (float)vb[(long)(yy * W + xx) * C], s);
        }
        out[i] = (f16)s;
    }
}

// codeword squared norms
__global__ void cc_k(const float* __restrict__ cw, float* __restrict__ cc, int D)
{
    int k = threadIdx.x;
    if (k < 32) {
        float s = 0.f;
        for (int d = 0; d < D; d++) { float v = cw[(long)k * D + d]; s += v * v; }
        cc[k] = s;
    }
}

// soft-assign: x f16 NHWC, xc f16 [l][32] -> A f32 [l][32]
__global__ __launch_bounds__(256)
void assign_h(const f16* __restrict__ x, const f16* __restrict__ xc,
              const float* __restrict__ cc, const float* __restrict__ scale,
              float* __restrict__ A)
{
    int l = blockIdx.x * 256 + threadIdx.x;
    int bb = blockIdx.y;
    if (l >= 4096) return;
    const f16* xr = x + ((long)bb * 4096 + l) * 512;
    float xx = 0.f;
    for (int d = 0; d < 512; d += 8) {
        f16x8 v = *(const f16x8*)&xr[d];
#pragma unroll
        for (int j = 0; j < 8; j++) { float f = (float)v[j]; xx = fmaf(f, f, xx); }
    }
    const f16* xcr = xc + ((long)bb * 4096 + l) * 32;
    float e[32]; float mx = -1e30f;
#pragma unroll
    for (int k2 = 0; k2 < 32; k2++) {
        float dist = xx + cc[k2] - 2.f * (float)xcr[k2];
        float en = -scale[k2] * dist;
        e[k2] = en; mx = fmaxf(mx, en);
    }
    float s = 0.f;
#pragma unroll
    for (int k2 = 0; k2 < 32; k2++) { e[k2] = expf(e[k2] - mx); s += e[k2]; }
    float inv = 1.f / s;
    long base = ((long)bb * 4096 + l) * 32;
#pragma unroll
    for (int k2 = 0; k2 < 32; k2++) A[base + k2] = e[k2] * inv;
}

__global__ __launch_bounds__(256)
void asum_k(const float* __restrict__ A, float* __restrict__ Asum, int HW)
{
    int k2 = blockIdx.x, b = blockIdx.y;
    float s = 0.f;
    for (int l = threadIdx.x; l < HW; l += 256) s += A[((long)b * HW + l) * 32 + k2];
    __shared__ float sh[256];
    sh[threadIdx.x] = s;
    __syncthreads();
    for (int o = 128; o > 0; o >>= 1) {
        if (threadIdx.x < o) sh[threadIdx.x] += sh[threadIdx.x + o];
        __syncthreads();
    }
    if (threadIdx.x == 0) Asum[b * 32 + k2] = sh[0];
}

// Et partial GEMM: Etp[z][k2][d] = sum_{l in chunk} A[l][k2] * X[l][d], z = b*16+chunk
__global__ __launch_bounds__(256)
void etg_k(const float* __restrict__ Af, const f16* __restrict__ Xh, float* __restrict__ Etp)
{
    int z = blockIdx.z; int b = z >> 4; int ch = z & 15;
    int kbase = ch * 256;
    const float* Ab = Af + (long)b * 4096 * 32;
    const f16* Xb = Xh + (long)b * 4096 * 512;
    int n0 = blockIdx.x * 64;
    __shared__ float As[16][65];
    __shared__ float Bs[16][64];
    int tid = threadIdx.x; int tx = tid & 15, ty = tid >> 4;
    float acc[4][4];
#pragma unroll
    for (int i = 0; i < 4; i++)
#pragma unroll
        for (int j = 0; j < 4; j++) acc[i][j] = 0.f;
    for (int k0 = 0; k0 < 256; k0 += 16) {
#pragma unroll
        for (int i = 0; i < 4; i++) {
            int idx = tid + i * 256;
            int kk = idx & 15, mm = idx >> 4;
            float vv = 0.f;
            if (mm < 32) vv = Ab[(long)(kbase + k0 + kk) * 32 + mm];
            As[kk][mm] = vv;
        }
#pragma unroll
        for (int i = 0; i < 4; i++) {
            int idx = tid + i * 256;
            int nn = idx & 63, kk = idx >> 6;
            Bs[kk][nn] = (float)Xb[(long)(kbase + k0 + kk) * 512 + n0 + nn];
        }
        __syncthreads();
#pragma unroll
        for (int kk = 0; kk < 16; kk++) {
            float a[4], bb2[4];
#pragma unroll
            for (int i = 0; i < 4; i++) a[i] = As[kk][ty + i * 16];
#pragma unroll
            for (int j = 0; j < 4; j++) bb2[j] = Bs[kk][tx + j * 16];
#pragma unroll
            for (int i = 0; i < 4; i++)
#pragma unroll
                for (int j = 0; j < 4; j++)
                    acc[i][j] = fmaf(a[i], bb2[j], acc[i][j]);
        }
        __syncthreads();
    }
    float* Ob = Etp + (long)z * 32 * 512;
#pragma unroll
    for (int i = 0; i < 4; i++) {
        int m = ty + i * 16;
        if (m >= 32) continue;
#pragma unroll
        for (int j = 0; j < 4; j++) Ob[(long)m * 512 + n0 + tx + j * 16] = acc[i][j];
    }
}

// E[b,k,d] = sum_chunks Etp - Asum*cw
__global__ void efix2_k(const float* __restrict__ Etp, const float* __restrict__ asumf,
                        const float* __restrict__ cwf, float* __restrict__ Ef)
{
    int i = blockIdx.x * 256 + threadIdx.x;
    if (i >= 2 * 32 * 512) return;
    int d = i % 512; int k2 = (i / 512) % 32; int bb = i / (512 * 32);
    float s = 0.f;
#pragma unroll
    for (int c2 = 0; c2 < 16; c2++) s += Etp[((long)(bb * 16 + c2) * 32 + k2) * 512 + d];
    Ef[i] = s - asumf[bb * 32 + k2] * cwf[k2 * 512 + d];
}

// BN stats (mean/var) over (n,spatial) per channel, f32 input (for E)
__global__ __launch_bounds__(256)
void bn_stats_k(const float* __restrict__ x, float* __restrict__ mv,
                int HW, int Nb, long strideN)
{
    int c = blockIdx.x;
    long total = (long)Nb * HW;
    float s = 0.f, s2 = 0.f;
    for (long i = threadIdx.x; i < total; i += 256) {
        int n = (int)(i / HW); int l = (int)(i % HW);
        float v = x[(long)n * strideN + (long)c * HW + l];
        s += v; s2 += v * v;
    }
    __shared__ float sh0[256], sh1[256];
    sh0[threadIdx.x] = s; sh1[threadIdx.x] = s2;
    __syncthreads();
    for (int o = 128; o > 0; o >>= 1) {
        if (threadIdx.x < o) { sh0[threadIdx.x] += sh0[threadIdx.x + o]; sh1[threadIdx.x] += sh1[threadIdx.x + o]; }
        __syncthreads();
    }
    if (threadIdx.x == 0) {
        float inv = 1.f / (float)total;
        float m = sh0[0] * inv;
        mv[2 * c] = m;
        mv[2 * c + 1] = sh1[0] * inv - m * m;
    }
}

// en[b,d] = mean_k relu(BN1d(E[b,k,d]))
__global__ __launch_bounds__(256)
void en_k(const float* __restrict__ E, const float* __restrict__ mv,
          const float* __restrict__ gK, const float* __restrict__ bK,
          float* __restrict__ en, int D)
{
    int i = blockIdx.x * 256 + threadIdx.x;
    if (i >= 2 * D) return;
    int b = i / D, d = i % D;
    float s = 0.f;
#pragma unroll
    for (int k2 = 0; k2 < 32; k2++) {
        float m = mv[2 * k2], vv = mv[2 * k2 + 1];
        float r = (E[((long)b * 32 + k2) * D + d] - m) * rsqrtf(vv + EPSBN) * gK[k2] + bK[k2];
        s += fmaxf(r, 0.f);
    }
    en[i] = s * (1.f / 32.f);
}

__global__ __launch_bounds__(256)
void fc_k(const float* __restrict__ W, const float* __restrict__ bias,
          const float* __restrict__ in, float* __restrict__ out,
          int O, int D, int mode)
{
    int o = blockIdx.x * 256 + threadIdx.x;
    int b = blockIdx.y;
    if (o >= O) return;
    const float* ib = in + (long)b * D;
    float s = bias[o];
    for (int d = 0; d < D; d++) s += W[(long)o * D + d] * ib[d];
    if (mode == 1) s = 1.f / (1.f + expf(-s));
    out[(long)b * O + o] = s;
}

// y = relu(feat * (1+gamma)), f16 NHWC
__global__ __launch_bounds__(256)
void ymul_h(const f16* __restrict__ feat, const float* __restrict__ gamma,
            f16* __restrict__ y)
{
    long total = 2L * 4096 * 512;
    for (long i = blockIdx.x * 256L + threadIdx.x; i < total; i += (long)gridDim.x * 256) {
        int c = (int)(i % 512);
        int bb = (int)(i / (4096L * 512));
        y[i] = (f16)fmaxf((float)feat[i] * (1.f + gamma[bb * 512 + c]), 0.f);
    }
}

extern "C" void kernel_launch(void* const* d_in, const int* in_sizes, int n_in,
                              void* d_out, int out_size, void* d_ws, size_t ws_size,
                              hipStream_t stream)
{
    (void)in_sizes; (void)n_in; (void)out_size; (void)ws_size;
    const float* c2  = (const float*)d_in[1];
    const float* c3  = (const float*)d_in[2];
    const float* c4  = (const float*)d_in[3];
    const float* wq4 = (const float*)d_in[7];
    const float* gq4 = (const float*)d_in[8];
    const float* bq4 = (const float*)d_in[9];
    const float* wk4 = (const float*)d_in[10];
    const float* gk4 = (const float*)d_in[11];
    const float* bk4 = (const float*)d_in[12];
    const float* wv4 = (const float*)d_in[13];
    const float* wq3 = (const float*)d_in[14];
    const float* gq3 = (const float*)d_in[15];
    const float* bq3 = (const float*)d_in[16];
    const float* wk3 = (const float*)d_in[17];
    const float* gk3 = (const float*)d_in[18];
    const float* bk3 = (const float*)d_in[19];
    const float* wv3 = (const float*)d_in[20];
    const float* w5  = (const float*)d_in[21];
    const float* g5  = (const float*)d_in[22];
    const float* b5  = (const float*)d_in[23];
    const float* we  = (const float*)d_in[24];
    const float* ge  = (const float*)d_in[25];
    const float* be  = (const float*)d_in[26];
    const float* cw  = (const float*)d_in[27];
    const float* scl = (const float*)d_in[28];
    const float* gK  = (const float*)d_in[29];
    const float* bK  = (const float*)d_in[30];
    const float* wfc = (const float*)d_in[31];
    const float* bfc = (const float*)d_in[32];
    const float* wse = (const float*)d_in[33];
    const float* bse = (const float*)d_in[34];
    const float* w6  = (const float*)d_in[35];
    const float* b6  = (const float*)d_in[36];
    float* outp = (float*)d_out;
    char* ws = (char*)d_ws;

    // ---- workspace (byte offsets), liveness-checked overlays ----
    auto H = [&](long off) { return (f16*)(ws + off); };
    auto F = [&](long off) { return (float*)(ws + off); };
    const long O_wq4h = 0;         // 262144
    const long O_wk4h = 262144;    // 524288
    const long O_wv4h = 786432;    // 4194304
    const long O_wq3h = 4980736;   // 65536
    const long O_wk3h = 5046272;   // 131072
    const long O_wv3h = 5177344;   // 1048576
    const long O_w5r  = 6225920;   // 4718592
    const long O_weh  = 10944512;  // 524288
    const long O_cwh  = 11468800;  // 32768
    const long O_w6h  = 11501568;  // 153600 -> 11655168
    const long O_c3h  = 11665408;  // 4.19MB [dead after q4 gemm]
    const long O_Xh   = 11665408;  // 8.39MB (reuses c3h; created post-conv)
    const long O_c4h  = 20054016;  // 2.1MB [dead after upsample4]
    const long O_cku4h= 22151168;  // 8.39MB [dead after v4 gemm]
    const long O_v3h  = 22151168;  // 8.39MB (reuses cku4h; created at v3 gemm)
    const long O_q4h  = 30539776;  // 524288
    const long O_k4h  = 31064064;  // 524288
    const long O_v4h  = 31588352;  // 4.19MB [dead after attout4]
    // stage-B/D smalls reuse q4h/k4h/v4h region after stage A:
    const long O_att3 = 30539776;  // 294912 f32
    const long O_xch  = 30834688;  // 524288 f16
    const long O_Af   = 31358976;  // 1048576 f32
    const long O_Etp  = 32407552;  // 2097152 f32
    const long O_Ef   = 34504704;  // 131072 f32
    const long O_asum = 34635776;  // 256
    const long O_cc   = 34636032;  // 128
    const long O_en   = 34636160;  // 4096
    const long O_gam  = 34640256;  // 4096
    const long O_mv   = 34644352;  // 11520 (2880 floats)
    const long O_att4 = 35782656;  // 73728 f32
    const long O_out4h= 35856384;  // 4.19MB [dead after upsample3]
    const long O_yh   = 35856384;  // 8.39MB (reuses out4h+c2h-head; created at ymul)
    const long O_c2h  = 40050688;  // 8.39MB [dead after q3 gemm]
    const long O_cku3h= 48439296;  // 16.78MB [dead after v3 gemm]
    const long O_feath= 48439296;  // 8.39MB (reuses cku3h; created at conv)
    const long O_out3h= 56827904;  // 8.39MB (reuses cku3h tail; created attout3, dead post conv)
    const long O_q3h  = 65216512;  // 1048576
    const long O_k3h  = 66265088;  // 1048576 -> end 67313664 (~67.3MB)

    float* mv = F(O_mv);

    // ---- conversions ----
    chw2nhwc_k<<<dim3(128, 16, 2), 256, 0, stream>>>(c2, H(O_c2h), 512, 4096);
    chw2nhwc_k<<<dim3(32, 32, 2), 256, 0, stream>>>(c3, H(O_c3h), 1024, 1024);
    chw2nhwc_k<<<dim3(8, 64, 2), 256, 0, stream>>>(c4, H(O_c4h), 2048, 256);
    auto cvt = [&](const float* s, long o, long n) {
        f2h_k<<<(int)((n + 255) / 256), 256, 0, stream>>>(s, H(o), n);
    };
    cvt(wq4, O_wq4h, 128L * 1024); cvt(wk4, O_wk4h, 128L * 2048);
    cvt(wv4, O_wv4h, 1024L * 2048); cvt(wq3, O_wq3h, 64L * 512);
    cvt(wk3, O_wk3h, 64L * 1024); cvt(wv3, O_wv3h, 512L * 1024);
    cvt(we, O_weh, 512L * 512); cvt(cw, O_cwh, 32L * 512);
    cvt(w6, O_w6h, 150L * 512);
    w5r_k<<<9216, 256, 0, stream>>>(w5, H(O_w5r));
    zero_k<<<11, 256, 0, stream>>>(mv, 2816);

    // ---- Stage A: local_up(c3, c4) -> out4h (NHWC 2x1024x1024) ----
    hgemm_k<0><<<dim3(8, 1, 2), 256, 0, stream>>>(H(O_wq4h), H(O_c3h), H(O_q4h), nullptr,
        128, 1024, 1024, 1024, 1024L * 1024, 1024L * 128, 0, 0);
    bnsum_k<<<dim3(1, 64), 256, 0, stream>>>(H(O_q4h), mv + 0, 128, 2048);
    bnapply_k<<<128, 256, 0, stream>>>(H(O_q4h), mv + 0, gq4, bq4, 128, 2L * 1024 * 128, 1.f / 2048.f, 0);
    upsample_h<<<16384, 256, 0, stream>>>(H(O_c4h), H(O_cku4h), 2048, 16, 16, 32, 32);
    hgemm_k<0><<<dim3(8, 1, 2), 256, 0, stream>>>(H(O_wk4h), H(O_cku4h), H(O_k4h), nullptr,
        128, 2048, 1024, 2048, 1024L * 2048, 1024L * 128, 0, 0);
    bnsum_k<<<dim3(1, 64), 256, 0, stream>>>(H(O_k4h), mv + 256, 128, 2048);
    bnapply_k<<<128, 256, 0, stream>>>(H(O_k4h), mv + 256, gk4, bk4, 128, 2L * 1024 * 128, 1.f / 2048.f, 0);
    hgemm_k<0><<<dim3(8, 8, 2), 256, 0, stream>>>(H(O_wv4h), H(O_cku4h), H(O_v4h), nullptr,
        1024, 2048, 1024, 2048, 1024L * 2048, 1024L * 1024, 0, 0);
    att_h<<<dim3(4, 2), 256, 0, stream>>>(H(O_q4h), H(O_k4h), F(O_att4), 128, 32, 32);
    attout_h<<<8192, 256, 0, stream>>>(F(O_att4), H(O_v4h), H(O_out4h), 1024, 32, 32);

    // ---- Stage B: local_up(c2, out4) -> out3h (NHWC 2x4096x512) ----
    hgemm_k<0><<<dim3(32, 1, 2), 256, 0, stream>>>(H(O_wq3h), H(O_c2h), H(O_q3h), nullptr,
        64, 512, 4096, 512, 4096L * 512, 4096L * 64, 0, 0);
    bnsum_k<<<dim3(1, 64), 256, 0, stream>>>(H(O_q3h), mv + 512, 64, 8192);
    bnapply_k<<<256, 256, 0, stream>>>(H(O_q3h), mv + 512, gq3, bq3, 64, 2L * 4096 * 64, 1.f / 8192.f, 0);
    upsample_h<<<32768, 256, 0, stream>>>(H(O_out4h), H(O_cku3h), 1024, 32, 32, 64, 64);
    hgemm_k<0><<<dim3(32, 1, 2), 256, 0, stream>>>(H(O_wk3h), H(O_cku3h), H(O_k3h), nullptr,
        64, 1024, 4096, 1024, 4096L * 1024, 4096L * 64, 0, 0);
    bnsum_k<<<dim3(1, 64), 256, 0, stream>>>(H(O_k3h), mv + 640, 64, 8192);
    bnapply_k<<<256, 256, 0, stream>>>(H(O_k3h), mv + 640, gk3, bk3, 64, 2L * 4096 * 64, 1.f / 8192.f, 0);
    hgemm_k<0><<<dim3(32, 4, 2), 256, 0, stream>>>(H(O_wv3h), H(O_cku3h), H(O_v3h), nullptr,
        512, 1024, 4096, 1024, 4096L * 1024, 4096L * 512, 0, 0);
    att_h<<<dim3(16, 2), 256, 0, stream>>>(H(O_q3h), H(O_k3h), F(O_att3), 64, 64, 64);
    attout_h<<<16384, 256, 0, stream>>>(F(O_att3), H(O_v3h), H(O_out3h), 512, 64, 64);

    // ---- Stage C: feat = relu(BN(conv3x3(out3))) — single K=4608 MFMA GEMM ----
    hgemm_k<1><<<dim3(32, 4, 2), 256, 0, stream>>>(H(O_w5r), H(O_out3h), H(O_feath), nullptr,
        512, 4608, 4096, 512, 4096L * 512, 4096L * 512, 64, 64);
    bnsum_k<<<dim3(2, 64), 256, 0, stream>>>(H(O_feath), mv + 768, 512, 8192);
    bnapply_k<<<2048, 256, 0, stream>>>(H(O_feath), mv + 768, g5, b5, 512, 2L * 4096 * 512, 1.f / 8192.f, 1);

    // ---- Stage D: enc_module ----
    hgemm_k<0><<<dim3(32, 4, 2), 256, 0, stream>>>(H(O_weh), H(O_feath), H(O_Xh), nullptr,
        512, 512, 4096, 512, 4096L * 512, 4096L * 512, 0, 0);
    bnsum_k<<<dim3(2, 64), 256, 0, stream>>>(H(O_Xh), mv + 1792, 512, 8192);
    bnapply_k<<<2048, 256, 0, stream>>>(H(O_Xh), mv + 1792, ge, be, 512, 2L * 4096 * 512, 1.f / 8192.f, 1);
    hgemm_k<0><<<dim3(32, 1, 2), 256, 0, stream>>>(H(O_cwh), H(O_Xh), H(O_xch), nullptr,
        32, 512, 4096, 512, 4096L * 512, 4096L * 32, 0, 0);
    cc_k<<<1, 32, 0, stream>>>(cw, F(O_cc), 512);
    assign_h<<<dim3(16, 2), 256, 0, stream>>>(H(O_Xh), H(O_xch), F(O_cc), scl, F(O_Af));
    asum_k<<<dim3(32, 2), 256, 0, stream>>>(F(O_Af), F(O_asum), 4096);
    etg_k<<<dim3(8, 1, 32), 256, 0, stream>>>(F(O_Af), H(O_Xh), F(O_Etp));
    efix2_k<<<128, 256, 0, stream>>>(F(O_Etp), F(O_asum), cw, F(O_Ef));
    bn_stats_k<<<32, 256, 0, stream>>>(F(O_Ef), mv + 2816, 512, 2, 32L * 512);
    en_k<<<4, 256, 0, stream>>>(F(O_Ef), mv + 2816, gK, bK, F(O_en), 512);
    fc_k<<<dim3(2, 2), 256, 0, stream>>>(wfc, bfc, F(O_en), F(O_gam), 512, 512, 1);
    fc_k<<<dim3(1, 2), 256, 0, stream>>>(wse, bse, F(O_en), outp + 1228800, 150, 512, 0);
    ymul_h<<<16384, 256, 0, stream>>>(H(O_feath), F(O_gam), H(O_yh));

    // ---- Stage E: seg = w6 @ y + b6 -> d_out (CHW f32) ----
    hgemm_k<2><<<dim3(32, 2, 2), 256, 0, stream>>>(H(O_w6h), H(O_yh), outp, b6,
        150, 512, 4096, 512, 4096L * 512, 150L * 4096, 0, 0);
}

// Round 6
// 755.771 us; speedup vs baseline: 4.7031x; 1.2905x over previous
//
#include <hip/hip_runtime.h>
#include <math.h>

#define EPSBN 1e-5f

typedef _Float16 f16;
typedef _Float16 f16x8 __attribute__((ext_vector_type(8)));
typedef _Float16 f16x4 __attribute__((ext_vector_type(4)));
typedef float f32x4 __attribute__((ext_vector_type(4)));

static __device__ inline f16x8 h8zero() {
    f16x8 v;
#pragma unroll
    for (int j = 0; j < 8; j++) v[j] = (f16)0.f;
    return v;
}

// ---------------------------------------------------------------------------
// MFMA f16 GEMM, NHWC activations. D[m][n] = sum_k W[m][k] * act[n][k].
// BM=64, BN=128, BK=64. 4 waves (2x2), wave tile 32x64 (2x4 frags of 16x16).
// 2-phase pipeline: reg-stage tile t+1 global loads before MFMA of tile t,
// ds_write after, ONE barrier per tile.
// Swizzle discipline (rule #21): global SOURCE col is pre-swizzled in LOAD,
// LDS write is LINEAR, MFMA read applies the same XOR -> conflict-free b128.
// MODE 0: out f16 NHWC ([n][M]); MODE 1: conv3x3-d1 tap-shifted B (K=Cact*9,
// weight layout [O][tap][C]); MODE 2: out f32 CHW ([m][N]) + bias.
// ---------------------------------------------------------------------------
template<int MODE>
__global__ __launch_bounds__(256)
void hgemm_k(const f16* __restrict__ Wh, const f16* __restrict__ act,
             void* __restrict__ outv, const float* __restrict__ bias,
             int M, int K, int N, int Cact, long actStride, long outStride,
             int IW, int IH)
{
    const int b = blockIdx.z;
    const int n0 = blockIdx.x * 128, m0 = blockIdx.y * 64;
    const f16* actb = act + (long)b * actStride;
    __shared__ __align__(16) f16 As[2][64 * 64];
    __shared__ __align__(16) f16 Bs[2][128 * 64];
    const int tid = threadIdx.x;
    const int wave = tid >> 6, lane = tid & 63;
    const int wm = (wave >> 1) * 32, wn = (wave & 1) * 64;
    const int lr = lane & 15, lg = lane >> 4;
    f32x4 acc[2][4];
#pragma unroll
    for (int i = 0; i < 2; i++)
#pragma unroll
        for (int j = 0; j < 4; j++)
#pragma unroll
            for (int r = 0; r < 4; r++) acc[i][j][r] = 0.f;

    const int nt = K >> 6;
    f16x8 ra[2], rb[4];

    auto LOAD = [&](int t) {
        const int kt = t << 6;
#pragma unroll
        for (int u = 0; u < 2; u++) {
            int idx = u * 256 + tid;
            int row = idx >> 3, slot = idx & 7;
            int col = kt + ((slot ^ (row & 7)) << 3);   // pre-swizzled source
            int m = m0 + row;
            ra[u] = (m < M) ? *(const f16x8*)&Wh[(long)m * K + col] : h8zero();
        }
#pragma unroll
        for (int u = 0; u < 4; u++) {
            int idx = u * 256 + tid;
            int row = idx >> 3, slot = idx & 7;
            int scol = (slot ^ (row & 7)) << 3;         // pre-swizzled source
            int n = n0 + row;
            if (MODE == 1) {
                int tap = kt >> 9;
                int kc = (kt & 511) + scol;
                int dy = tap / 3 - 1, dx = tap % 3 - 1;
                int yy = n / IW + dy, xx = n % IW + dx;
                rb[u] = (yy >= 0 && yy < IH && xx >= 0 && xx < IW)
                        ? *(const f16x8*)&actb[(long)(yy * IW + xx) * Cact + kc]
                        : h8zero();
            } else {
                rb[u] = *(const f16x8*)&actb[(long)n * Cact + kt + scol];
            }
        }
    };
    auto WRITE = [&](int bufw) {
#pragma unroll
        for (int u = 0; u < 2; u++) {
            int idx = u * 256 + tid;
            int row = idx >> 3, slot = idx & 7;
            *(f16x8*)&As[bufw][(row * 8 + slot) * 8] = ra[u];   // LINEAR write
        }
#pragma unroll
        for (int u = 0; u < 4; u++) {
            int idx = u * 256 + tid;
            int row = idx >> 3, slot = idx & 7;
            *(f16x8*)&Bs[bufw][(row * 8 + slot) * 8] = rb[u];   // LINEAR write
        }
    };

    LOAD(0); WRITE(0); __syncthreads();
    int buf = 0;
    for (int t = 0; t < nt; t++) {
        if (t + 1 < nt) LOAD(t + 1);
#pragma unroll
        for (int s = 0; s < 2; s++) {
            f16x8 af[2], bf[4];
#pragma unroll
            for (int i = 0; i < 2; i++) {
                int r = wm + i * 16 + lr;
                af[i] = *(const f16x8*)&As[buf][(r * 8 + ((s * 4 + lg) ^ (r & 7))) * 8];
            }
#pragma unroll
            for (int j = 0; j < 4; j++) {
                int r = wn + j * 16 + lr;
                bf[j] = *(const f16x8*)&Bs[buf][(r * 8 + ((s * 4 + lg) ^ (r & 7))) * 8];
            }
#pragma unroll
            for (int i = 0; i < 2; i++)
#pragma unroll
                for (int j = 0; j < 4; j++)
                    acc[i][j] = __builtin_amdgcn_mfma_f32_16x16x32_f16(af[i], bf[j], acc[i][j], 0, 0, 0);
        }
        if (t + 1 < nt) WRITE(buf ^ 1);
        __syncthreads();
        buf ^= 1;
    }

    if (MODE == 2) {
        float* outp = (float*)outv + (long)b * outStride;
#pragma unroll
        for (int i = 0; i < 2; i++)
#pragma unroll
            for (int j = 0; j < 4; j++) {
                int n = n0 + wn + j * 16 + lr;
#pragma unroll
                for (int r = 0; r < 4; r++) {
                    int m = m0 + wm + i * 16 + lg * 4 + r;
                    if (m < M) outp[(long)m * N + n] = acc[i][j][r] + bias[m];
                }
            }
    } else {
        f16* outp = (f16*)outv + (long)b * outStride;
#pragma unroll
        for (int i = 0; i < 2; i++)
#pragma unroll
            for (int j = 0; j < 4; j++) {
                int n = n0 + wn + j * 16 + lr;
                int mb = m0 + wm + i * 16 + lg * 4;
                if (mb < M) {
                    f16x4 hv;
#pragma unroll
                    for (int r = 0; r < 4; r++) hv[r] = (f16)acc[i][j][r];
                    *(f16x4*)&outp[(long)n * M + mb] = hv;
                }
            }
    }
}

// CHW f32 -> NHWC f16 tiled transpose (C, HW multiples of 32)
__global__ __launch_bounds__(256)
void chw2nhwc_k(const float* __restrict__ in, f16* __restrict__ out, int C, int HW)
{
    int b = blockIdx.z;
    int l0 = blockIdx.x * 32, c0 = blockIdx.y * 32;
    __shared__ float t[32][33];
    int tx = threadIdx.x & 31, ty = threadIdx.x >> 5;
    const float* ib = in + (long)b * C * HW;
#pragma unroll
    for (int j = 0; j < 4; j++) {
        int c = c0 + ty + j * 8;
        t[ty + j * 8][tx] = ib[(long)c * HW + l0 + tx];
    }
    __syncthreads();
    f16* ob = out + (long)b * HW * C;
#pragma unroll
    for (int j = 0; j < 4; j++) {
        int l = l0 + ty + j * 8;
        ob[(long)l * C + c0 + tx] = (f16)t[tx][ty + j * 8];
    }
}

// flat f32 -> f16
__global__ void f2h_k(const float* __restrict__ src, f16* __restrict__ dst, long n)
{
    long i = blockIdx.x * 256L + threadIdx.x;
    if (i < n) dst[i] = (f16)src[i];
}

// w5 (O,C,3,3) f32 -> w5r[O][tap][C] f16  (K ordered taps-outer, c-inner)
__global__ void w5r_k(const float* __restrict__ src, f16* __restrict__ dst)
{
    long i = blockIdx.x * 256L + threadIdx.x;
    if (i >= 9L * 512 * 512) return;
    int c = (int)(i % 512); long t2 = i / 512;
    int t = (int)(t2 % 9); int o = (int)(t2 / 9);
    dst[i] = (f16)src[(long)o * 4608 + c * 9 + t];
}

__global__ void zero_k(float* __restrict__ p, int n)
{
    int i = blockIdx.x * 256 + threadIdx.x;
    if (i < n) p[i] = 0.f;
}

// atomic column sums over NHWC rows: sums[2c] += x, sums[2c+1] += x^2
__global__ __launch_bounds__(256)
void bnsum_k(const f16* __restrict__ x, float* __restrict__ sums, int C, long rows)
{
    int CB = C < 256 ? C : 256;
    int RT = 256 / CB;
    int c = blockIdx.x * 256 + (threadIdx.x % CB);
    int rg = threadIdx.x / CB;
    float s = 0.f, s2 = 0.f;
    for (long r = (long)blockIdx.y * RT + rg; r < rows; r += 64L * RT) {
        float v = (float)x[r * C + c];
        s += v; s2 += v * v;
    }
    atomicAdd(&sums[2 * c], s);
    atomicAdd(&sums[2 * c + 1], s2);
}

// apply BN (from raw sums) elementwise, f16 in/out, 8 elems/thread
__global__ __launch_bounds__(256)
void bnapply_k(f16* __restrict__ x, const float* __restrict__ mv,
               const float* __restrict__ g, const float* __restrict__ bta,
               int C, long total, float inv, int dorelu)
{
    long i8 = (blockIdx.x * 256L + threadIdx.x) * 8;
    if (i8 >= total) return;
    int c0 = (int)(i8 % C);
    f16x8 v = *(f16x8*)&x[i8];
#pragma unroll
    for (int j = 0; j < 8; j++) {
        int c = c0 + j;
        float m = mv[2 * c] * inv;
        float var = mv[2 * c + 1] * inv - m * m;
        float r = ((float)v[j] - m) * rsqrtf(var + EPSBN) * g[c] + bta[c];
        if (dorelu) r = fmaxf(r, 0.f);
        v[j] = (f16)r;
    }
    *(f16x8*)&x[i8] = v;
}

// bilinear upsample align_corners=True, NHWC f16
__global__ __launch_bounds__(256)
void upsample_h(const f16* __restrict__ in, f16* __restrict__ out,
                int C, int H, int W, int OH, int OW)
{
    long total = 2L * C * OH * OW;
    float ry = (float)(H - 1) / (float)(OH - 1);
    float rx = (float)(W - 1) / (float)(OW - 1);
    for (long i = blockIdx.x * 256L + threadIdx.x; i < total; i += (long)gridDim.x * 256) {
        int c = (int)(i % C); long t = i / C;
        int l = (int)(t % (OH * OW)); int bb = (int)(t / (OH * OW));
        int oy = l / OW, ox = l % OW;
        float fy = oy * ry, fx = ox * rx;
        int y0 = (int)fy, x0 = (int)fx;
        int y1 = min(y0 + 1, H - 1), x1 = min(x0 + 1, W - 1);
        float wy = fy - y0, wx = fx - x0;
        const f16* p = in + (long)bb * H * W * C + c;
        float v00 = (float)p[(long)(y0 * W + x0) * C];
        float v01 = (float)p[(long)(y0 * W + x1) * C];
        float v10 = (float)p[(long)(y1 * W + x0) * C];
        float v11 = (float)p[(long)(y1 * W + x1) * C];
        out[i] = (f16)((v00 * (1.f - wx) + v01 * wx) * (1.f - wy) +
                       (v10 * (1.f - wx) + v11 * wx) * wy);
    }
}

// energy + softmax over 9 dilated-2 taps (NHWC f16 q/k) -> att f32 (n,l,9)
__global__ __launch_bounds__(256)
void att_h(const f16* __restrict__ q, const f16* __restrict__ k,
           float* __restrict__ att, int C, int H, int W)
{
    int HW = H * W;
    int l = blockIdx.x * 256 + threadIdx.x;
    int n = blockIdx.y;
    if (l >= HW) return;
    int y = l / W, x = l % W;
    int offs[9]; bool val[9];
#pragma unroll
    for (int t = 0; t < 9; t++) {
        int a = t / 3, bj = t % 3;
        int yy = y + 2 * a - 2, xx = x + 2 * bj - 2;
        val[t] = (yy >= 0 && yy < H && xx >= 0 && xx < W);
        offs[t] = val[t] ? yy * W + xx : 0;
    }
    float e[9] = {0.f, 0.f, 0.f, 0.f, 0.f, 0.f, 0.f, 0.f, 0.f};
    const f16* qr = q + ((long)n * HW + l) * C;
    const f16* kb = k + (long)n * HW * C;
    for (int c = 0; c < C; c += 8) {
        f16x8 qv = *(const f16x8*)&qr[c];
        float qf[8];
#pragma unroll
        for (int j = 0; j < 8; j++) qf[j] = (float)qv[j];
#pragma unroll
        for (int t = 0; t < 9; t++) {
            if (!val[t]) continue;
            f16x8 kv = *(const f16x8*)&kb[(long)offs[t] * C + c];
#pragma unroll
            for (int j = 0; j < 8; j++) e[t] = fmaf(qf[j], (float)kv[j], e[t]);
        }
    }
    float mx = e[0];
#pragma unroll
    for (int t = 1; t < 9; t++) mx = fmaxf(mx, e[t]);
    float s = 0.f; float ex[9];
#pragma unroll
    for (int t = 0; t < 9; t++) { ex[t] = expf(e[t] - mx); s += ex[t]; }
    float inv = 1.f / s;
    long base = ((long)n * HW + l) * 9;
#pragma unroll
    for (int t = 0; t < 9; t++) att[base + t] = ex[t] * inv;
}

// out[b,l,c] = sum_t att * v[neigh] (NHWC f16)
__global__ __launch_bounds__(256)
void attout_h(const float* __restrict__ att, const f16* __restrict__ v,
              f16* __restrict__ out, int C, int H, int W)
{
    int HW = H * W;
    long total = 2L * HW * C;
    for (long i = blockIdx.x * 256L + threadIdx.x; i < total; i += (long)gridDim.x * 256) {
        int c = (int)(i % C); long t2 = i / C;
        int l = (int)(t2 % HW); int bb = (int)(t2 / HW);
        int y = l / W, x = l % W;
        long abase = ((long)bb * HW + l) * 9;
        const f16* vb = v + (long)bb * HW * C + c;
        float s = 0.f;
#pragma unroll
        for (int t = 0; t < 9; t++) {
            int aa = t / 3, bj = t % 3;
            int yy = y + 2 * aa - 2, xx = x + 2 * bj - 2;
            if (yy >= 0 && yy < H && xx >= 0 && xx < W)
                s = fmaf(att[abase + t], (float)vb[(long)(yy * W + xx) * C], s);
        }
        out[i] = (f16)s;
    }
}

// codeword squared norms
__global__ void cc_k(const float* __restrict__ cw, float* __restrict__ cc, int D)
{
    int k = threadIdx.x;
    if (k < 32) {
        float s = 0.f;
        for (int d = 0; d < D; d++) { float v = cw[(long)k * D + d]; s += v * v; }
        cc[k] = s;
    }
}

// soft-assign: x f16 NHWC, xc f16 [l][32] -> A f32 [l][32]
__global__ __launch_bounds__(256)
void assign_h(const f16* __restrict__ x, const f16* __restrict__ xc,
              const float* __restrict__ cc, const float* __restrict__ scale,
              float* __restrict__ A)
{
    int l = blockIdx.x * 256 + threadIdx.x;
    int bb = blockIdx.y;
    if (l >= 4096) return;
    const f16* xr = x + ((long)bb * 4096 + l) * 512;
    float xx = 0.f;
    for (int d = 0; d < 512; d += 8) {
        f16x8 v = *(const f16x8*)&xr[d];
#pragma unroll
        for (int j = 0; j < 8; j++) { float f = (float)v[j]; xx = fmaf(f, f, xx); }
    }
    const f16* xcr = xc + ((long)bb * 4096 + l) * 32;
    float e[32]; float mx = -1e30f;
#pragma unroll
    for (int k2 = 0; k2 < 32; k2++) {
        float dist = xx + cc[k2] - 2.f * (float)xcr[k2];
        float en = -scale[k2] * dist;
        e[k2] = en; mx = fmaxf(mx, en);
    }
    float s = 0.f;
#pragma unroll
    for (int k2 = 0; k2 < 32; k2++) { e[k2] = expf(e[k2] - mx); s += e[k2]; }
    float inv = 1.f / s;
    long base = ((long)bb * 4096 + l) * 32;
#pragma unroll
    for (int k2 = 0; k2 < 32; k2++) A[base + k2] = e[k2] * inv;
}

__global__ __launch_bounds__(256)
void asum_k(const float* __restrict__ A, float* __restrict__ Asum, int HW)
{
    int k2 = blockIdx.x, b = blockIdx.y;
    float s = 0.f;
    for (int l = threadIdx.x; l < HW; l += 256) s += A[((long)b * HW + l) * 32 + k2];
    __shared__ float sh[256];
    sh[threadIdx.x] = s;
    __syncthreads();
    for (int o = 128; o > 0; o >>= 1) {
        if (threadIdx.x < o) sh[threadIdx.x] += sh[threadIdx.x + o];
        __syncthreads();
    }
    if (threadIdx.x == 0) Asum[b * 32 + k2] = sh[0];
}

// Et partial GEMM: Etp[z][k2][d] = sum_{l in chunk} A[l][k2] * X[l][d], z = b*16+chunk
__global__ __launch_bounds__(256)
void etg_k(const float* __restrict__ Af, const f16* __restrict__ Xh, float* __restrict__ Etp)
{
    int z = blockIdx.z; int b = z >> 4; int ch = z & 15;
    int kbase = ch * 256;
    const float* Ab = Af + (long)b * 4096 * 32;
    const f16* Xb = Xh + (long)b * 4096 * 512;
    int n0 = blockIdx.x * 64;
    __shared__ float As[16][65];
    __shared__ float Bs[16][64];
    int tid = threadIdx.x; int tx = tid & 15, ty = tid >> 4;
    float acc[4][4];
#pragma unroll
    for (int i = 0; i < 4; i++)
#pragma unroll
        for (int j = 0; j < 4; j++) acc[i][j] = 0.f;
    for (int k0 = 0; k0 < 256; k0 += 16) {
#pragma unroll
        for (int i = 0; i < 4; i++) {
            int idx = tid + i * 256;
            int kk = idx & 15, mm = idx >> 4;
            float vv = 0.f;
            if (mm < 32) vv = Ab[(long)(kbase + k0 + kk) * 32 + mm];
            As[kk][mm] = vv;
        }
#pragma unroll
        for (int i = 0; i < 4; i++) {
            int idx = tid + i * 256;
            int nn = idx & 63, kk = idx >> 6;
            Bs[kk][nn] = (float)Xb[(long)(kbase + k0 + kk) * 512 + n0 + nn];
        }
        __syncthreads();
#pragma unroll
        for (int kk = 0; kk < 16; kk++) {
            float a[4], bb2[4];
#pragma unroll
            for (int i = 0; i < 4; i++) a[i] = As[kk][ty + i * 16];
#pragma unroll
            for (int j = 0; j < 4; j++) bb2[j] = Bs[kk][tx + j * 16];
#pragma unroll
            for (int i = 0; i < 4; i++)
#pragma unroll
                for (int j = 0; j < 4; j++)
                    acc[i][j] = fmaf(a[i], bb2[j], acc[i][j]);
        }
        __syncthreads();
    }
    float* Ob = Etp + (long)z * 32 * 512;
#pragma unroll
    for (int i = 0; i < 4; i++) {
        int m = ty + i * 16;
        if (m >= 32) continue;
#pragma unroll
        for (int j = 0; j < 4; j++) Ob[(long)m * 512 + n0 + tx + j * 16] = acc[i][j];
    }
}

// E[b,k,d] = sum_chunks Etp - Asum*cw
__global__ void efix2_k(const float* __restrict__ Etp, const float* __restrict__ asumf,
                        const float* __restrict__ cwf, float* __restrict__ Ef)
{
    int i = blockIdx.x * 256 + threadIdx.x;
    if (i >= 2 * 32 * 512) return;
    int d = i % 512; int k2 = (i / 512) % 32; int bb = i / (512 * 32);
    float s = 0.f;
#pragma unroll
    for (int c2 = 0; c2 < 16; c2++) s += Etp[((long)(bb * 16 + c2) * 32 + k2) * 512 + d];
    Ef[i] = s - asumf[bb * 32 + k2] * cwf[k2 * 512 + d];
}

// BN stats (mean/var) over (n,spatial) per channel, f32 input (for E)
__global__ __launch_bounds__(256)
void bn_stats_k(const float* __restrict__ x, float* __restrict__ mv,
                int HW, int Nb, long strideN)
{
    int c = blockIdx.x;
    long total = (long)Nb * HW;
    float s = 0.f, s2 = 0.f;
    for (long i = threadIdx.x; i < total; i += 256) {
        int n = (int)(i / HW); int l = (int)(i % HW);
        float v = x[(long)n * strideN + (long)c * HW + l];
        s += v; s2 += v * v;
    }
    __shared__ float sh0[256], sh1[256];
    sh0[threadIdx.x] = s; sh1[threadIdx.x] = s2;
    __syncthreads();
    for (int o = 128; o > 0; o >>= 1) {
        if (threadIdx.x < o) { sh0[threadIdx.x] += sh0[threadIdx.x + o]; sh1[threadIdx.x] += sh1[threadIdx.x + o]; }
        __syncthreads();
    }
    if (threadIdx.x == 0) {
        float inv = 1.f / (float)total;
        float m = sh0[0] * inv;
        mv[2 * c] = m;
        mv[2 * c + 1] = sh1[0] * inv - m * m;
    }
}

// en[b,d] = mean_k relu(BN1d(E[b,k,d]))
__global__ __launch_bounds__(256)
void en_k(const float* __restrict__ E, const float* __restrict__ mv,
          const float* __restrict__ gK, const float* __restrict__ bK,
          float* __restrict__ en, int D)
{
    int i = blockIdx.x * 256 + threadIdx.x;
    if (i >= 2 * D) return;
    int b = i / D, d = i % D;
    float s = 0.f;
#pragma unroll
    for (int k2 = 0; k2 < 32; k2++) {
        float m = mv[2 * k2], vv = mv[2 * k2 + 1];
        float r = (E[((long)b * 32 + k2) * D + d] - m) * rsqrtf(vv + EPSBN) * gK[k2] + bK[k2];
        s += fmaxf(r, 0.f);
    }
    en[i] = s * (1.f / 32.f);
}

__global__ __launch_bounds__(256)
void fc_k(const float* __restrict__ W, const float* __restrict__ bias,
          const float* __restrict__ in, float* __restrict__ out,
          int O, int D, int mode)
{
    int o = blockIdx.x * 256 + threadIdx.x;
    int b = blockIdx.y;
    if (o >= O) return;
    const float* ib = in + (long)b * D;
    float s = bias[o];
    for (int d = 0; d < D; d++) s += W[(long)o * D + d] * ib[d];
    if (mode == 1) s = 1.f / (1.f + expf(-s));
    out[(long)b * O + o] = s;
}

// y = relu(feat * (1+gamma)), f16 NHWC
__global__ __launch_bounds__(256)
void ymul_h(const f16* __restrict__ feat, const float* __restrict__ gamma,
            f16* __restrict__ y)
{
    long total = 2L * 4096 * 512;
    for (long i = blockIdx.x * 256L + threadIdx.x; i < total; i += (long)gridDim.x * 256) {
        int c = (int)(i % 512);
        int bb = (int)(i / (4096L * 512));
        y[i] = (f16)fmaxf((float)feat[i] * (1.f + gamma[bb * 512 + c]), 0.f);
    }
}

static inline dim3 hgrid(int M, int N) { return dim3((N + 127) / 128, (M + 63) / 64, 2); }

extern "C" void kernel_launch(void* const* d_in, const int* in_sizes, int n_in,
                              void* d_out, int out_size, void* d_ws, size_t ws_size,
                              hipStream_t stream)
{
    (void)in_sizes; (void)n_in; (void)out_size; (void)ws_size;
    const float* c2  = (const float*)d_in[1];
    const float* c3  = (const float*)d_in[2];
    const float* c4  = (const float*)d_in[3];
    const float* wq4 = (const float*)d_in[7];
    const float* gq4 = (const float*)d_in[8];
    const float* bq4 = (const float*)d_in[9];
    const float* wk4 = (const float*)d_in[10];
    const float* gk4 = (const float*)d_in[11];
    const float* bk4 = (const float*)d_in[12];
    const float* wv4 = (const float*)d_in[13];
    const float* wq3 = (const float*)d_in[14];
    const float* gq3 = (const float*)d_in[15];
    const float* bq3 = (const float*)d_in[16];
    const float* wk3 = (const float*)d_in[17];
    const float* gk3 = (const float*)d_in[18];
    const float* bk3 = (const float*)d_in[19];
    const float* wv3 = (const float*)d_in[20];
    const float* w5  = (const float*)d_in[21];
    const float* g5  = (const float*)d_in[22];
    const float* b5  = (const float*)d_in[23];
    const float* we  = (const float*)d_in[24];
    const float* ge  = (const float*)d_in[25];
    const float* be  = (const float*)d_in[26];
    const float* cw  = (const float*)d_in[27];
    const float* scl = (const float*)d_in[28];
    const float* gK  = (const float*)d_in[29];
    const float* bK  = (const float*)d_in[30];
    const float* wfc = (const float*)d_in[31];
    const float* bfc = (const float*)d_in[32];
    const float* wse = (const float*)d_in[33];
    const float* bse = (const float*)d_in[34];
    const float* w6  = (const float*)d_in[35];
    const float* b6  = (const float*)d_in[36];
    float* outp = (float*)d_out;
    char* ws = (char*)d_ws;

    // ---- workspace (byte offsets), liveness-checked overlays ----
    auto H = [&](long off) { return (f16*)(ws + off); };
    auto F = [&](long off) { return (float*)(ws + off); };
    const long O_wq4h = 0;         // 262144
    const long O_wk4h = 262144;    // 524288
    const long O_wv4h = 786432;    // 4194304
    const long O_wq3h = 4980736;   // 65536
    const long O_wk3h = 5046272;   // 131072
    const long O_wv3h = 5177344;   // 1048576
    const long O_w5r  = 6225920;   // 4718592
    const long O_weh  = 10944512;  // 524288
    const long O_cwh  = 11468800;  // 32768
    const long O_w6h  = 11501568;  // 153600 -> 11655168
    const long O_c3h  = 11665408;  // 4.19MB [dead after q4 gemm]
    const long O_Xh   = 11665408;  // 8.39MB (reuses c3h; created post-conv)
    const long O_c4h  = 20054016;  // 2.1MB [dead after upsample4]
    const long O_cku4h= 22151168;  // 8.39MB [dead after v4 gemm]
    const long O_v3h  = 22151168;  // 8.39MB (reuses cku4h; created at v3 gemm)
    const long O_q4h  = 30539776;  // 524288
    const long O_k4h  = 31064064;  // 524288
    const long O_v4h  = 31588352;  // 4.19MB [dead after attout4]
    // stage-B/D smalls reuse q4h/k4h/v4h region after stage A:
    const long O_att3 = 30539776;  // 294912 f32
    const long O_xch  = 30834688;  // 524288 f16
    const long O_Af   = 31358976;  // 1048576 f32
    const long O_Etp  = 32407552;  // 2097152 f32
    const long O_Ef   = 34504704;  // 131072 f32
    const long O_asum = 34635776;  // 256
    const long O_cc   = 34636032;  // 128
    const long O_en   = 34636160;  // 4096
    const long O_gam  = 34640256;  // 4096
    const long O_mv   = 34644352;  // 11520 (2880 floats)
    const long O_att4 = 35782656;  // 73728 f32
    const long O_out4h= 35856384;  // 4.19MB [dead after upsample3]
    const long O_yh   = 35856384;  // 8.39MB (reuses out4h+c2h-head; created at ymul)
    const long O_c2h  = 40050688;  // 8.39MB [dead after q3 gemm]
    const long O_cku3h= 48439296;  // 16.78MB [dead after v3 gemm]
    const long O_feath= 48439296;  // 8.39MB (reuses cku3h; created at conv)
    const long O_out3h= 56827904;  // 8.39MB (reuses cku3h tail; created attout3, dead post conv)
    const long O_q3h  = 65216512;  // 1048576
    const long O_k3h  = 66265088;  // 1048576 -> end 67313664 (~67.3MB)

    float* mv = F(O_mv);

    // ---- conversions ----
    chw2nhwc_k<<<dim3(128, 16, 2), 256, 0, stream>>>(c2, H(O_c2h), 512, 4096);
    chw2nhwc_k<<<dim3(32, 32, 2), 256, 0, stream>>>(c3, H(O_c3h), 1024, 1024);
    chw2nhwc_k<<<dim3(8, 64, 2), 256, 0, stream>>>(c4, H(O_c4h), 2048, 256);
    auto cvt = [&](const float* s, long o, long n) {
        f2h_k<<<(int)((n + 255) / 256), 256, 0, stream>>>(s, H(o), n);
    };
    cvt(wq4, O_wq4h, 128L * 1024); cvt(wk4, O_wk4h, 128L * 2048);
    cvt(wv4, O_wv4h, 1024L * 2048); cvt(wq3, O_wq3h, 64L * 512);
    cvt(wk3, O_wk3h, 64L * 1024); cvt(wv3, O_wv3h, 512L * 1024);
    cvt(we, O_weh, 512L * 512); cvt(cw, O_cwh, 32L * 512);
    cvt(w6, O_w6h, 150L * 512);
    w5r_k<<<9216, 256, 0, stream>>>(w5, H(O_w5r));
    zero_k<<<11, 256, 0, stream>>>(mv, 2816);

    // ---- Stage A: local_up(c3, c4) -> out4h (NHWC 2x1024x1024) ----
    hgemm_k<0><<<hgrid(128, 1024), 256, 0, stream>>>(H(O_wq4h), H(O_c3h), H(O_q4h), nullptr,
        128, 1024, 1024, 1024, 1024L * 1024, 1024L * 128, 0, 0);
    bnsum_k<<<dim3(1, 64), 256, 0, stream>>>(H(O_q4h), mv + 0, 128, 2048);
    bnapply_k<<<128, 256, 0, stream>>>(H(O_q4h), mv + 0, gq4, bq4, 128, 2L * 1024 * 128, 1.f / 2048.f, 0);
    upsample_h<<<16384, 256, 0, stream>>>(H(O_c4h), H(O_cku4h), 2048, 16, 16, 32, 32);
    hgemm_k<0><<<hgrid(128, 1024), 256, 0, stream>>>(H(O_wk4h), H(O_cku4h), H(O_k4h), nullptr,
        128, 2048, 1024, 2048, 1024L * 2048, 1024L * 128, 0, 0);
    bnsum_k<<<dim3(1, 64), 256, 0, stream>>>(H(O_k4h), mv + 256, 128, 2048);
    bnapply_k<<<128, 256, 0, stream>>>(H(O_k4h), mv + 256, gk4, bk4, 128, 2L * 1024 * 128, 1.f / 2048.f, 0);
    hgemm_k<0><<<hgrid(1024, 1024), 256, 0, stream>>>(H(O_wv4h), H(O_cku4h), H(O_v4h), nullptr,
        1024, 2048, 1024, 2048, 1024L * 2048, 1024L * 1024, 0, 0);
    att_h<<<dim3(4, 2), 256, 0, stream>>>(H(O_q4h), H(O_k4h), F(O_att4), 128, 32, 32);
    attout_h<<<8192, 256, 0, stream>>>(F(O_att4), H(O_v4h), H(O_out4h), 1024, 32, 32);

    // ---- Stage B: local_up(c2, out4) -> out3h (NHWC 2x4096x512) ----
    hgemm_k<0><<<hgrid(64, 4096), 256, 0, stream>>>(H(O_wq3h), H(O_c2h), H(O_q3h), nullptr,
        64, 512, 4096, 512, 4096L * 512, 4096L * 64, 0, 0);
    bnsum_k<<<dim3(1, 64), 256, 0, stream>>>(H(O_q3h), mv + 512, 64, 8192);
    bnapply_k<<<256, 256, 0, stream>>>(H(O_q3h), mv + 512, gq3, bq3, 64, 2L * 4096 * 64, 1.f / 8192.f, 0);
    upsample_h<<<32768, 256, 0, stream>>>(H(O_out4h), H(O_cku3h), 1024, 32, 32, 64, 64);
    hgemm_k<0><<<hgrid(64, 4096), 256, 0, stream>>>(H(O_wk3h), H(O_cku3h), H(O_k3h), nullptr,
        64, 1024, 4096, 1024, 4096L * 1024, 4096L * 64, 0, 0);
    bnsum_k<<<dim3(1, 64), 256, 0, stream>>>(H(O_k3h), mv + 640, 64, 8192);
    bnapply_k<<<256, 256, 0, stream>>>(H(O_k3h), mv + 640, gk3, bk3, 64, 2L * 4096 * 64, 1.f / 8192.f, 0);
    hgemm_k<0><<<hgrid(512, 4096), 256, 0, stream>>>(H(O_wv3h), H(O_cku3h), H(O_v3h), nullptr,
        512, 1024, 4096, 1024, 4096L * 1024, 4096L * 512, 0, 0);
    att_h<<<dim3(16, 2), 256, 0, stream>>>(H(O_q3h), H(O_k3h), F(O_att3), 64, 64, 64);
    attout_h<<<16384, 256, 0, stream>>>(F(O_att3), H(O_v3h), H(O_out3h), 512, 64, 64);

    // ---- Stage C: feat = relu(BN(conv3x3(out3))) — single K=4608 MFMA GEMM ----
    hgemm_k<1><<<hgrid(512, 4096), 256, 0, stream>>>(H(O_w5r), H(O_out3h), H(O_feath), nullptr,
        512, 4608, 4096, 512, 4096L * 512, 4096L * 512, 64, 64);
    bnsum_k<<<dim3(2, 64), 256, 0, stream>>>(H(O_feath), mv + 768, 512, 8192);
    bnapply_k<<<2048, 256, 0, stream>>>(H(O_feath), mv + 768, g5, b5, 512, 2L * 4096 * 512, 1.f / 8192.f, 1);

    // ---- Stage D: enc_module ----
    hgemm_k<0><<<hgrid(512, 4096), 256, 0, stream>>>(H(O_weh), H(O_feath), H(O_Xh), nullptr,
        512, 512, 4096, 512, 4096L * 512, 4096L * 512, 0, 0);
    bnsum_k<<<dim3(2, 64), 256, 0, stream>>>(H(O_Xh), mv + 1792, 512, 8192);
    bnapply_k<<<2048, 256, 0, stream>>>(H(O_Xh), mv + 1792, ge, be, 512, 2L * 4096 * 512, 1.f / 8192.f, 1);
    hgemm_k<0><<<hgrid(32, 4096), 256, 0, stream>>>(H(O_cwh), H(O_Xh), H(O_xch), nullptr,
        32, 512, 4096, 512, 4096L * 512, 4096L * 32, 0, 0);
    cc_k<<<1, 32, 0, stream>>>(cw, F(O_cc), 512);
    assign_h<<<dim3(16, 2), 256, 0, stream>>>(H(O_Xh), H(O_xch), F(O_cc), scl, F(O_Af));
    asum_k<<<dim3(32, 2), 256, 0, stream>>>(F(O_Af), F(O_asum), 4096);
    etg_k<<<dim3(8, 1, 32), 256, 0, stream>>>(F(O_Af), H(O_Xh), F(O_Etp));
    efix2_k<<<128, 256, 0, stream>>>(F(O_Etp), F(O_asum), cw, F(O_Ef));
    bn_stats_k<<<32, 256, 0, stream>>>(F(O_Ef), mv + 2816, 512, 2, 32L * 512);
    en_k<<<4, 256, 0, stream>>>(F(O_Ef), mv + 2816, gK, bK, F(O_en), 512);
    fc_k<<<dim3(2, 2), 256, 0, stream>>>(wfc, bfc, F(O_en), F(O_gam), 512, 512, 1);
    fc_k<<<dim3(1, 2), 256, 0, stream>>>(wse, bse, F(O_en), outp + 1228800, 150, 512, 0);
    ymul_h<<<16384, 256, 0, stream>>>(H(O_feath), F(O_gam), H(O_yh));

    // ---- Stage E: seg = w6 @ y + b6 -> d_out (CHW f32) ----
    hgemm_k<2><<<hgrid(150, 4096), 256, 0, stream>>>(H(O_w6h), H(O_yh), outp, b6,
        150, 512, 4096, 512, 4096L * 512, 150L * 4096, 0, 0);
}

// Round 9
// 720.187 us; speedup vs baseline: 4.9355x; 1.0494x over previous
//
#include <hip/hip_runtime.h>
#include <math.h>

#define EPSBN 1e-5f

typedef _Float16 f16;
typedef _Float16 f16x8 __attribute__((ext_vector_type(8)));
typedef _Float16 f16x4 __attribute__((ext_vector_type(4)));
typedef float f32x4 __attribute__((ext_vector_type(4)));

static __device__ inline f16x8 h8zero() {
    f16x8 v;
#pragma unroll
    for (int j = 0; j < 8; j++) v[j] = (f16)0.f;
    return v;
}

// ---------------------------------------------------------------------------
// MFMA f16 GEMM, NHWC activations. D[m][n] = sum_k W[m][k] * act[n][k].
// BM=64, BN=128, BK=64. 4 waves (2x2), wave tile 32x64. 2-phase pipeline,
// pre-swizzled global source + linear LDS write + swizzled read.
// Optional fused BN column sums (sums != nullptr): sums[2m]+=x, sums[2m+1]+=x^2.
// MODE 0: out f16 NHWC ([n][M]); MODE 1: conv3x3-d1 tap-shifted B; MODE 2:
// out f32 CHW ([m][N]) + bias.
// ---------------------------------------------------------------------------
template<int MODE>
__global__ __launch_bounds__(256)
void hgemm_k(const f16* __restrict__ Wh, const f16* __restrict__ act,
             void* __restrict__ outv, const float* __restrict__ bias,
             int M, int K, int N, int Cact, long actStride, long outStride,
             int IW, int IH, float* __restrict__ sums)
{
    const int b = blockIdx.z;
    const int n0 = blockIdx.x * 128, m0 = blockIdx.y * 64;
    const f16* actb = act + (long)b * actStride;
    __shared__ __align__(16) f16 As[2][64 * 64];
    __shared__ __align__(16) f16 Bs[2][128 * 64];
    const int tid = threadIdx.x;
    const int wave = tid >> 6, lane = tid & 63;
    const int wm = (wave >> 1) * 32, wn = (wave & 1) * 64;
    const int lr = lane & 15, lg = lane >> 4;
    f32x4 acc[2][4];
#pragma unroll
    for (int i = 0; i < 2; i++)
#pragma unroll
        for (int j = 0; j < 4; j++)
#pragma unroll
            for (int r = 0; r < 4; r++) acc[i][j][r] = 0.f;

    const int nt = K >> 6;
    f16x8 ra[2], rb[4];

    auto LOAD = [&](int t) {
        const int kt = t << 6;
#pragma unroll
        for (int u = 0; u < 2; u++) {
            int idx = u * 256 + tid;
            int row = idx >> 3, slot = idx & 7;
            int col = kt + ((slot ^ (row & 7)) << 3);   // pre-swizzled source
            int m = m0 + row;
            ra[u] = (m < M) ? *(const f16x8*)&Wh[(long)m * K + col] : h8zero();
        }
#pragma unroll
        for (int u = 0; u < 4; u++) {
            int idx = u * 256 + tid;
            int row = idx >> 3, slot = idx & 7;
            int scol = (slot ^ (row & 7)) << 3;         // pre-swizzled source
            int n = n0 + row;
            if (MODE == 1) {
                int tap = kt >> 9;
                int kc = (kt & 511) + scol;
                int dy = tap / 3 - 1, dx = tap % 3 - 1;
                int yy = n / IW + dy, xx = n % IW + dx;
                rb[u] = (yy >= 0 && yy < IH && xx >= 0 && xx < IW)
                        ? *(const f16x8*)&actb[(long)(yy * IW + xx) * Cact + kc]
                        : h8zero();
            } else {
                rb[u] = *(const f16x8*)&actb[(long)n * Cact + kt + scol];
            }
        }
    };
    auto WRITE = [&](int bufw) {
#pragma unroll
        for (int u = 0; u < 2; u++) {
            int idx = u * 256 + tid;
            int row = idx >> 3, slot = idx & 7;
            *(f16x8*)&As[bufw][(row * 8 + slot) * 8] = ra[u];   // LINEAR write
        }
#pragma unroll
        for (int u = 0; u < 4; u++) {
            int idx = u * 256 + tid;
            int row = idx >> 3, slot = idx & 7;
            *(f16x8*)&Bs[bufw][(row * 8 + slot) * 8] = rb[u];   // LINEAR write
        }
    };

    LOAD(0); WRITE(0); __syncthreads();
    int buf = 0;
    for (int t = 0; t < nt; t++) {
        if (t + 1 < nt) LOAD(t + 1);
#pragma unroll
        for (int s = 0; s < 2; s++) {
            f16x8 af[2], bf[4];
#pragma unroll
            for (int i = 0; i < 2; i++) {
                int r = wm + i * 16 + lr;
                af[i] = *(const f16x8*)&As[buf][(r * 8 + ((s * 4 + lg) ^ (r & 7))) * 8];
            }
#pragma unroll
            for (int j = 0; j < 4; j++) {
                int r = wn + j * 16 + lr;
                bf[j] = *(const f16x8*)&Bs[buf][(r * 8 + ((s * 4 + lg) ^ (r & 7))) * 8];
            }
#pragma unroll
            for (int i = 0; i < 2; i++)
#pragma unroll
                for (int j = 0; j < 4; j++)
                    acc[i][j] = __builtin_amdgcn_mfma_f32_16x16x32_f16(af[i], bf[j], acc[i][j], 0, 0, 0);
        }
        if (t + 1 < nt) WRITE(buf ^ 1);
        __syncthreads();
        buf ^= 1;
    }

    if (MODE == 2) {
        float* outp = (float*)outv + (long)b * outStride;
#pragma unroll
        for (int i = 0; i < 2; i++)
#pragma unroll
            for (int j = 0; j < 4; j++) {
                int n = n0 + wn + j * 16 + lr;
#pragma unroll
                for (int r = 0; r < 4; r++) {
                    int m = m0 + wm + i * 16 + lg * 4 + r;
                    if (m < M) outp[(long)m * N + n] = acc[i][j][r] + bias[m];
                }
            }
    } else {
        f16* outp = (f16*)outv + (long)b * outStride;
#pragma unroll
        for (int i = 0; i < 2; i++)
#pragma unroll
            for (int j = 0; j < 4; j++) {
                int n = n0 + wn + j * 16 + lr;
                int mb = m0 + wm + i * 16 + lg * 4;
                if (mb < M) {
                    f16x4 hv;
#pragma unroll
                    for (int r = 0; r < 4; r++) hv[r] = (f16)acc[i][j][r];
                    *(f16x4*)&outp[(long)n * M + mb] = hv;
                }
            }
        if (sums) {
#pragma unroll
            for (int i = 0; i < 2; i++)
#pragma unroll
                for (int r = 0; r < 4; r++) {
                    int m = m0 + wm + i * 16 + lg * 4 + r;
                    float s = 0.f, s2 = 0.f;
#pragma unroll
                    for (int j = 0; j < 4; j++) {
                        float v = (float)(f16)acc[i][j][r];   // rounded value
                        s += v; s2 += v * v;
                    }
#pragma unroll
                    for (int msk = 1; msk < 16; msk <<= 1) {
                        s += __shfl_xor(s, msk);
                        s2 += __shfl_xor(s2, msk);
                    }
                    if (lr == 0 && m < M) {
                        atomicAdd(&sums[2 * m], s);
                        atomicAdd(&sums[2 * m + 1], s2);
                    }
                }
        }
    }
}

// CHW f32 -> NHWC f16 tiled transpose (C, HW multiples of 32)
__global__ __launch_bounds__(256)
void chw2nhwc_k(const float* __restrict__ in, f16* __restrict__ out, int C, int HW)
{
    int b = blockIdx.z;
    int l0 = blockIdx.x * 32, c0 = blockIdx.y * 32;
    __shared__ float t[32][33];
    int tx = threadIdx.x & 31, ty = threadIdx.x >> 5;
    const float* ib = in + (long)b * C * HW;
#pragma unroll
    for (int j = 0; j < 4; j++) {
        int c = c0 + ty + j * 8;
        t[ty + j * 8][tx] = ib[(long)c * HW + l0 + tx];
    }
    __syncthreads();
    f16* ob = out + (long)b * HW * C;
#pragma unroll
    for (int j = 0; j < 4; j++) {
        int l = l0 + ty + j * 8;
        ob[(long)l * C + c0 + tx] = (f16)t[tx][ty + j * 8];
    }
}

// flat f32 -> f16
__global__ void f2h_k(const float* __restrict__ src, f16* __restrict__ dst, long n)
{
    long i = blockIdx.x * 256L + threadIdx.x;
    if (i < n) dst[i] = (f16)src[i];
}

// w5 (O,C,3,3) f32 -> w5r[O][tap][C] f16  (K ordered taps-outer, c-inner)
__global__ void w5r_k(const float* __restrict__ src, f16* __restrict__ dst)
{
    long i = blockIdx.x * 256L + threadIdx.x;
    if (i >= 9L * 512 * 512) return;
    int c = (int)(i % 512); long t2 = i / 512;
    int t = (int)(t2 % 9); int o = (int)(t2 / 9);
    dst[i] = (f16)src[(long)o * 4608 + c * 9 + t];
}

__global__ void zero_k(float* __restrict__ p, int n)
{
    int i = blockIdx.x * 256 + threadIdx.x;
    if (i < n) p[i] = 0.f;
}

// apply BN (from raw sums) elementwise, f16 in/out, 8 elems/thread
__global__ __launch_bounds__(256)
void bnapply_k(f16* __restrict__ x, const float* __restrict__ mv,
               const float* __restrict__ g, const float* __restrict__ bta,
               int C, long total, float inv, int dorelu)
{
    long i8 = (blockIdx.x * 256L + threadIdx.x) * 8;
    if (i8 >= total) return;
    int c0 = (int)(i8 % C);
    f16x8 v = *(f16x8*)&x[i8];
#pragma unroll
    for (int j = 0; j < 8; j++) {
        int c = c0 + j;
        float m = mv[2 * c] * inv;
        float var = mv[2 * c + 1] * inv - m * m;
        float r = ((float)v[j] - m) * rsqrtf(var + EPSBN) * g[c] + bta[c];
        if (dorelu) r = fmaxf(r, 0.f);
        v[j] = (f16)r;
    }
    *(f16x8*)&x[i8] = v;
}

// bilinear upsample align_corners=True, NHWC f16
__global__ __launch_bounds__(256)
void upsample_h(const f16* __restrict__ in, f16* __restrict__ out,
                int C, int H, int W, int OH, int OW)
{
    long total = 2L * C * OH * OW;
    float ry = (float)(H - 1) / (float)(OH - 1);
    float rx = (float)(W - 1) / (float)(OW - 1);
    for (long i = blockIdx.x * 256L + threadIdx.x; i < total; i += (long)gridDim.x * 256) {
        int c = (int)(i % C); long t = i / C;
        int l = (int)(t % (OH * OW)); int bb = (int)(t / (OH * OW));
        int oy = l / OW, ox = l % OW;
        float fy = oy * ry, fx = ox * rx;
        int y0 = (int)fy, x0 = (int)fx;
        int y1 = min(y0 + 1, H - 1), x1 = min(x0 + 1, W - 1);
        float wy = fy - y0, wx = fx - x0;
        const f16* p = in + (long)bb * H * W * C + c;
        float v00 = (float)p[(long)(y0 * W + x0) * C];
        float v01 = (float)p[(long)(y0 * W + x1) * C];
        float v10 = (float)p[(long)(y1 * W + x0) * C];
        float v11 = (float)p[(long)(y1 * W + x1) * C];
        out[i] = (f16)((v00 * (1.f - wx) + v01 * wx) * (1.f - wy) +
                       (v10 * (1.f - wx) + v11 * wx) * wy);
    }
}

// energy + softmax over 9 dilated-2 taps (NHWC f16 q/k) -> att f32 (n,l,9)
__global__ __launch_bounds__(256)
void att_h(const f16* __restrict__ q, const f16* __restrict__ k,
           float* __restrict__ att, int C, int H, int W)
{
    int HW = H * W;
    int l = blockIdx.x * 256 + threadIdx.x;
    int n = blockIdx.y;
    if (l >= HW) return;
    int y = l / W, x = l % W;
    int offs[9]; bool val[9];
#pragma unroll
    for (int t = 0; t < 9; t++) {
        int a = t / 3, bj = t % 3;
        int yy = y + 2 * a - 2, xx = x + 2 * bj - 2;
        val[t] = (yy >= 0 && yy < H && xx >= 0 && xx < W);
        offs[t] = val[t] ? yy * W + xx : 0;
    }
    float e[9] = {0.f, 0.f, 0.f, 0.f, 0.f, 0.f, 0.f, 0.f, 0.f};
    const f16* qr = q + ((long)n * HW + l) * C;
    const f16* kb = k + (long)n * HW * C;
    for (int c = 0; c < C; c += 8) {
        f16x8 qv = *(const f16x8*)&qr[c];
        float qf[8];
#pragma unroll
        for (int j = 0; j < 8; j++) qf[j] = (float)qv[j];
#pragma unroll
        for (int t = 0; t < 9; t++) {
            if (!val[t]) continue;
            f16x8 kv = *(const f16x8*)&kb[(long)offs[t] * C + c];
#pragma unroll
            for (int j = 0; j < 8; j++) e[t] = fmaf(qf[j], (float)kv[j], e[t]);
        }
    }
    float mx = e[0];
#pragma unroll
    for (int t = 1; t < 9; t++) mx = fmaxf(mx, e[t]);
    float s = 0.f; float ex[9];
#pragma unroll
    for (int t = 0; t < 9; t++) { ex[t] = expf(e[t] - mx); s += ex[t]; }
    float inv = 1.f / s;
    long base = ((long)n * HW + l) * 9;
#pragma unroll
    for (int t = 0; t < 9; t++) att[base + t] = ex[t] * inv;
}

// out[b,l,c] = sum_t att * v[neigh] (NHWC f16)
__global__ __launch_bounds__(256)
void attout_h(const float* __restrict__ att, const f16* __restrict__ v,
              f16* __restrict__ out, int C, int H, int W)
{
    int HW = H * W;
    long total = 2L * HW * C;
    for (long i = blockIdx.x * 256L + threadIdx.x; i < total; i += (long)gridDim.x * 256) {
        int c = (int)(i % C); long t2 = i / C;
        int l = (int)(t2 % HW); int bb = (int)(t2 / HW);
        int y = l / W, x = l % W;
        long abase = ((long)bb * HW + l) * 9;
        const f16* vb = v + (long)bb * HW * C + c;
        float s = 0.f;
#pragma unroll
        for (int t = 0; t < 9; t++) {
            int aa = t / 3, bj = t % 3;
            int yy = y + 2 * aa - 2, xx = x + 2 * bj - 2;
            if (yy >= 0 && yy < H && xx >= 0 && xx < W)
                s = fmaf(att[abase + t], (float)vb[(long)(yy * W + xx) * C], s);
        }
        out[i] = (f16)s;
    }
}

// codeword squared norms
__global__ void cc_k(const float* __restrict__ cw, float* __restrict__ cc, int D)
{
    int k = threadIdx.x;
    if (k < 32) {
        float s = 0.f;
        for (int d = 0; d < D; d++) { float v = cw[(long)k * D + d]; s += v * v; }
        cc[k] = s;
    }
}

// soft-assign: x f16 NHWC, xc f16 [l][32] -> A f32 [l][32]
__global__ __launch_bounds__(256)
void assign_h(const f16* __restrict__ x, const f16* __restrict__ xc,
              const float* __restrict__ cc, const float* __restrict__ scale,
              float* __restrict__ A)
{
    int l = blockIdx.x * 256 + threadIdx.x;
    int bb = blockIdx.y;
    if (l >= 4096) return;
    const f16* xr = x + ((long)bb * 4096 + l) * 512;
    float xx = 0.f;
    for (int d = 0; d < 512; d += 8) {
        f16x8 v = *(const f16x8*)&xr[d];
#pragma unroll
        for (int j = 0; j < 8; j++) { float f = (float)v[j]; xx = fmaf(f, f, xx); }
    }
    const f16* xcr = xc + ((long)bb * 4096 + l) * 32;
    float e[32]; float mx = -1e30f;
#pragma unroll
    for (int k2 = 0; k2 < 32; k2++) {
        float dist = xx + cc[k2] - 2.f * (float)xcr[k2];
        float en = -scale[k2] * dist;
        e[k2] = en; mx = fmaxf(mx, en);
    }
    float s = 0.f;
#pragma unroll
    for (int k2 = 0; k2 < 32; k2++) { e[k2] = expf(e[k2] - mx); s += e[k2]; }
    float inv = 1.f / s;
    long base = ((long)bb * 4096 + l) * 32;
#pragma unroll
    for (int k2 = 0; k2 < 32; k2++) A[base + k2] = e[k2] * inv;
}

__global__ __launch_bounds__(256)
void asum_k(const float* __restrict__ A, float* __restrict__ Asum, int HW)
{
    int k2 = blockIdx.x, b = blockIdx.y;
    float s = 0.f;
    for (int l = threadIdx.x; l < HW; l += 256) s += A[((long)b * HW + l) * 32 + k2];
    __shared__ float sh[256];
    sh[threadIdx.x] = s;
    __syncthreads();
    for (int o = 128; o > 0; o >>= 1) {
        if (threadIdx.x < o) sh[threadIdx.x] += sh[threadIdx.x + o];
        __syncthreads();
    }
    if (threadIdx.x == 0) Asum[b * 32 + k2] = sh[0];
}

// Et partial GEMM: Etp[z][k2][d] = sum_{l in chunk} A[l][k2] * X[l][d]
__global__ __launch_bounds__(256)
void etg_k(const float* __restrict__ Af, const f16* __restrict__ Xh, float* __restrict__ Etp)
{
    int z = blockIdx.z; int b = z >> 4; int ch = z & 15;
    int kbase = ch * 256;
    const float* Ab = Af + (long)b * 4096 * 32;
    const f16* Xb = Xh + (long)b * 4096 * 512;
    int n0 = blockIdx.x * 64;
    __shared__ float As[16][65];
    __shared__ float Bs[16][64];
    int tid = threadIdx.x; int tx = tid & 15, ty = tid >> 4;
    float acc[4][4];
#pragma unroll
    for (int i = 0; i < 4; i++)
#pragma unroll
        for (int j = 0; j < 4; j++) acc[i][j] = 0.f;
    for (int k0 = 0; k0 < 256; k0 += 16) {
#pragma unroll
        for (int i = 0; i < 4; i++) {
            int idx = tid + i * 256;
            int kk = idx & 15, mm = idx >> 4;
            float vv = 0.f;
            if (mm < 32) vv = Ab[(long)(kbase + k0 + kk) * 32 + mm];
            As[kk][mm] = vv;
        }
#pragma unroll
        for (int i = 0; i < 4; i++) {
            int idx = tid + i * 256;
            int nn = idx & 63, kk = idx >> 6;
            Bs[kk][nn] = (float)Xb[(long)(kbase + k0 + kk) * 512 + n0 + nn];
        }
        __syncthreads();
#pragma unroll
        for (int kk = 0; kk < 16; kk++) {
            float a[4], bb2[4];
#pragma unroll
            for (int i = 0; i < 4; i++) a[i] = As[kk][ty + i * 16];
#pragma unroll
            for (int j = 0; j < 4; j++) bb2[j] = Bs[kk][tx + j * 16];
#pragma unroll
            for (int i = 0; i < 4; i++)
#pragma unroll
                for (int j = 0; j < 4; j++)
                    acc[i][j] = fmaf(a[i], bb2[j], acc[i][j]);
        }
        __syncthreads();
    }
    float* Ob = Etp + (long)z * 32 * 512;
#pragma unroll
    for (int i = 0; i < 4; i++) {
        int m = ty + i * 16;
        if (m >= 32) continue;
#pragma unroll
        for (int j = 0; j < 4; j++) Ob[(long)m * 512 + n0 + tx + j * 16] = acc[i][j];
    }
}

// E[b,k,d] = sum_chunks Etp - Asum*cw
__global__ void efix2_k(const float* __restrict__ Etp, const float* __restrict__ asumf,
                        const float* __restrict__ cwf, float* __restrict__ Ef)
{
    int i = blockIdx.x * 256 + threadIdx.x;
    if (i >= 2 * 32 * 512) return;
    int d = i % 512; int k2 = (i / 512) % 32; int bb = i / (512 * 32);
    float s = 0.f;
#pragma unroll
    for (int c2 = 0; c2 < 16; c2++) s += Etp[((long)(bb * 16 + c2) * 32 + k2) * 512 + d];
    Ef[i] = s - asumf[bb * 32 + k2] * cwf[k2 * 512 + d];
}

// BN stats (mean/var) per channel, f32 input (for E)
__global__ __launch_bounds__(256)
void bn_stats_k(const float* __restrict__ x, float* __restrict__ mv,
                int HW, int Nb, long strideN)
{
    int c = blockIdx.x;
    long total = (long)Nb * HW;
    float s = 0.f, s2 = 0.f;
    for (long i = threadIdx.x; i < total; i += 256) {
        int n = (int)(i / HW); int l = (int)(i % HW);
        float v = x[(long)n * strideN + (long)c * HW + l];
        s += v; s2 += v * v;
    }
    __shared__ float sh0[256], sh1[256];
    sh0[threadIdx.x] = s; sh1[threadIdx.x] = s2;
    __syncthreads();
    for (int o = 128; o > 0; o >>= 1) {
        if (threadIdx.x < o) { sh0[threadIdx.x] += sh0[threadIdx.x + o]; sh1[threadIdx.x] += sh1[threadIdx.x + o]; }
        __syncthreads();
    }
    if (threadIdx.x == 0) {
        float inv = 1.f / (float)total;
        float m = sh0[0] * inv;
        mv[2 * c] = m;
        mv[2 * c + 1] = sh1[0] * inv - m * m;
    }
}

// en[b,d] = mean_k relu(BN1d(E[b,k,d]))
__global__ __launch_bounds__(256)
void en_k(const float* __restrict__ E, const float* __restrict__ mv,
          const float* __restrict__ gK, const float* __restrict__ bK,
          float* __restrict__ en, int D)
{
    int i = blockIdx.x * 256 + threadIdx.x;
    if (i >= 2 * D) return;
    int b = i / D, d = i % D;
    float s = 0.f;
#pragma unroll
    for (int k2 = 0; k2 < 32; k2++) {
        float m = mv[2 * k2], vv = mv[2 * k2 + 1];
        float r = (E[((long)b * 32 + k2) * D + d] - m) * rsqrtf(vv + EPSBN) * gK[k2] + bK[k2];
        s += fmaxf(r, 0.f);
    }
    en[i] = s * (1.f / 32.f);
}

__global__ __launch_bounds__(256)
void fc_k(const float* __restrict__ W, const float* __restrict__ bias,
          const float* __restrict__ in, float* __restrict__ out,
          int O, int D, int mode)
{
    int o = blockIdx.x * 256 + threadIdx.x;
    int b = blockIdx.y;
    if (o >= O) return;
    const float* ib = in + (long)b * D;
    float s = bias[o];
    for (int d = 0; d < D; d++) s += W[(long)o * D + d] * ib[d];
    if (mode == 1) s = 1.f / (1.f + expf(-s));
    out[(long)b * O + o] = s;
}

// y = relu(feat * (1+gamma)), f16 NHWC
__global__ __launch_bounds__(256)
void ymul_h(const f16* __restrict__ feat, const float* __restrict__ gamma,
            f16* __restrict__ y)
{
    long total = 2L * 4096 * 512;
    for (long i = blockIdx.x * 256L + threadIdx.x; i < total; i += (long)gridDim.x * 256) {
        int c = (int)(i % 512);
        int bb = (int)(i / (4096L * 512));
        y[i] = (f16)fmaxf((float)feat[i] * (1.f + gamma[bb * 512 + c]), 0.f);
    }
}

static inline dim3 hgrid(int M, int N) { return dim3((N + 127) / 128, (M + 63) / 64, 2); }

extern "C" void kernel_launch(void* const* d_in, const int* in_sizes, int n_in,
                              void* d_out, int out_size, void* d_ws, size_t ws_size,
                              hipStream_t stream)
{
    (void)in_sizes; (void)n_in; (void)out_size; (void)ws_size;
    const float* c2  = (const float*)d_in[1];
    const float* c3  = (const float*)d_in[2];
    const float* c4  = (const float*)d_in[3];
    const float* wq4 = (const float*)d_in[7];
    const float* gq4 = (const float*)d_in[8];
    const float* bq4 = (const float*)d_in[9];
    const float* wk4 = (const float*)d_in[10];
    const float* gk4 = (const float*)d_in[11];
    const float* bk4 = (const float*)d_in[12];
    const float* wv4 = (const float*)d_in[13];
    const float* wq3 = (const float*)d_in[14];
    const float* gq3 = (const float*)d_in[15];
    const float* bq3 = (const float*)d_in[16];
    const float* wk3 = (const float*)d_in[17];
    const float* gk3 = (const float*)d_in[18];
    const float* bk3 = (const float*)d_in[19];
    const float* wv3 = (const float*)d_in[20];
    const float* w5  = (const float*)d_in[21];
    const float* g5  = (const float*)d_in[22];
    const float* b5  = (const float*)d_in[23];
    const float* we  = (const float*)d_in[24];
    const float* ge  = (const float*)d_in[25];
    const float* be  = (const float*)d_in[26];
    const float* cw  = (const float*)d_in[27];
    const float* scl = (const float*)d_in[28];
    const float* gK  = (const float*)d_in[29];
    const float* bK  = (const float*)d_in[30];
    const float* wfc = (const float*)d_in[31];
    const float* bfc = (const float*)d_in[32];
    const float* wse = (const float*)d_in[33];
    const float* bse = (const float*)d_in[34];
    const float* w6  = (const float*)d_in[35];
    const float* b6  = (const float*)d_in[36];
    float* outp = (float*)d_out;
    char* ws = (char*)d_ws;

    // ---- workspace (byte offsets), liveness-checked overlays ----
    auto H = [&](long off) { return (f16*)(ws + off); };
    auto F = [&](long off) { return (float*)(ws + off); };
    const long O_wq4h = 0;
    const long O_wk4h = 262144;
    const long O_wv4h = 786432;
    const long O_wq3h = 4980736;
    const long O_wk3h = 5046272;
    const long O_wv3h = 5177344;
    const long O_w5r  = 6225920;
    const long O_weh  = 10944512;
    const long O_cwh  = 11468800;
    const long O_w6h  = 11501568;
    const long O_c3h  = 11665408;
    const long O_Xh   = 11665408;
    const long O_c4h  = 20054016;
    const long O_cku4h= 22151168;
    const long O_v3h  = 22151168;
    const long O_q4h  = 30539776;
    const long O_k4h  = 31064064;
    const long O_v4h  = 31588352;
    const long O_att3 = 30539776;
    const long O_xch  = 30834688;
    const long O_Af   = 31358976;
    const long O_Etp  = 32407552;
    const long O_Ef   = 34504704;
    const long O_asum = 34635776;
    const long O_cc   = 34636032;
    const long O_en   = 34636160;
    const long O_gam  = 34640256;
    const long O_mv   = 34644352;
    const long O_att4 = 35782656;
    const long O_out4h= 35856384;
    const long O_yh   = 35856384;
    const long O_c2h  = 40050688;
    const long O_cku3h= 48439296;
    const long O_feath= 48439296;
    const long O_out3h= 56827904;
    const long O_q3h  = 65216512;
    const long O_k3h  = 66265088;

    float* mv = F(O_mv);

    // ---- conversions (r6-verbatim) ----
    chw2nhwc_k<<<dim3(128, 16, 2), 256, 0, stream>>>(c2, H(O_c2h), 512, 4096);
    chw2nhwc_k<<<dim3(32, 32, 2), 256, 0, stream>>>(c3, H(O_c3h), 1024, 1024);
    chw2nhwc_k<<<dim3(8, 64, 2), 256, 0, stream>>>(c4, H(O_c4h), 2048, 256);
    auto cvt = [&](const float* s, long o, long n) {
        f2h_k<<<(int)((n + 255) / 256), 256, 0, stream>>>(s, H(o), n);
    };
    cvt(wq4, O_wq4h, 128L * 1024); cvt(wk4, O_wk4h, 128L * 2048);
    cvt(wv4, O_wv4h, 1024L * 2048); cvt(wq3, O_wq3h, 64L * 512);
    cvt(wk3, O_wk3h, 64L * 1024); cvt(wv3, O_wv3h, 512L * 1024);
    cvt(we, O_weh, 512L * 512); cvt(cw, O_cwh, 32L * 512);
    cvt(w6, O_w6h, 150L * 512);
    w5r_k<<<9216, 256, 0, stream>>>(w5, H(O_w5r));
    zero_k<<<11, 256, 0, stream>>>(mv, 2816);

    // ---- Stage A: local_up(c3, c4) -> out4h (NHWC 2x1024x1024) ----
    hgemm_k<0><<<hgrid(128, 1024), 256, 0, stream>>>(H(O_wq4h), H(O_c3h), H(O_q4h), nullptr,
        128, 1024, 1024, 1024, 1024L * 1024, 1024L * 128, 0, 0, mv + 0);
    bnapply_k<<<128, 256, 0, stream>>>(H(O_q4h), mv + 0, gq4, bq4, 128, 2L * 1024 * 128, 1.f / 2048.f, 0);
    upsample_h<<<16384, 256, 0, stream>>>(H(O_c4h), H(O_cku4h), 2048, 16, 16, 32, 32);
    hgemm_k<0><<<hgrid(128, 1024), 256, 0, stream>>>(H(O_wk4h), H(O_cku4h), H(O_k4h), nullptr,
        128, 2048, 1024, 2048, 1024L * 2048, 1024L * 128, 0, 0, mv + 256);
    bnapply_k<<<128, 256, 0, stream>>>(H(O_k4h), mv + 256, gk4, bk4, 128, 2L * 1024 * 128, 1.f / 2048.f, 0);
    hgemm_k<0><<<hgrid(1024, 1024), 256, 0, stream>>>(H(O_wv4h), H(O_cku4h), H(O_v4h), nullptr,
        1024, 2048, 1024, 2048, 1024L * 2048, 1024L * 1024, 0, 0, nullptr);
    att_h<<<dim3(4, 2), 256, 0, stream>>>(H(O_q4h), H(O_k4h), F(O_att4), 128, 32, 32);
    attout_h<<<8192, 256, 0, stream>>>(F(O_att4), H(O_v4h), H(O_out4h), 1024, 32, 32);

    // ---- Stage B: local_up(c2, out4) -> out3h (NHWC 2x4096x512) ----
    hgemm_k<0><<<hgrid(64, 4096), 256, 0, stream>>>(H(O_wq3h), H(O_c2h), H(O_q3h), nullptr,
        64, 512, 4096, 512, 4096L * 512, 4096L * 64, 0, 0, mv + 512);
    bnapply_k<<<256, 256, 0, stream>>>(H(O_q3h), mv + 512, gq3, bq3, 64, 2L * 4096 * 64, 1.f / 8192.f, 0);
    upsample_h<<<32768, 256, 0, stream>>>(H(O_out4h), H(O_cku3h), 1024, 32, 32, 64, 64);
    hgemm_k<0><<<hgrid(64, 4096), 256, 0, stream>>>(H(O_wk3h), H(O_cku3h), H(O_k3h), nullptr,
        64, 1024, 4096, 1024, 4096L * 1024, 4096L * 64, 0, 0, mv + 640);
    bnapply_k<<<256, 256, 0, stream>>>(H(O_k3h), mv + 640, gk3, bk3, 64, 2L * 4096 * 64, 1.f / 8192.f, 0);
    hgemm_k<0><<<hgrid(512, 4096), 256, 0, stream>>>(H(O_wv3h), H(O_cku3h), H(O_v3h), nullptr,
        512, 1024, 4096, 1024, 4096L * 1024, 4096L * 512, 0, 0, nullptr);
    att_h<<<dim3(16, 2), 256, 0, stream>>>(H(O_q3h), H(O_k3h), F(O_att3), 64, 64, 64);
    attout_h<<<16384, 256, 0, stream>>>(F(O_att3), H(O_v3h), H(O_out3h), 512, 64, 64);

    // ---- Stage C: feat = relu(BN(conv3x3(out3))) ----
    hgemm_k<1><<<hgrid(512, 4096), 256, 0, stream>>>(H(O_w5r), H(O_out3h), H(O_feath), nullptr,
        512, 4608, 4096, 512, 4096L * 512, 4096L * 512, 64, 64, mv + 768);
    bnapply_k<<<2048, 256, 0, stream>>>(H(O_feath), mv + 768, g5, b5, 512, 2L * 4096 * 512, 1.f / 8192.f, 1);

    // ---- Stage D: enc_module ----
    hgemm_k<0><<<hgrid(512, 4096), 256, 0, stream>>>(H(O_weh), H(O_feath), H(O_Xh), nullptr,
        512, 512, 4096, 512, 4096L * 512, 4096L * 512, 0, 0, mv + 1792);
    bnapply_k<<<2048, 256, 0, stream>>>(H(O_Xh), mv + 1792, ge, be, 512, 2L * 4096 * 512, 1.f / 8192.f, 1);
    hgemm_k<0><<<hgrid(32, 4096), 256, 0, stream>>>(H(O_cwh), H(O_Xh), H(O_xch), nullptr,
        32, 512, 4096, 512, 4096L * 512, 4096L * 32, 0, 0, nullptr);
    cc_k<<<1, 32, 0, stream>>>(cw, F(O_cc), 512);
    assign_h<<<dim3(16, 2), 256, 0, stream>>>(H(O_Xh), H(O_xch), F(O_cc), scl, F(O_Af));
    asum_k<<<dim3(32, 2), 256, 0, stream>>>(F(O_Af), F(O_asum), 4096);
    etg_k<<<dim3(8, 1, 32), 256, 0, stream>>>(F(O_Af), H(O_Xh), F(O_Etp));
    efix2_k<<<128, 256, 0, stream>>>(F(O_Etp), F(O_asum), cw, F(O_Ef));
    bn_stats_k<<<32, 256, 0, stream>>>(F(O_Ef), mv + 2816, 512, 2, 32L * 512);
    en_k<<<4, 256, 0, stream>>>(F(O_Ef), mv + 2816, gK, bK, F(O_en), 512);
    fc_k<<<dim3(2, 2), 256, 0, stream>>>(wfc, bfc, F(O_en), F(O_gam), 512, 512, 1);
    fc_k<<<dim3(1, 2), 256, 0, stream>>>(wse, bse, F(O_en), outp + 1228800, 150, 512, 0);
    ymul_h<<<16384, 256, 0, stream>>>(H(O_feath), F(O_gam), H(O_yh));

    // ---- Stage E: seg = w6 @ y + b6 -> d_out (CHW f32) ----
    hgemm_k<2><<<hgrid(150, 4096), 256, 0, stream>>>(H(O_w6h), H(O_yh), outp, b6,
        150, 512, 4096, 512, 4096L * 512, 150L * 4096, 0, 0, nullptr);
}

// Round 10
// 656.083 us; speedup vs baseline: 5.4177x; 1.0977x over previous
//
#include <hip/hip_runtime.h>
#include <math.h>

#define EPSBN 1e-5f

typedef _Float16 f16;
typedef _Float16 f16x8 __attribute__((ext_vector_type(8)));
typedef _Float16 f16x4 __attribute__((ext_vector_type(4)));
typedef float f32x4 __attribute__((ext_vector_type(4)));

static __device__ inline f16x8 h8zero() {
    f16x8 v;
#pragma unroll
    for (int j = 0; j < 8; j++) v[j] = (f16)0.f;
    return v;
}

// ---------------------------------------------------------------------------
// MFMA f16 GEMM, NHWC activations. D[m][n] = sum_k W[m][k] * act[n][k].
// BM=64, BN=128, BK=64. 4 waves (2x2), wave tile 32x64. 2-phase pipeline,
// pre-swizzled global source + linear LDS write + swizzled read.
// Optional fused BN column sums (sums != nullptr): sums[2m]+=x, sums[2m+1]+=x^2.
// MODE 0: out f16 NHWC ([n][M]); MODE 1: conv3x3-d1 tap-shifted B; MODE 2:
// out f32 CHW ([m][N]) + bias.
// ---------------------------------------------------------------------------
template<int MODE>
__global__ __launch_bounds__(256)
void hgemm_k(const f16* __restrict__ Wh, const f16* __restrict__ act,
             void* __restrict__ outv, const float* __restrict__ bias,
             int M, int K, int N, int Cact, long actStride, long outStride,
             int IW, int IH, float* __restrict__ sums)
{
    const int b = blockIdx.z;
    const int n0 = blockIdx.x * 128, m0 = blockIdx.y * 64;
    const f16* actb = act + (long)b * actStride;
    __shared__ __align__(16) f16 As[2][64 * 64];
    __shared__ __align__(16) f16 Bs[2][128 * 64];
    const int tid = threadIdx.x;
    const int wave = tid >> 6, lane = tid & 63;
    const int wm = (wave >> 1) * 32, wn = (wave & 1) * 64;
    const int lr = lane & 15, lg = lane >> 4;
    f32x4 acc[2][4];
#pragma unroll
    for (int i = 0; i < 2; i++)
#pragma unroll
        for (int j = 0; j < 4; j++)
#pragma unroll
            for (int r = 0; r < 4; r++) acc[i][j][r] = 0.f;

    const int nt = K >> 6;
    f16x8 ra[2], rb[4];

    auto LOAD = [&](int t) {
        const int kt = t << 6;
#pragma unroll
        for (int u = 0; u < 2; u++) {
            int idx = u * 256 + tid;
            int row = idx >> 3, slot = idx & 7;
            int col = kt + ((slot ^ (row & 7)) << 3);   // pre-swizzled source
            int m = m0 + row;
            ra[u] = (m < M) ? *(const f16x8*)&Wh[(long)m * K + col] : h8zero();
        }
#pragma unroll
        for (int u = 0; u < 4; u++) {
            int idx = u * 256 + tid;
            int row = idx >> 3, slot = idx & 7;
            int scol = (slot ^ (row & 7)) << 3;         // pre-swizzled source
            int n = n0 + row;
            if (MODE == 1) {
                int tap = kt >> 9;
                int kc = (kt & 511) + scol;
                int dy = tap / 3 - 1, dx = tap % 3 - 1;
                int yy = n / IW + dy, xx = n % IW + dx;
                rb[u] = (yy >= 0 && yy < IH && xx >= 0 && xx < IW)
                        ? *(const f16x8*)&actb[(long)(yy * IW + xx) * Cact + kc]
                        : h8zero();
            } else {
                rb[u] = *(const f16x8*)&actb[(long)n * Cact + kt + scol];
            }
        }
    };
    auto WRITE = [&](int bufw) {
#pragma unroll
        for (int u = 0; u < 2; u++) {
            int idx = u * 256 + tid;
            int row = idx >> 3, slot = idx & 7;
            *(f16x8*)&As[bufw][(row * 8 + slot) * 8] = ra[u];   // LINEAR write
        }
#pragma unroll
        for (int u = 0; u < 4; u++) {
            int idx = u * 256 + tid;
            int row = idx >> 3, slot = idx & 7;
            *(f16x8*)&Bs[bufw][(row * 8 + slot) * 8] = rb[u];   // LINEAR write
        }
    };

    LOAD(0); WRITE(0); __syncthreads();
    int buf = 0;
    for (int t = 0; t < nt; t++) {
        if (t + 1 < nt) LOAD(t + 1);
#pragma unroll
        for (int s = 0; s < 2; s++) {
            f16x8 af[2], bf[4];
#pragma unroll
            for (int i = 0; i < 2; i++) {
                int r = wm + i * 16 + lr;
                af[i] = *(const f16x8*)&As[buf][(r * 8 + ((s * 4 + lg) ^ (r & 7))) * 8];
            }
#pragma unroll
            for (int j = 0; j < 4; j++) {
                int r = wn + j * 16 + lr;
                bf[j] = *(const f16x8*)&Bs[buf][(r * 8 + ((s * 4 + lg) ^ (r & 7))) * 8];
            }
#pragma unroll
            for (int i = 0; i < 2; i++)
#pragma unroll
                for (int j = 0; j < 4; j++)
                    acc[i][j] = __builtin_amdgcn_mfma_f32_16x16x32_f16(af[i], bf[j], acc[i][j], 0, 0, 0);
        }
        if (t + 1 < nt) WRITE(buf ^ 1);
        __syncthreads();
        buf ^= 1;
    }

    if (MODE == 2) {
        float* outp = (float*)outv + (long)b * outStride;
#pragma unroll
        for (int i = 0; i < 2; i++)
#pragma unroll
            for (int j = 0; j < 4; j++) {
                int n = n0 + wn + j * 16 + lr;
#pragma unroll
                for (int r = 0; r < 4; r++) {
                    int m = m0 + wm + i * 16 + lg * 4 + r;
                    if (m < M) outp[(long)m * N + n] = acc[i][j][r] + bias[m];
                }
            }
    } else {
        f16* outp = (f16*)outv + (long)b * outStride;
#pragma unroll
        for (int i = 0; i < 2; i++)
#pragma unroll
            for (int j = 0; j < 4; j++) {
                int n = n0 + wn + j * 16 + lr;
                int mb = m0 + wm + i * 16 + lg * 4;
                if (mb < M) {
                    f16x4 hv;
#pragma unroll
                    for (int r = 0; r < 4; r++) hv[r] = (f16)acc[i][j][r];
                    *(f16x4*)&outp[(long)n * M + mb] = hv;
                }
            }
        if (sums) {
#pragma unroll
            for (int i = 0; i < 2; i++)
#pragma unroll
                for (int r = 0; r < 4; r++) {
                    int m = m0 + wm + i * 16 + lg * 4 + r;
                    float s = 0.f, s2 = 0.f;
#pragma unroll
                    for (int j = 0; j < 4; j++) {
                        float v = (float)(f16)acc[i][j][r];   // rounded value
                        s += v; s2 += v * v;
                    }
#pragma unroll
                    for (int msk = 1; msk < 16; msk <<= 1) {
                        s += __shfl_xor(s, msk);
                        s2 += __shfl_xor(s2, msk);
                    }
                    if (lr == 0 && m < M) {
                        atomicAdd(&sums[2 * m], s);
                        atomicAdd(&sums[2 * m + 1], s2);
                    }
                }
        }
    }
}

// CHW f32 -> NHWC f16 tiled transpose (C, HW multiples of 32)
__global__ __launch_bounds__(256)
void chw2nhwc_k(const float* __restrict__ in, f16* __restrict__ out, int C, int HW)
{
    int b = blockIdx.z;
    int l0 = blockIdx.x * 32, c0 = blockIdx.y * 32;
    __shared__ float t[32][33];
    int tx = threadIdx.x & 31, ty = threadIdx.x >> 5;
    const float* ib = in + (long)b * C * HW;
#pragma unroll
    for (int j = 0; j < 4; j++) {
        int c = c0 + ty + j * 8;
        t[ty + j * 8][tx] = ib[(long)c * HW + l0 + tx];
    }
    __syncthreads();
    f16* ob = out + (long)b * HW * C;
#pragma unroll
    for (int j = 0; j < 4; j++) {
        int l = l0 + ty + j * 8;
        ob[(long)l * C + c0 + tx] = (f16)t[tx][ty + j * 8];
    }
}

// flat f32 -> f16
__global__ void f2h_k(const float* __restrict__ src, f16* __restrict__ dst, long n)
{
    long i = blockIdx.x * 256L + threadIdx.x;
    if (i < n) dst[i] = (f16)src[i];
}

// w5 (O,C,3,3) f32 -> w5r[O][tap][C] f16  (K ordered taps-outer, c-inner)
__global__ void w5r_k(const float* __restrict__ src, f16* __restrict__ dst)
{
    long i = blockIdx.x * 256L + threadIdx.x;
    if (i >= 9L * 512 * 512) return;
    int c = (int)(i % 512); long t2 = i / 512;
    int t = (int)(t2 % 9); int o = (int)(t2 / 9);
    dst[i] = (f16)src[(long)o * 4608 + c * 9 + t];
}

__global__ void zero_k(float* __restrict__ p, int n)
{
    int i = blockIdx.x * 256 + threadIdx.x;
    if (i < n) p[i] = 0.f;
}

// apply BN (from raw sums) elementwise, f16 in/out, 8 elems/thread
__global__ __launch_bounds__(256)
void bnapply_k(f16* __restrict__ x, const float* __restrict__ mv,
               const float* __restrict__ g, const float* __restrict__ bta,
               int C, long total, float inv, int dorelu)
{
    long i8 = (blockIdx.x * 256L + threadIdx.x) * 8;
    if (i8 >= total) return;
    int c0 = (int)(i8 % C);
    f16x8 v = *(f16x8*)&x[i8];
#pragma unroll
    for (int j = 0; j < 8; j++) {
        int c = c0 + j;
        float m = mv[2 * c] * inv;
        float var = mv[2 * c + 1] * inv - m * m;
        float r = ((float)v[j] - m) * rsqrtf(var + EPSBN) * g[c] + bta[c];
        if (dorelu) r = fmaxf(r, 0.f);
        v[j] = (f16)r;
    }
    *(f16x8*)&x[i8] = v;
}

// bilinear upsample align_corners=True, NHWC f16
__global__ __launch_bounds__(256)
void upsample_h(const f16* __restrict__ in, f16* __restrict__ out,
                int C, int H, int W, int OH, int OW)
{
    long total = 2L * C * OH * OW;
    float ry = (float)(H - 1) / (float)(OH - 1);
    float rx = (float)(W - 1) / (float)(OW - 1);
    for (long i = blockIdx.x * 256L + threadIdx.x; i < total; i += (long)gridDim.x * 256) {
        int c = (int)(i % C); long t = i / C;
        int l = (int)(t % (OH * OW)); int bb = (int)(t / (OH * OW));
        int oy = l / OW, ox = l % OW;
        float fy = oy * ry, fx = ox * rx;
        int y0 = (int)fy, x0 = (int)fx;
        int y1 = min(y0 + 1, H - 1), x1 = min(x0 + 1, W - 1);
        float wy = fy - y0, wx = fx - x0;
        const f16* p = in + (long)bb * H * W * C + c;
        float v00 = (float)p[(long)(y0 * W + x0) * C];
        float v01 = (float)p[(long)(y0 * W + x1) * C];
        float v10 = (float)p[(long)(y1 * W + x0) * C];
        float v11 = (float)p[(long)(y1 * W + x1) * C];
        out[i] = (f16)((v00 * (1.f - wx) + v01 * wx) * (1.f - wy) +
                       (v10 * (1.f - wx) + v11 * wx) * wy);
    }
}

// ---------------------------------------------------------------------------
// Wave-per-pixel energy+softmax over 9 dilated-2 taps. One wave handles one
// pixel; 64 lanes span C; __shfl_xor tree reduce. Invalid taps keep energy 0
// (they participate in softmax, matching torch unfold zero-padding).
// ---------------------------------------------------------------------------
template<int C, int WDIM>
__global__ __launch_bounds__(256)
void att_hw(const f16* __restrict__ q, const f16* __restrict__ k,
            float* __restrict__ att)
{
    const int HW = WDIM * WDIM;
    const int wave = threadIdx.x >> 6, lane = threadIdx.x & 63;
    const int l = blockIdx.x * 4 + wave;
    const int bb = blockIdx.y;
    const int y = l / WDIM, x = l % WDIM;
    int offs[9]; bool val[9];
#pragma unroll
    for (int t = 0; t < 9; t++) {
        int aa = t / 3, bj = t % 3;
        int yy = y + 2 * aa - 2, xx = x + 2 * bj - 2;
        val[t] = (yy >= 0 && yy < WDIM && xx >= 0 && xx < WDIM);
        offs[t] = val[t] ? yy * WDIM + xx : 0;
    }
    const int NC = C / 64;
    float qv[NC];
    const f16* qr = q + ((long)bb * HW + l) * C;
#pragma unroll
    for (int ch = 0; ch < NC; ch++) qv[ch] = (float)qr[lane + ch * 64];
    const f16* kb = k + (long)bb * HW * C;
    float e[9];
#pragma unroll
    for (int t = 0; t < 9; t++) {
        float s = 0.f;
        if (val[t]) {
            const f16* kr = kb + (long)offs[t] * C;
#pragma unroll
            for (int ch = 0; ch < NC; ch++)
                s = fmaf(qv[ch], (float)kr[lane + ch * 64], s);
#pragma unroll
            for (int msk = 1; msk < 64; msk <<= 1) s += __shfl_xor(s, msk);
        }
        e[t] = s;
    }
    float mx = e[0];
#pragma unroll
    for (int t = 1; t < 9; t++) mx = fmaxf(mx, e[t]);
    float ssum = 0.f; float a[9];
#pragma unroll
    for (int t = 0; t < 9; t++) { a[t] = expf(e[t] - mx); ssum += a[t]; }
    float inv = 1.f / ssum;
    long base = ((long)bb * HW + l) * 9;
    if (lane < 9) att[base + lane] = a[lane] * inv;
}

// out[b,l,c] = sum_t att * v[neigh] (NHWC f16)
__global__ __launch_bounds__(256)
void attout_h(const float* __restrict__ att, const f16* __restrict__ v,
              f16* __restrict__ out, int C, int H, int W)
{
    int HW = H * W;
    long total = 2L * HW * C;
    for (long i = blockIdx.x * 256L + threadIdx.x; i < total; i += (long)gridDim.x * 256) {
        int c = (int)(i % C); long t2 = i / C;
        int l = (int)(t2 % HW); int bb = (int)(t2 / HW);
        int y = l / W, x = l % W;
        long abase = ((long)bb * HW + l) * 9;
        const f16* vb = v + (long)bb * HW * C + c;
        float s = 0.f;
#pragma unroll
        for (int t = 0; t < 9; t++) {
            int aa = t / 3, bj = t % 3;
            int yy = y + 2 * aa - 2, xx = x + 2 * bj - 2;
            if (yy >= 0 && yy < H && xx >= 0 && xx < W)
                s = fmaf(att[abase + t], (float)vb[(long)(yy * W + xx) * C], s);
        }
        out[i] = (f16)s;
    }
}

// codeword squared norms — wave per codeword, shuffle reduce
__global__ void cc_k(const float* __restrict__ cw, float* __restrict__ cc, int D)
{
    int k = blockIdx.x;
    int lane = threadIdx.x;
    float s = 0.f;
    for (int d = lane; d < D; d += 64) { float v = cw[(long)k * D + d]; s += v * v; }
#pragma unroll
    for (int msk = 1; msk < 64; msk <<= 1) s += __shfl_xor(s, msk);
    if (lane == 0) cc[k] = s;
}

// soft-assign: x f16 NHWC, xc f16 [l][32] -> A f32 [l][32]
__global__ __launch_bounds__(256)
void assign_h(const f16* __restrict__ x, const f16* __restrict__ xc,
              const float* __restrict__ cc, const float* __restrict__ scale,
              float* __restrict__ A)
{
    int l = blockIdx.x * 256 + threadIdx.x;
    int bb = blockIdx.y;
    if (l >= 4096) return;
    const f16* xr = x + ((long)bb * 4096 + l) * 512;
    float xx = 0.f;
    for (int d = 0; d < 512; d += 8) {
        f16x8 v = *(const f16x8*)&xr[d];
#pragma unroll
        for (int j = 0; j < 8; j++) { float f = (float)v[j]; xx = fmaf(f, f, xx); }
    }
    const f16* xcr = xc + ((long)bb * 4096 + l) * 32;
    float e[32]; float mx = -1e30f;
#pragma unroll
    for (int k2 = 0; k2 < 32; k2++) {
        float dist = xx + cc[k2] - 2.f * (float)xcr[k2];
        float en = -scale[k2] * dist;
        e[k2] = en; mx = fmaxf(mx, en);
    }
    float s = 0.f;
#pragma unroll
    for (int k2 = 0; k2 < 32; k2++) { e[k2] = expf(e[k2] - mx); s += e[k2]; }
    float inv = 1.f / s;
    long base = ((long)bb * 4096 + l) * 32;
#pragma unroll
    for (int k2 = 0; k2 < 32; k2++) A[base + k2] = e[k2] * inv;
}

__global__ __launch_bounds__(256)
void asum_k(const float* __restrict__ A, float* __restrict__ Asum, int HW)
{
    int k2 = blockIdx.x, b = blockIdx.y;
    float s = 0.f;
    for (int l = threadIdx.x; l < HW; l += 256) s += A[((long)b * HW + l) * 32 + k2];
    __shared__ float sh[256];
    sh[threadIdx.x] = s;
    __syncthreads();
    for (int o = 128; o > 0; o >>= 1) {
        if (threadIdx.x < o) sh[threadIdx.x] += sh[threadIdx.x + o];
        __syncthreads();
    }
    if (threadIdx.x == 0) Asum[b * 32 + k2] = sh[0];
}

// Et partial GEMM: Etp[z][k2][d] = sum_{l in chunk} A[l][k2] * X[l][d]
__global__ __launch_bounds__(256)
void etg_k(const float* __restrict__ Af, const f16* __restrict__ Xh, float* __restrict__ Etp)
{
    int z = blockIdx.z; int b = z >> 4; int ch = z & 15;
    int kbase = ch * 256;
    const float* Ab = Af + (long)b * 4096 * 32;
    const f16* Xb = Xh + (long)b * 4096 * 512;
    int n0 = blockIdx.x * 64;
    __shared__ float As[16][65];
    __shared__ float Bs[16][64];
    int tid = threadIdx.x; int tx = tid & 15, ty = tid >> 4;
    float acc[4][4];
#pragma unroll
    for (int i = 0; i < 4; i++)
#pragma unroll
        for (int j = 0; j < 4; j++) acc[i][j] = 0.f;
    for (int k0 = 0; k0 < 256; k0 += 16) {
#pragma unroll
        for (int i = 0; i < 4; i++) {
            int idx = tid + i * 256;
            int kk = idx & 15, mm = idx >> 4;
            float vv = 0.f;
            if (mm < 32) vv = Ab[(long)(kbase + k0 + kk) * 32 + mm];
            As[kk][mm] = vv;
        }
#pragma unroll
        for (int i = 0; i < 4; i++) {
            int idx = tid + i * 256;
            int nn = idx & 63, kk = idx >> 6;
            Bs[kk][nn] = (float)Xb[(long)(kbase + k0 + kk) * 512 + n0 + nn];
        }
        __syncthreads();
#pragma unroll
        for (int kk = 0; kk < 16; kk++) {
            float a[4], bb2[4];
#pragma unroll
            for (int i = 0; i < 4; i++) a[i] = As[kk][ty + i * 16];
#pragma unroll
            for (int j = 0; j < 4; j++) bb2[j] = Bs[kk][tx + j * 16];
#pragma unroll
            for (int i = 0; i < 4; i++)
#pragma unroll
                for (int j = 0; j < 4; j++)
                    acc[i][j] = fmaf(a[i], bb2[j], acc[i][j]);
        }
        __syncthreads();
    }
    float* Ob = Etp + (long)z * 32 * 512;
#pragma unroll
    for (int i = 0; i < 4; i++) {
        int m = ty + i * 16;
        if (m >= 32) continue;
#pragma unroll
        for (int j = 0; j < 4; j++) Ob[(long)m * 512 + n0 + tx + j * 16] = acc[i][j];
    }
}

// E[b,k,d] = sum_chunks Etp - Asum*cw
__global__ void efix2_k(const float* __restrict__ Etp, const float* __restrict__ asumf,
                        const float* __restrict__ cwf, float* __restrict__ Ef)
{
    int i = blockIdx.x * 256 + threadIdx.x;
    if (i >= 2 * 32 * 512) return;
    int d = i % 512; int k2 = (i / 512) % 32; int bb = i / (512 * 32);
    float s = 0.f;
#pragma unroll
    for (int c2 = 0; c2 < 16; c2++) s += Etp[((long)(bb * 16 + c2) * 32 + k2) * 512 + d];
    Ef[i] = s - asumf[bb * 32 + k2] * cwf[k2 * 512 + d];
}

// BN stats (mean/var) per channel, f32 input (for E)
__global__ __launch_bounds__(256)
void bn_stats_k(const float* __restrict__ x, float* __restrict__ mv,
                int HW, int Nb, long strideN)
{
    int c = blockIdx.x;
    long total = (long)Nb * HW;
    float s = 0.f, s2 = 0.f;
    for (long i = threadIdx.x; i < total; i += 256) {
        int n = (int)(i / HW); int l = (int)(i % HW);
        float v = x[(long)n * strideN + (long)c * HW + l];
        s += v; s2 += v * v;
    }
    __shared__ float sh0[256], sh1[256];
    sh0[threadIdx.x] = s; sh1[threadIdx.x] = s2;
    __syncthreads();
    for (int o = 128; o > 0; o >>= 1) {
        if (threadIdx.x < o) { sh0[threadIdx.x] += sh0[threadIdx.x + o]; sh1[threadIdx.x] += sh1[threadIdx.x + o]; }
        __syncthreads();
    }
    if (threadIdx.x == 0) {
        float inv = 1.f / (float)total;
        float m = sh0[0] * inv;
        mv[2 * c] = m;
        mv[2 * c + 1] = sh1[0] * inv - m * m;
    }
}

// en[b,d] = mean_k relu(BN1d(E[b,k,d]))
__global__ __launch_bounds__(256)
void en_k(const float* __restrict__ E, const float* __restrict__ mv,
          const float* __restrict__ gK, const float* __restrict__ bK,
          float* __restrict__ en, int D)
{
    int i = blockIdx.x * 256 + threadIdx.x;
    if (i >= 2 * D) return;
    int b = i / D, d = i % D;
    float s = 0.f;
#pragma unroll
    for (int k2 = 0; k2 < 32; k2++) {
        float m = mv[2 * k2], vv = mv[2 * k2 + 1];
        float r = (E[((long)b * 32 + k2) * D + d] - m) * rsqrtf(vv + EPSBN) * gK[k2] + bK[k2];
        s += fmaxf(r, 0.f);
    }
    en[i] = s * (1.f / 32.f);
}

__global__ __launch_bounds__(256)
void fc_k(const float* __restrict__ W, const float* __restrict__ bias,
          const float* __restrict__ in, float* __restrict__ out,
          int O, int D, int mode)
{
    int o = blockIdx.x * 256 + threadIdx.x;
    int b = blockIdx.y;
    if (o >= O) return;
    const float* ib = in + (long)b * D;
    float s = bias[o];
    for (int d = 0; d < D; d++) s += W[(long)o * D + d] * ib[d];
    if (mode == 1) s = 1.f / (1.f + expf(-s));
    out[(long)b * O + o] = s;
}

// y = relu(feat * (1+gamma)), f16 NHWC
__global__ __launch_bounds__(256)
void ymul_h(const f16* __restrict__ feat, const float* __restrict__ gamma,
            f16* __restrict__ y)
{
    long total = 2L * 4096 * 512;
    for (long i = blockIdx.x * 256L + threadIdx.x; i < total; i += (long)gridDim.x * 256) {
        int c = (int)(i % 512);
        int bb = (int)(i / (4096L * 512));
        y[i] = (f16)fmaxf((float)feat[i] * (1.f + gamma[bb * 512 + c]), 0.f);
    }
}

static inline dim3 hgrid(int M, int N) { return dim3((N + 127) / 128, (M + 63) / 64, 2); }

extern "C" void kernel_launch(void* const* d_in, const int* in_sizes, int n_in,
                              void* d_out, int out_size, void* d_ws, size_t ws_size,
                              hipStream_t stream)
{
    (void)in_sizes; (void)n_in; (void)out_size; (void)ws_size;
    const float* c2  = (const float*)d_in[1];
    const float* c3  = (const float*)d_in[2];
    const float* c4  = (const float*)d_in[3];
    const float* wq4 = (const float*)d_in[7];
    const float* gq4 = (const float*)d_in[8];
    const float* bq4 = (const float*)d_in[9];
    const float* wk4 = (const float*)d_in[10];
    const float* gk4 = (const float*)d_in[11];
    const float* bk4 = (const float*)d_in[12];
    const float* wv4 = (const float*)d_in[13];
    const float* wq3 = (const float*)d_in[14];
    const float* gq3 = (const float*)d_in[15];
    const float* bq3 = (const float*)d_in[16];
    const float* wk3 = (const float*)d_in[17];
    const float* gk3 = (const float*)d_in[18];
    const float* bk3 = (const float*)d_in[19];
    const float* wv3 = (const float*)d_in[20];
    const float* w5  = (const float*)d_in[21];
    const float* g5  = (const float*)d_in[22];
    const float* b5  = (const float*)d_in[23];
    const float* we  = (const float*)d_in[24];
    const float* ge  = (const float*)d_in[25];
    const float* be  = (const float*)d_in[26];
    const float* cw  = (const float*)d_in[27];
    const float* scl = (const float*)d_in[28];
    const float* gK  = (const float*)d_in[29];
    const float* bK  = (const float*)d_in[30];
    const float* wfc = (const float*)d_in[31];
    const float* bfc = (const float*)d_in[32];
    const float* wse = (const float*)d_in[33];
    const float* bse = (const float*)d_in[34];
    const float* w6  = (const float*)d_in[35];
    const float* b6  = (const float*)d_in[36];
    float* outp = (float*)d_out;
    char* ws = (char*)d_ws;

    // ---- workspace (byte offsets), liveness-checked overlays ----
    auto H = [&](long off) { return (f16*)(ws + off); };
    auto F = [&](long off) { return (float*)(ws + off); };
    const long O_wq4h = 0;
    const long O_wk4h = 262144;
    const long O_wv4h = 786432;
    const long O_wq3h = 4980736;
    const long O_wk3h = 5046272;
    const long O_wv3h = 5177344;
    const long O_w5r  = 6225920;
    const long O_weh  = 10944512;
    const long O_cwh  = 11468800;
    const long O_w6h  = 11501568;
    const long O_c3h  = 11665408;
    const long O_Xh   = 11665408;
    const long O_c4h  = 20054016;
    const long O_cku4h= 22151168;
    const long O_v3h  = 22151168;
    const long O_q4h  = 30539776;
    const long O_k4h  = 31064064;
    const long O_v4h  = 31588352;
    const long O_att3 = 30539776;
    const long O_xch  = 30834688;
    const long O_Af   = 31358976;
    const long O_Etp  = 32407552;
    const long O_Ef   = 34504704;
    const long O_asum = 34635776;
    const long O_cc   = 34636032;
    const long O_en   = 34636160;
    const long O_gam  = 34640256;
    const long O_mv   = 34644352;
    const long O_att4 = 35782656;
    const long O_out4h= 35856384;
    const long O_yh   = 35856384;
    const long O_c2h  = 40050688;
    const long O_cku3h= 48439296;
    const long O_feath= 48439296;
    const long O_out3h= 56827904;
    const long O_q3h  = 65216512;
    const long O_k3h  = 66265088;

    float* mv = F(O_mv);

    // ---- conversions ----
    chw2nhwc_k<<<dim3(128, 16, 2), 256, 0, stream>>>(c2, H(O_c2h), 512, 4096);
    chw2nhwc_k<<<dim3(32, 32, 2), 256, 0, stream>>>(c3, H(O_c3h), 1024, 1024);
    chw2nhwc_k<<<dim3(8, 64, 2), 256, 0, stream>>>(c4, H(O_c4h), 2048, 256);
    auto cvt = [&](const float* s, long o, long n) {
        f2h_k<<<(int)((n + 255) / 256), 256, 0, stream>>>(s, H(o), n);
    };
    cvt(wq4, O_wq4h, 128L * 1024); cvt(wk4, O_wk4h, 128L * 2048);
    cvt(wv4, O_wv4h, 1024L * 2048); cvt(wq3, O_wq3h, 64L * 512);
    cvt(wk3, O_wk3h, 64L * 1024); cvt(wv3, O_wv3h, 512L * 1024);
    cvt(we, O_weh, 512L * 512); cvt(cw, O_cwh, 32L * 512);
    cvt(w6, O_w6h, 150L * 512);
    w5r_k<<<9216, 256, 0, stream>>>(w5, H(O_w5r));
    zero_k<<<11, 256, 0, stream>>>(mv, 2816);

    // ---- Stage A: local_up(c3, c4) -> out4h (NHWC 2x1024x1024) ----
    hgemm_k<0><<<hgrid(128, 1024), 256, 0, stream>>>(H(O_wq4h), H(O_c3h), H(O_q4h), nullptr,
        128, 1024, 1024, 1024, 1024L * 1024, 1024L * 128, 0, 0, mv + 0);
    bnapply_k<<<128, 256, 0, stream>>>(H(O_q4h), mv + 0, gq4, bq4, 128, 2L * 1024 * 128, 1.f / 2048.f, 0);
    upsample_h<<<16384, 256, 0, stream>>>(H(O_c4h), H(O_cku4h), 2048, 16, 16, 32, 32);
    hgemm_k<0><<<hgrid(128, 1024), 256, 0, stream>>>(H(O_wk4h), H(O_cku4h), H(O_k4h), nullptr,
        128, 2048, 1024, 2048, 1024L * 2048, 1024L * 128, 0, 0, mv + 256);
    bnapply_k<<<128, 256, 0, stream>>>(H(O_k4h), mv + 256, gk4, bk4, 128, 2L * 1024 * 128, 1.f / 2048.f, 0);
    hgemm_k<0><<<hgrid(1024, 1024), 256, 0, stream>>>(H(O_wv4h), H(O_cku4h), H(O_v4h), nullptr,
        1024, 2048, 1024, 2048, 1024L * 2048, 1024L * 1024, 0, 0, nullptr);
    att_hw<128, 32><<<dim3(256, 2), 256, 0, stream>>>(H(O_q4h), H(O_k4h), F(O_att4));
    attout_h<<<8192, 256, 0, stream>>>(F(O_att4), H(O_v4h), H(O_out4h), 1024, 32, 32);

    // ---- Stage B: local_up(c2, out4) -> out3h (NHWC 2x4096x512) ----
    hgemm_k<0><<<hgrid(64, 4096), 256, 0, stream>>>(H(O_wq3h), H(O_c2h), H(O_q3h), nullptr,
        64, 512, 4096, 512, 4096L * 512, 4096L * 64, 0, 0, mv + 512);
    bnapply_k<<<256, 256, 0, stream>>>(H(O_q3h), mv + 512, gq3, bq3, 64, 2L * 4096 * 64, 1.f / 8192.f, 0);
    upsample_h<<<32768, 256, 0, stream>>>(H(O_out4h), H(O_cku3h), 1024, 32, 32, 64, 64);
    hgemm_k<0><<<hgrid(64, 4096), 256, 0, stream>>>(H(O_wk3h), H(O_cku3h), H(O_k3h), nullptr,
        64, 1024, 4096, 1024, 4096L * 1024, 4096L * 64, 0, 0, mv + 640);
    bnapply_k<<<256, 256, 0, stream>>>(H(O_k3h), mv + 640, gk3, bk3, 64, 2L * 4096 * 64, 1.f / 8192.f, 0);
    hgemm_k<0><<<hgrid(512, 4096), 256, 0, stream>>>(H(O_wv3h), H(O_cku3h), H(O_v3h), nullptr,
        512, 1024, 4096, 1024, 4096L * 1024, 4096L * 512, 0, 0, nullptr);
    att_hw<64, 64><<<dim3(1024, 2), 256, 0, stream>>>(H(O_q3h), H(O_k3h), F(O_att3));
    attout_h<<<16384, 256, 0, stream>>>(F(O_att3), H(O_v3h), H(O_out3h), 512, 64, 64);

    // ---- Stage C: feat = relu(BN(conv3x3(out3))) ----
    hgemm_k<1><<<hgrid(512, 4096), 256, 0, stream>>>(H(O_w5r), H(O_out3h), H(O_feath), nullptr,
        512, 4608, 4096, 512, 4096L * 512, 4096L * 512, 64, 64, mv + 768);
    bnapply_k<<<2048, 256, 0, stream>>>(H(O_feath), mv + 768, g5, b5, 512, 2L * 4096 * 512, 1.f / 8192.f, 1);

    // ---- Stage D: enc_module ----
    hgemm_k<0><<<hgrid(512, 4096), 256, 0, stream>>>(H(O_weh), H(O_feath), H(O_Xh), nullptr,
        512, 512, 4096, 512, 4096L * 512, 4096L * 512, 0, 0, mv + 1792);
    bnapply_k<<<2048, 256, 0, stream>>>(H(O_Xh), mv + 1792, ge, be, 512, 2L * 4096 * 512, 1.f / 8192.f, 1);
    hgemm_k<0><<<hgrid(32, 4096), 256, 0, stream>>>(H(O_cwh), H(O_Xh), H(O_xch), nullptr,
        32, 512, 4096, 512, 4096L * 512, 4096L * 32, 0, 0, nullptr);
    cc_k<<<32, 64, 0, stream>>>(cw, F(O_cc), 512);
    assign_h<<<dim3(16, 2), 256, 0, stream>>>(H(O_Xh), H(O_xch), F(O_cc), scl, F(O_Af));
    asum_k<<<dim3(32, 2), 256, 0, stream>>>(F(O_Af), F(O_asum), 4096);
    etg_k<<<dim3(8, 1, 32), 256, 0, stream>>>(F(O_Af), H(O_Xh), F(O_Etp));
    efix2_k<<<128, 256, 0, stream>>>(F(O_Etp), F(O_asum), cw, F(O_Ef));
    bn_stats_k<<<32, 256, 0, stream>>>(F(O_Ef), mv + 2816, 512, 2, 32L * 512);
    en_k<<<4, 256, 0, stream>>>(F(O_Ef), mv + 2816, gK, bK, F(O_en), 512);
    fc_k<<<dim3(2, 2), 256, 0, stream>>>(wfc, bfc, F(O_en), F(O_gam), 512, 512, 1);
    fc_k<<<dim3(1, 2), 256, 0, stream>>>(wse, bse, F(O_en), outp + 1228800, 150, 512, 0);
    ymul_h<<<16384, 256, 0, stream>>>(H(O_feath), F(O_gam), H(O_yh));

    // ---- Stage E: seg = w6 @ y + b6 -> d_out (CHW f32) ----
    hgemm_k<2><<<hgrid(150, 4096), 256, 0, stream>>>(H(O_w6h), H(O_yh), outp, b6,
        150, 512, 4096, 512, 4096L * 512, 150L * 4096, 0, 0, nullptr);
}

// Round 11
// 641.342 us; speedup vs baseline: 5.5422x; 1.0230x over previous
//
#include <hip/hip_runtime.h>
#include <math.h>

#define EPSBN 1e-5f

typedef _Float16 f16;
typedef _Float16 f16x8 __attribute__((ext_vector_type(8)));
typedef _Float16 f16x4 __attribute__((ext_vector_type(4)));
typedef float f32x4 __attribute__((ext_vector_type(4)));

static __device__ inline f16x8 h8zero() {
    f16x8 v;
#pragma unroll
    for (int j = 0; j < 8; j++) v[j] = (f16)0.f;
    return v;
}

// ---------------------------------------------------------------------------
// MFMA f16 GEMM, NHWC activations. D[m][n] = sum_k W[m][k] * act[n][k].
// BM=64, BN=128, BK=64. 4 waves (2x2), wave tile 32x64.
// 2-DEEP register pipeline: LOAD(t+2) issued at iter t (two static reg sets,
// loop unrolled x2 so all reg indexing is compile-time). Requires nt EVEN
// (all K used are multiples of 128). Pre-swizzled global source + linear LDS
// write + swizzled read. Optional fused BN column sums via shfl+atomicAdd.
// MODE 0: out f16 NHWC ([n][M]); MODE 1: conv3x3-d1 tap-shifted B (spatial
// HARDCODED 64x64); MODE 2: out f32 CHW ([m][N]) + bias.
// ---------------------------------------------------------------------------
template<int MODE>
__global__ __launch_bounds__(256)
void hgemm_k(const f16* __restrict__ Wh, const f16* __restrict__ act,
             void* __restrict__ outv, const float* __restrict__ bias,
             int M, int K, int N, int Cact, long actStride, long outStride,
             int IW, int IH, float* __restrict__ sums)
{
    const int b = blockIdx.z;
    const int n0 = blockIdx.x * 128, m0 = blockIdx.y * 64;
    const f16* actb = act + (long)b * actStride;
    __shared__ __align__(16) f16 As[2][64 * 64];
    __shared__ __align__(16) f16 Bs[2][128 * 64];
    const int tid = threadIdx.x;
    const int wave = tid >> 6, lane = tid & 63;
    const int wm = (wave >> 1) * 32, wn = (wave & 1) * 64;
    const int lr = lane & 15, lg = lane >> 4;
    f32x4 acc[2][4];
#pragma unroll
    for (int i = 0; i < 2; i++)
#pragma unroll
        for (int j = 0; j < 4; j++)
#pragma unroll
            for (int r = 0; r < 4; r++) acc[i][j][r] = 0.f;

    const int nt = K >> 6;           // EVEN for all shapes used
    f16x8 raA[2], rbA[4], raB[2], rbB[4];

    auto LOADA = [&](int t) {
        const int kt = t << 6;
#pragma unroll
        for (int u = 0; u < 2; u++) {
            int idx = u * 256 + tid;
            int row = idx >> 3, slot = idx & 7;
            int col = kt + ((slot ^ (row & 7)) << 3);
            int m = m0 + row;
            raA[u] = (m < M) ? *(const f16x8*)&Wh[(long)m * K + col] : h8zero();
        }
#pragma unroll
        for (int u = 0; u < 4; u++) {
            int idx = u * 256 + tid;
            int row = idx >> 3, slot = idx & 7;
            int scol = (slot ^ (row & 7)) << 3;
            int n = n0 + row;
            if (MODE == 1) {
                int tap = kt >> 9;
                int kc = (kt & 511) + scol;
                int dy = tap / 3 - 1, dx = tap % 3 - 1;
                int yy = (n >> 6) + dy, xx = (n & 63) + dx;   // 64x64 spatial
                rbA[u] = (yy >= 0 && yy < 64 && xx >= 0 && xx < 64)
                        ? *(const f16x8*)&actb[(long)((yy << 6) + xx) * Cact + kc]
                        : h8zero();
            } else {
                rbA[u] = *(const f16x8*)&actb[(long)n * Cact + kt + scol];
            }
        }
    };
    auto LOADB = [&](int t) {
        const int kt = t << 6;
#pragma unroll
        for (int u = 0; u < 2; u++) {
            int idx = u * 256 + tid;
            int row = idx >> 3, slot = idx & 7;
            int col = kt + ((slot ^ (row & 7)) << 3);
            int m = m0 + row;
            raB[u] = (m < M) ? *(const f16x8*)&Wh[(long)m * K + col] : h8zero();
        }
#pragma unroll
        for (int u = 0; u < 4; u++) {
            int idx = u * 256 + tid;
            int row = idx >> 3, slot = idx & 7;
            int scol = (slot ^ (row & 7)) << 3;
            int n = n0 + row;
            if (MODE == 1) {
                int tap = kt >> 9;
                int kc = (kt & 511) + scol;
                int dy = tap / 3 - 1, dx = tap % 3 - 1;
                int yy = (n >> 6) + dy, xx = (n & 63) + dx;
                rbB[u] = (yy >= 0 && yy < 64 && xx >= 0 && xx < 64)
                        ? *(const f16x8*)&actb[(long)((yy << 6) + xx) * Cact + kc]
                        : h8zero();
            } else {
                rbB[u] = *(const f16x8*)&actb[(long)n * Cact + kt + scol];
            }
        }
    };
    auto WRITEA = [&](int bufw) {
#pragma unroll
        for (int u = 0; u < 2; u++) {
            int idx = u * 256 + tid;
            int row = idx >> 3, slot = idx & 7;
            *(f16x8*)&As[bufw][(row * 8 + slot) * 8] = raA[u];
        }
#pragma unroll
        for (int u = 0; u < 4; u++) {
            int idx = u * 256 + tid;
            int row = idx >> 3, slot = idx & 7;
            *(f16x8*)&Bs[bufw][(row * 8 + slot) * 8] = rbA[u];
        }
    };
    auto WRITEB = [&](int bufw) {
#pragma unroll
        for (int u = 0; u < 2; u++) {
            int idx = u * 256 + tid;
            int row = idx >> 3, slot = idx & 7;
            *(f16x8*)&As[bufw][(row * 8 + slot) * 8] = raB[u];
        }
#pragma unroll
        for (int u = 0; u < 4; u++) {
            int idx = u * 256 + tid;
            int row = idx >> 3, slot = idx & 7;
            *(f16x8*)&Bs[bufw][(row * 8 + slot) * 8] = rbB[u];
        }
    };
    auto MFMA = [&](int bufr) {
#pragma unroll
        for (int s = 0; s < 2; s++) {
            f16x8 af[2], bf[4];
#pragma unroll
            for (int i = 0; i < 2; i++) {
                int r = wm + i * 16 + lr;
                af[i] = *(const f16x8*)&As[bufr][(r * 8 + ((s * 4 + lg) ^ (r & 7))) * 8];
            }
#pragma unroll
            for (int j = 0; j < 4; j++) {
                int r = wn + j * 16 + lr;
                bf[j] = *(const f16x8*)&Bs[bufr][(r * 8 + ((s * 4 + lg) ^ (r & 7))) * 8];
            }
#pragma unroll
            for (int i = 0; i < 2; i++)
#pragma unroll
                for (int j = 0; j < 4; j++)
                    acc[i][j] = __builtin_amdgcn_mfma_f32_16x16x32_f16(af[i], bf[j], acc[i][j], 0, 0, 0);
        }
    };

    // prologue: tile 0 -> LDS via setA; tile 1 loaded into setB
    LOADA(0); WRITEA(0); LOADB(1);
    __syncthreads();
    int buf = 0;
    for (int t = 0; t < nt; t += 2) {
        // even tile t in LDS[buf]; setB holds t+1
        if (t + 2 < nt) LOADA(t + 2);
        MFMA(buf);
        WRITEB(buf ^ 1);
        __syncthreads();
        buf ^= 1;
        // odd tile t+1 in LDS[buf]; setA holds t+2
        if (t + 3 < nt) LOADB(t + 3);
        MFMA(buf);
        if (t + 2 < nt) WRITEA(buf ^ 1);
        __syncthreads();
        buf ^= 1;
    }

    if (MODE == 2) {
        float* outp = (float*)outv + (long)b * outStride;
#pragma unroll
        for (int i = 0; i < 2; i++)
#pragma unroll
            for (int j = 0; j < 4; j++) {
                int n = n0 + wn + j * 16 + lr;
#pragma unroll
                for (int r = 0; r < 4; r++) {
                    int m = m0 + wm + i * 16 + lg * 4 + r;
                    if (m < M) outp[(long)m * N + n] = acc[i][j][r] + bias[m];
                }
            }
    } else {
        f16* outp = (f16*)outv + (long)b * outStride;
#pragma unroll
        for (int i = 0; i < 2; i++)
#pragma unroll
            for (int j = 0; j < 4; j++) {
                int n = n0 + wn + j * 16 + lr;
                int mb = m0 + wm + i * 16 + lg * 4;
                if (mb < M) {
                    f16x4 hv;
#pragma unroll
                    for (int r = 0; r < 4; r++) hv[r] = (f16)acc[i][j][r];
                    *(f16x4*)&outp[(long)n * M + mb] = hv;
                }
            }
        if (sums) {
#pragma unroll
            for (int i = 0; i < 2; i++)
#pragma unroll
                for (int r = 0; r < 4; r++) {
                    int m = m0 + wm + i * 16 + lg * 4 + r;
                    float s = 0.f, s2 = 0.f;
#pragma unroll
                    for (int j = 0; j < 4; j++) {
                        float v = (float)(f16)acc[i][j][r];   // rounded value
                        s += v; s2 += v * v;
                    }
#pragma unroll
                    for (int msk = 1; msk < 16; msk <<= 1) {
                        s += __shfl_xor(s, msk);
                        s2 += __shfl_xor(s2, msk);
                    }
                    if (lr == 0 && m < M) {
                        atomicAdd(&sums[2 * m], s);
                        atomicAdd(&sums[2 * m + 1], s2);
                    }
                }
        }
    }
}

// CHW f32 -> NHWC f16 tiled transpose (C, HW multiples of 32)
__global__ __launch_bounds__(256)
void chw2nhwc_k(const float* __restrict__ in, f16* __restrict__ out, int C, int HW)
{
    int b = blockIdx.z;
    int l0 = blockIdx.x * 32, c0 = blockIdx.y * 32;
    __shared__ float t[32][33];
    int tx = threadIdx.x & 31, ty = threadIdx.x >> 5;
    const float* ib = in + (long)b * C * HW;
#pragma unroll
    for (int j = 0; j < 4; j++) {
        int c = c0 + ty + j * 8;
        t[ty + j * 8][tx] = ib[(long)c * HW + l0 + tx];
    }
    __syncthreads();
    f16* ob = out + (long)b * HW * C;
#pragma unroll
    for (int j = 0; j < 4; j++) {
        int l = l0 + ty + j * 8;
        ob[(long)l * C + c0 + tx] = (f16)t[tx][ty + j * 8];
    }
}

// flat f32 -> f16
__global__ void f2h_k(const float* __restrict__ src, f16* __restrict__ dst, long n)
{
    long i = blockIdx.x * 256L + threadIdx.x;
    if (i < n) dst[i] = (f16)src[i];
}

// w5 (O,C,3,3) f32 -> w5r[O][tap][C] f16  (K ordered taps-outer, c-inner)
__global__ void w5r_k(const float* __restrict__ src, f16* __restrict__ dst)
{
    long i = blockIdx.x * 256L + threadIdx.x;
    if (i >= 9L * 512 * 512) return;
    int c = (int)(i % 512); long t2 = i / 512;
    int t = (int)(t2 % 9); int o = (int)(t2 / 9);
    dst[i] = (f16)src[(long)o * 4608 + c * 9 + t];
}

__global__ void zero_k(float* __restrict__ p, int n)
{
    int i = blockIdx.x * 256 + threadIdx.x;
    if (i < n) p[i] = 0.f;
}

// apply BN (from raw sums) elementwise, f16 in/out, 8 elems/thread
__global__ __launch_bounds__(256)
void bnapply_k(f16* __restrict__ x, const float* __restrict__ mv,
               const float* __restrict__ g, const float* __restrict__ bta,
               int C, long total, float inv, int dorelu)
{
    long i8 = (blockIdx.x * 256L + threadIdx.x) * 8;
    if (i8 >= total) return;
    int c0 = (int)(i8 % C);
    f16x8 v = *(f16x8*)&x[i8];
#pragma unroll
    for (int j = 0; j < 8; j++) {
        int c = c0 + j;
        float m = mv[2 * c] * inv;
        float var = mv[2 * c + 1] * inv - m * m;
        float r = ((float)v[j] - m) * rsqrtf(var + EPSBN) * g[c] + bta[c];
        if (dorelu) r = fmaxf(r, 0.f);
        v[j] = (f16)r;
    }
    *(f16x8*)&x[i8] = v;
}

// bilinear upsample align_corners=True, NHWC f16
__global__ __launch_bounds__(256)
void upsample_h(const f16* __restrict__ in, f16* __restrict__ out,
                int C, int H, int W, int OH, int OW)
{
    long total = 2L * C * OH * OW;
    float ry = (float)(H - 1) / (float)(OH - 1);
    float rx = (float)(W - 1) / (float)(OW - 1);
    for (long i = blockIdx.x * 256L + threadIdx.x; i < total; i += (long)gridDim.x * 256) {
        int c = (int)(i % C); long t = i / C;
        int l = (int)(t % (OH * OW)); int bb = (int)(t / (OH * OW));
        int oy = l / OW, ox = l % OW;
        float fy = oy * ry, fx = ox * rx;
        int y0 = (int)fy, x0 = (int)fx;
        int y1 = min(y0 + 1, H - 1), x1 = min(x0 + 1, W - 1);
        float wy = fy - y0, wx = fx - x0;
        const f16* p = in + (long)bb * H * W * C + c;
        float v00 = (float)p[(long)(y0 * W + x0) * C];
        float v01 = (float)p[(long)(y0 * W + x1) * C];
        float v10 = (float)p[(long)(y1 * W + x0) * C];
        float v11 = (float)p[(long)(y1 * W + x1) * C];
        out[i] = (f16)((v00 * (1.f - wx) + v01 * wx) * (1.f - wy) +
                       (v10 * (1.f - wx) + v11 * wx) * wy);
    }
}

// Wave-per-pixel energy+softmax over 9 dilated-2 taps.
template<int C, int WDIM>
__global__ __launch_bounds__(256)
void att_hw(const f16* __restrict__ q, const f16* __restrict__ k,
            float* __restrict__ att)
{
    const int HW = WDIM * WDIM;
    const int wave = threadIdx.x >> 6, lane = threadIdx.x & 63;
    const int l = blockIdx.x * 4 + wave;
    const int bb = blockIdx.y;
    const int y = l / WDIM, x = l % WDIM;
    int offs[9]; bool val[9];
#pragma unroll
    for (int t = 0; t < 9; t++) {
        int aa = t / 3, bj = t % 3;
        int yy = y + 2 * aa - 2, xx = x + 2 * bj - 2;
        val[t] = (yy >= 0 && yy < WDIM && xx >= 0 && xx < WDIM);
        offs[t] = val[t] ? yy * WDIM + xx : 0;
    }
    const int NC = C / 64;
    float qv[NC];
    const f16* qr = q + ((long)bb * HW + l) * C;
#pragma unroll
    for (int ch = 0; ch < NC; ch++) qv[ch] = (float)qr[lane + ch * 64];
    const f16* kb = k + (long)bb * HW * C;
    float e[9];
#pragma unroll
    for (int t = 0; t < 9; t++) {
        float s = 0.f;
        if (val[t]) {
            const f16* kr = kb + (long)offs[t] * C;
#pragma unroll
            for (int ch = 0; ch < NC; ch++)
                s = fmaf(qv[ch], (float)kr[lane + ch * 64], s);
#pragma unroll
            for (int msk = 1; msk < 64; msk <<= 1) s += __shfl_xor(s, msk);
        }
        e[t] = s;
    }
    float mx = e[0];
#pragma unroll
    for (int t = 1; t < 9; t++) mx = fmaxf(mx, e[t]);
    float ssum = 0.f; float a[9];
#pragma unroll
    for (int t = 0; t < 9; t++) { a[t] = expf(e[t] - mx); ssum += a[t]; }
    float inv = 1.f / ssum;
    long base = ((long)bb * HW + l) * 9;
    if (lane < 9) att[base + lane] = a[lane] * inv;
}

// out[b,l,c] = sum_t att * v[neigh] (NHWC f16)
__global__ __launch_bounds__(256)
void attout_h(const float* __restrict__ att, const f16* __restrict__ v,
              f16* __restrict__ out, int C, int H, int W)
{
    int HW = H * W;
    long total = 2L * HW * C;
    for (long i = blockIdx.x * 256L + threadIdx.x; i < total; i += (long)gridDim.x * 256) {
        int c = (int)(i % C); long t2 = i / C;
        int l = (int)(t2 % HW); int bb = (int)(t2 / HW);
        int y = l / W, x = l % W;
        long abase = ((long)bb * HW + l) * 9;
        const f16* vb = v + (long)bb * HW * C + c;
        float s = 0.f;
#pragma unroll
        for (int t = 0; t < 9; t++) {
            int aa = t / 3, bj = t % 3;
            int yy = y + 2 * aa - 2, xx = x + 2 * bj - 2;
            if (yy >= 0 && yy < H && xx >= 0 && xx < W)
                s = fmaf(att[abase + t], (float)vb[(long)(yy * W + xx) * C], s);
        }
        out[i] = (f16)s;
    }
}

// codeword squared norms — wave per codeword, shuffle reduce
__global__ void cc_k(const float* __restrict__ cw, float* __restrict__ cc, int D)
{
    int k = blockIdx.x;
    int lane = threadIdx.x;
    float s = 0.f;
    for (int d = lane; d < D; d += 64) { float v = cw[(long)k * D + d]; s += v * v; }
#pragma unroll
    for (int msk = 1; msk < 64; msk <<= 1) s += __shfl_xor(s, msk);
    if (lane == 0) cc[k] = s;
}

// soft-assign: x f16 NHWC, xc f16 [l][32] -> A f32 [l][32]
__global__ __launch_bounds__(256)
void assign_h(const f16* __restrict__ x, const f16* __restrict__ xc,
              const float* __restrict__ cc, const float* __restrict__ scale,
              float* __restrict__ A)
{
    int l = blockIdx.x * 256 + threadIdx.x;
    int bb = blockIdx.y;
    if (l >= 4096) return;
    const f16* xr = x + ((long)bb * 4096 + l) * 512;
    float xx = 0.f;
    for (int d = 0; d < 512; d += 8) {
        f16x8 v = *(const f16x8*)&xr[d];
#pragma unroll
        for (int j = 0; j < 8; j++) { float f = (float)v[j]; xx = fmaf(f, f, xx); }
    }
    const f16* xcr = xc + ((long)bb * 4096 + l) * 32;
    float e[32]; float mx = -1e30f;
#pragma unroll
    for (int k2 = 0; k2 < 32; k2++) {
        float dist = xx + cc[k2] - 2.f * (float)xcr[k2];
        float en = -scale[k2] * dist;
        e[k2] = en; mx = fmaxf(mx, en);
    }
    float s = 0.f;
#pragma unroll
    for (int k2 = 0; k2 < 32; k2++) { e[k2] = expf(e[k2] - mx); s += e[k2]; }
    float inv = 1.f / s;
    long base = ((long)bb * 4096 + l) * 32;
#pragma unroll
    for (int k2 = 0; k2 < 32; k2++) A[base + k2] = e[k2] * inv;
}

__global__ __launch_bounds__(256)
void asum_k(const float* __restrict__ A, float* __restrict__ Asum, int HW)
{
    int k2 = blockIdx.x, b = blockIdx.y;
    float s = 0.f;
    for (int l = threadIdx.x; l < HW; l += 256) s += A[((long)b * HW + l) * 32 + k2];
    __shared__ float sh[256];
    sh[threadIdx.x] = s;
    __syncthreads();
    for (int o = 128; o > 0; o >>= 1) {
        if (threadIdx.x < o) sh[threadIdx.x] += sh[threadIdx.x + o];
        __syncthreads();
    }
    if (threadIdx.x == 0) Asum[b * 32 + k2] = sh[0];
}

// Et partial GEMM: Etp[z][k2][d] = sum_{l in chunk} A[l][k2] * X[l][d]
__global__ __launch_bounds__(256)
void etg_k(const float* __restrict__ Af, const f16* __restrict__ Xh, float* __restrict__ Etp)
{
    int z = blockIdx.z; int b = z >> 4; int ch = z & 15;
    int kbase = ch * 256;
    const float* Ab = Af + (long)b * 4096 * 32;
    const f16* Xb = Xh + (long)b * 4096 * 512;
    int n0 = blockIdx.x * 64;
    __shared__ float As[16][65];
    __shared__ float Bs[16][64];
    int tid = threadIdx.x; int tx = tid & 15, ty = tid >> 4;
    float acc[4][4];
#pragma unroll
    for (int i = 0; i < 4; i++)
#pragma unroll
        for (int j = 0; j < 4; j++) acc[i][j] = 0.f;
    for (int k0 = 0; k0 < 256; k0 += 16) {
#pragma unroll
        for (int i = 0; i < 4; i++) {
            int idx = tid + i * 256;
            int kk = idx & 15, mm = idx >> 4;
            float vv = 0.f;
            if (mm < 32) vv = Ab[(long)(kbase + k0 + kk) * 32 + mm];
            As[kk][mm] = vv;
        }
#pragma unroll
        for (int i = 0; i < 4; i++) {
            int idx = tid + i * 256;
            int nn = idx & 63, kk = idx >> 6;
            Bs[kk][nn] = (float)Xb[(long)(kbase + k0 + kk) * 512 + n0 + nn];
        }
        __syncthreads();
#pragma unroll
        for (int kk = 0; kk < 16; kk++) {
            float a[4], bb2[4];
#pragma unroll
            for (int i = 0; i < 4; i++) a[i] = As[kk][ty + i * 16];
#pragma unroll
            for (int j = 0; j < 4; j++) bb2[j] = Bs[kk][tx + j * 16];
#pragma unroll
            for (int i = 0; i < 4; i++)
#pragma unroll
                for (int j = 0; j < 4; j++)
                    acc[i][j] = fmaf(a[i], bb2[j], acc[i][j]);
        }
        __syncthreads();
    }
    float* Ob = Etp + (long)z * 32 * 512;
#pragma unroll
    for (int i = 0; i < 4; i++) {
        int m = ty + i * 16;
        if (m >= 32) continue;
#pragma unroll
        for (int j = 0; j < 4; j++) Ob[(long)m * 512 + n0 + tx + j * 16] = acc[i][j];
    }
}

// E[b,k,d] = sum_chunks Etp - Asum*cw
__global__ void efix2_k(const float* __restrict__ Etp, const float* __restrict__ asumf,
                        const float* __restrict__ cwf, float* __restrict__ Ef)
{
    int i = blockIdx.x * 256 + threadIdx.x;
    if (i >= 2 * 32 * 512) return;
    int d = i % 512; int k2 = (i / 512) % 32; int bb = i / (512 * 32);
    float s = 0.f;
#pragma unroll
    for (int c2 = 0; c2 < 16; c2++) s += Etp[((long)(bb * 16 + c2) * 32 + k2) * 512 + d];
    Ef[i] = s - asumf[bb * 32 + k2] * cwf[k2 * 512 + d];
}

// BN stats (mean/var) per channel, f32 input (for E)
__global__ __launch_bounds__(256)
void bn_stats_k(const float* __restrict__ x, float* __restrict__ mv,
                int HW, int Nb, long strideN)
{
    int c = blockIdx.x;
    long total = (long)Nb * HW;
    float s = 0.f, s2 = 0.f;
    for (long i = threadIdx.x; i < total; i += 256) {
        int n = (int)(i / HW); int l = (int)(i % HW);
        float v = x[(long)n * strideN + (long)c * HW + l];
        s += v; s2 += v * v;
    }
    __shared__ float sh0[256], sh1[256];
    sh0[threadIdx.x] = s; sh1[threadIdx.x] = s2;
    __syncthreads();
    for (int o = 128; o > 0; o >>= 1) {
        if (threadIdx.x < o) { sh0[threadIdx.x] += sh0[threadIdx.x + o]; sh1[threadIdx.x] += sh1[threadIdx.x + o]; }
        __syncthreads();
    }
    if (threadIdx.x == 0) {
        float inv = 1.f / (float)total;
        float m = sh0[0] * inv;
        mv[2 * c] = m;
        mv[2 * c + 1] = sh1[0] * inv - m * m;
    }
}

// en[b,d] = mean_k relu(BN1d(E[b,k,d]))
__global__ __launch_bounds__(256)
void en_k(const float* __restrict__ E, const float* __restrict__ mv,
          const float* __restrict__ gK, const float* __restrict__ bK,
          float* __restrict__ en, int D)
{
    int i = blockIdx.x * 256 + threadIdx.x;
    if (i >= 2 * D) return;
    int b = i / D, d = i % D;
    float s = 0.f;
#pragma unroll
    for (int k2 = 0; k2 < 32; k2++) {
        float m = mv[2 * k2], vv = mv[2 * k2 + 1];
        float r = (E[((long)b * 32 + k2) * D + d] - m) * rsqrtf(vv + EPSBN) * gK[k2] + bK[k2];
        s += fmaxf(r, 0.f);
    }
    en[i] = s * (1.f / 32.f);
}

__global__ __launch_bounds__(256)
void fc_k(const float* __restrict__ W, const float* __restrict__ bias,
          const float* __restrict__ in, float* __restrict__ out,
          int O, int D, int mode)
{
    int o = blockIdx.x * 256 + threadIdx.x;
    int b = blockIdx.y;
    if (o >= O) return;
    const float* ib = in + (long)b * D;
    float s = bias[o];
    for (int d = 0; d < D; d++) s += W[(long)o * D + d] * ib[d];
    if (mode == 1) s = 1.f / (1.f + expf(-s));
    out[(long)b * O + o] = s;
}

// y = relu(feat * (1+gamma)), f16 NHWC
__global__ __launch_bounds__(256)
void ymul_h(const f16* __restrict__ feat, const float* __restrict__ gamma,
            f16* __restrict__ y)
{
    long total = 2L * 4096 * 512;
    for (long i = blockIdx.x * 256L + threadIdx.x; i < total; i += (long)gridDim.x * 256) {
        int c = (int)(i % 512);
        int bb = (int)(i / (4096L * 512));
        y[i] = (f16)fmaxf((float)feat[i] * (1.f + gamma[bb * 512 + c]), 0.f);
    }
}

static inline dim3 hgrid(int M, int N) { return dim3((N + 127) / 128, (M + 63) / 64, 2); }

extern "C" void kernel_launch(void* const* d_in, const int* in_sizes, int n_in,
                              void* d_out, int out_size, void* d_ws, size_t ws_size,
                              hipStream_t stream)
{
    (void)in_sizes; (void)n_in; (void)out_size; (void)ws_size;
    const float* c2  = (const float*)d_in[1];
    const float* c3  = (const float*)d_in[2];
    const float* c4  = (const float*)d_in[3];
    const float* wq4 = (const float*)d_in[7];
    const float* gq4 = (const float*)d_in[8];
    const float* bq4 = (const float*)d_in[9];
    const float* wk4 = (const float*)d_in[10];
    const float* gk4 = (const float*)d_in[11];
    const float* bk4 = (const float*)d_in[12];
    const float* wv4 = (const float*)d_in[13];
    const float* wq3 = (const float*)d_in[14];
    const float* gq3 = (const float*)d_in[15];
    const float* bq3 = (const float*)d_in[16];
    const float* wk3 = (const float*)d_in[17];
    const float* gk3 = (const float*)d_in[18];
    const float* bk3 = (const float*)d_in[19];
    const float* wv3 = (const float*)d_in[20];
    const float* w5  = (const float*)d_in[21];
    const float* g5  = (const float*)d_in[22];
    const float* b5  = (const float*)d_in[23];
    const float* we  = (const float*)d_in[24];
    const float* ge  = (const float*)d_in[25];
    const float* be  = (const float*)d_in[26];
    const float* cw  = (const float*)d_in[27];
    const float* scl = (const float*)d_in[28];
    const float* gK  = (const float*)d_in[29];
    const float* bK  = (const float*)d_in[30];
    const float* wfc = (const float*)d_in[31];
    const float* bfc = (const float*)d_in[32];
    const float* wse = (const float*)d_in[33];
    const float* bse = (const float*)d_in[34];
    const float* w6  = (const float*)d_in[35];
    const float* b6  = (const float*)d_in[36];
    float* outp = (float*)d_out;
    char* ws = (char*)d_ws;

    // ---- workspace (byte offsets), liveness-checked overlays ----
    auto H = [&](long off) { return (f16*)(ws + off); };
    auto F = [&](long off) { return (float*)(ws + off); };
    const long O_wq4h = 0;
    const long O_wk4h = 262144;
    const long O_wv4h = 786432;
    const long O_wq3h = 4980736;
    const long O_wk3h = 5046272;
    const long O_wv3h = 5177344;
    const long O_w5r  = 6225920;
    const long O_weh  = 10944512;
    const long O_cwh  = 11468800;
    const long O_w6h  = 11501568;
    const long O_c3h  = 11665408;
    const long O_Xh   = 11665408;
    const long O_c4h  = 20054016;
    const long O_cku4h= 22151168;
    const long O_v3h  = 22151168;
    const long O_q4h  = 30539776;
    const long O_k4h  = 31064064;
    const long O_v4h  = 31588352;
    const long O_att3 = 30539776;
    const long O_xch  = 30834688;
    const long O_Af   = 31358976;
    const long O_Etp  = 32407552;
    const long O_Ef   = 34504704;
    const long O_asum = 34635776;
    const long O_cc   = 34636032;
    const long O_en   = 34636160;
    const long O_gam  = 34640256;
    const long O_mv   = 34644352;
    const long O_att4 = 35782656;
    const long O_out4h= 35856384;
    const long O_yh   = 35856384;
    const long O_c2h  = 40050688;
    const long O_cku3h= 48439296;
    const long O_feath= 48439296;
    const long O_out3h= 56827904;
    const long O_q3h  = 65216512;
    const long O_k3h  = 66265088;

    float* mv = F(O_mv);

    // ---- conversions ----
    chw2nhwc_k<<<dim3(128, 16, 2), 256, 0, stream>>>(c2, H(O_c2h), 512, 4096);
    chw2nhwc_k<<<dim3(32, 32, 2), 256, 0, stream>>>(c3, H(O_c3h), 1024, 1024);
    chw2nhwc_k<<<dim3(8, 64, 2), 256, 0, stream>>>(c4, H(O_c4h), 2048, 256);
    auto cvt = [&](const float* s, long o, long n) {
        f2h_k<<<(int)((n + 255) / 256), 256, 0, stream>>>(s, H(o), n);
    };
    cvt(wq4, O_wq4h, 128L * 1024); cvt(wk4, O_wk4h, 128L * 2048);
    cvt(wv4, O_wv4h, 1024L * 2048); cvt(wq3, O_wq3h, 64L * 512);
    cvt(wk3, O_wk3h, 64L * 1024); cvt(wv3, O_wv3h, 512L * 1024);
    cvt(we, O_weh, 512L * 512); cvt(cw, O_cwh, 32L * 512);
    cvt(w6, O_w6h, 150L * 512);
    w5r_k<<<9216, 256, 0, stream>>>(w5, H(O_w5r));
    zero_k<<<11, 256, 0, stream>>>(mv, 2816);

    // ---- Stage A: local_up(c3, c4) -> out4h (NHWC 2x1024x1024) ----
    hgemm_k<0><<<hgrid(128, 1024), 256, 0, stream>>>(H(O_wq4h), H(O_c3h), H(O_q4h), nullptr,
        128, 1024, 1024, 1024, 1024L * 1024, 1024L * 128, 0, 0, mv + 0);
    bnapply_k<<<128, 256, 0, stream>>>(H(O_q4h), mv + 0, gq4, bq4, 128, 2L * 1024 * 128, 1.f / 2048.f, 0);
    upsample_h<<<16384, 256, 0, stream>>>(H(O_c4h), H(O_cku4h), 2048, 16, 16, 32, 32);
    hgemm_k<0><<<hgrid(128, 1024), 256, 0, stream>>>(H(O_wk4h), H(O_cku4h), H(O_k4h), nullptr,
        128, 2048, 1024, 2048, 1024L * 2048, 1024L * 128, 0, 0, mv + 256);
    bnapply_k<<<128, 256, 0, stream>>>(H(O_k4h), mv + 256, gk4, bk4, 128, 2L * 1024 * 128, 1.f / 2048.f, 0);
    hgemm_k<0><<<hgrid(1024, 1024), 256, 0, stream>>>(H(O_wv4h), H(O_cku4h), H(O_v4h), nullptr,
        1024, 2048, 1024, 2048, 1024L * 2048, 1024L * 1024, 0, 0, nullptr);
    att_hw<128, 32><<<dim3(256, 2), 256, 0, stream>>>(H(O_q4h), H(O_k4h), F(O_att4));
    attout_h<<<8192, 256, 0, stream>>>(F(O_att4), H(O_v4h), H(O_out4h), 1024, 32, 32);

    // ---- Stage B: local_up(c2, out4) -> out3h (NHWC 2x4096x512) ----
    hgemm_k<0><<<hgrid(64, 4096), 256, 0, stream>>>(H(O_wq3h), H(O_c2h), H(O_q3h), nullptr,
        64, 512, 4096, 512, 4096L * 512, 4096L * 64, 0, 0, mv + 512);
    bnapply_k<<<256, 256, 0, stream>>>(H(O_q3h), mv + 512, gq3, bq3, 64, 2L * 4096 * 64, 1.f / 8192.f, 0);
    upsample_h<<<32768, 256, 0, stream>>>(H(O_out4h), H(O_cku3h), 1024, 32, 32, 64, 64);
    hgemm_k<0><<<hgrid(64, 4096), 256, 0, stream>>>(H(O_wk3h), H(O_cku3h), H(O_k3h), nullptr,
        64, 1024, 4096, 1024, 4096L * 1024, 4096L * 64, 0, 0, mv + 640);
    bnapply_k<<<256, 256, 0, stream>>>(H(O_k3h), mv + 640, gk3, bk3, 64, 2L * 4096 * 64, 1.f / 8192.f, 0);
    hgemm_k<0><<<hgrid(512, 4096), 256, 0, stream>>>(H(O_wv3h), H(O_cku3h), H(O_v3h), nullptr,
        512, 1024, 4096, 1024, 4096L * 1024, 4096L * 512, 0, 0, nullptr);
    att_hw<64, 64><<<dim3(1024, 2), 256, 0, stream>>>(H(O_q3h), H(O_k3h), F(O_att3));
    attout_h<<<16384, 256, 0, stream>>>(F(O_att3), H(O_v3h), H(O_out3h), 512, 64, 64);

    // ---- Stage C: feat = relu(BN(conv3x3(out3))) ----
    hgemm_k<1><<<hgrid(512, 4096), 256, 0, stream>>>(H(O_w5r), H(O_out3h), H(O_feath), nullptr,
        512, 4608, 4096, 512, 4096L * 512, 4096L * 512, 64, 64, mv + 768);
    bnapply_k<<<2048, 256, 0, stream>>>(H(O_feath), mv + 768, g5, b5, 512, 2L * 4096 * 512, 1.f / 8192.f, 1);

    // ---- Stage D: enc_module ----
    hgemm_k<0><<<hgrid(512, 4096), 256, 0, stream>>>(H(O_weh), H(O_feath), H(O_Xh), nullptr,
        512, 512, 4096, 512, 4096L * 512, 4096L * 512, 0, 0, mv + 1792);
    bnapply_k<<<2048, 256, 0, stream>>>(H(O_Xh), mv + 1792, ge, be, 512, 2L * 4096 * 512, 1.f / 8192.f, 1);
    hgemm_k<0><<<hgrid(32, 4096), 256, 0, stream>>>(H(O_cwh), H(O_Xh), H(O_xch), nullptr,
        32, 512, 4096, 512, 4096L * 512, 4096L * 32, 0, 0, nullptr);
    cc_k<<<32, 64, 0, stream>>>(cw, F(O_cc), 512);
    assign_h<<<dim3(16, 2), 256, 0, stream>>>(H(O_Xh), H(O_xch), F(O_cc), scl, F(O_Af));
    asum_k<<<dim3(32, 2), 256, 0, stream>>>(F(O_Af), F(O_asum), 4096);
    etg_k<<<dim3(8, 1, 32), 256, 0, stream>>>(F(O_Af), H(O_Xh), F(O_Etp));
    efix2_k<<<128, 256, 0, stream>>>(F(O_Etp), F(O_asum), cw, F(O_Ef));
    bn_stats_k<<<32, 256, 0, stream>>>(F(O_Ef), mv + 2816, 512, 2, 32L * 512);
    en_k<<<4, 256, 0, stream>>>(F(O_Ef), mv + 2816, gK, bK, F(O_en), 512);
    fc_k<<<dim3(2, 2), 256, 0, stream>>>(wfc, bfc, F(O_en), F(O_gam), 512, 512, 1);
    fc_k<<<dim3(1, 2), 256, 0, stream>>>(wse, bse, F(O_en), outp + 1228800, 150, 512, 0);
    ymul_h<<<16384, 256, 0, stream>>>(H(O_feath), F(O_gam), H(O_yh));

    // ---- Stage E: seg = w6 @ y + b6 -> d_out (CHW f32) ----
    hgemm_k<2><<<hgrid(150, 4096), 256, 0, stream>>>(H(O_w6h), H(O_yh), outp, b6,
        150, 512, 4096, 512, 4096L * 512, 150L * 4096, 0, 0, nullptr);
}

// Round 14
// 593.662 us; speedup vs baseline: 5.9873x; 1.0803x over previous
//
#include <hip/hip_runtime.h>
#include <math.h>

#define EPSBN 1e-5f

typedef _Float16 f16;
typedef _Float16 f16x8 __attribute__((ext_vector_type(8)));
typedef _Float16 f16x4 __attribute__((ext_vector_type(4)));
typedef float f32x4 __attribute__((ext_vector_type(4)));

static __device__ inline f16x8 h8zero() {
    f16x8 v;
#pragma unroll
    for (int j = 0; j < 8; j++) v[j] = (f16)0.f;
    return v;
}

// ---------------------------------------------------------------------------
// MFMA f16 GEMM (r11-proven, byte-identical). BM=64, BN=128, BK=64.
// 2-DEEP register pipeline, pre-swizzled source + linear LDS write + swizzled
// read. Optional fused BN column sums via shfl+atomicAdd.
// MODE 0: out f16 NHWC; MODE 1: conv3x3-d1 (spatial hardcoded 64x64);
// MODE 2: out f32 CHW + bias.
// ---------------------------------------------------------------------------
template<int MODE>
__global__ __launch_bounds__(256)
void hgemm_k(const f16* __restrict__ Wh, const f16* __restrict__ act,
             void* __restrict__ outv, const float* __restrict__ bias,
             int M, int K, int N, int Cact, long actStride, long outStride,
             int IW, int IH, float* __restrict__ sums)
{
    const int b = blockIdx.z;
    const int n0 = blockIdx.x * 128, m0 = blockIdx.y * 64;
    const f16* actb = act + (long)b * actStride;
    __shared__ __align__(16) f16 As[2][64 * 64];
    __shared__ __align__(16) f16 Bs[2][128 * 64];
    const int tid = threadIdx.x;
    const int wave = tid >> 6, lane = tid & 63;
    const int wm = (wave >> 1) * 32, wn = (wave & 1) * 64;
    const int lr = lane & 15, lg = lane >> 4;
    f32x4 acc[2][4];
#pragma unroll
    for (int i = 0; i < 2; i++)
#pragma unroll
        for (int j = 0; j < 4; j++)
#pragma unroll
            for (int r = 0; r < 4; r++) acc[i][j][r] = 0.f;

    const int nt = K >> 6;           // EVEN for all shapes used
    f16x8 raA[2], rbA[4], raB[2], rbB[4];

    auto LOADA = [&](int t) {
        const int kt = t << 6;
#pragma unroll
        for (int u = 0; u < 2; u++) {
            int idx = u * 256 + tid;
            int row = idx >> 3, slot = idx & 7;
            int col = kt + ((slot ^ (row & 7)) << 3);
            int m = m0 + row;
            raA[u] = (m < M) ? *(const f16x8*)&Wh[(long)m * K + col] : h8zero();
        }
#pragma unroll
        for (int u = 0; u < 4; u++) {
            int idx = u * 256 + tid;
            int row = idx >> 3, slot = idx & 7;
            int scol = (slot ^ (row & 7)) << 3;
            int n = n0 + row;
            if (MODE == 1) {
                int tap = kt >> 9;
                int kc = (kt & 511) + scol;
                int dy = tap / 3 - 1, dx = tap % 3 - 1;
                int yy = (n >> 6) + dy, xx = (n & 63) + dx;   // 64x64 spatial
                rbA[u] = (yy >= 0 && yy < 64 && xx >= 0 && xx < 64)
                        ? *(const f16x8*)&actb[(long)((yy << 6) + xx) * Cact + kc]
                        : h8zero();
            } else {
                rbA[u] = *(const f16x8*)&actb[(long)n * Cact + kt + scol];
            }
        }
    };
    auto LOADB = [&](int t) {
        const int kt = t << 6;
#pragma unroll
        for (int u = 0; u < 2; u++) {
            int idx = u * 256 + tid;
            int row = idx >> 3, slot = idx & 7;
            int col = kt + ((slot ^ (row & 7)) << 3);
            int m = m0 + row;
            raB[u] = (m < M) ? *(const f16x8*)&Wh[(long)m * K + col] : h8zero();
        }
#pragma unroll
        for (int u = 0; u < 4; u++) {
            int idx = u * 256 + tid;
            int row = idx >> 3, slot = idx & 7;
            int scol = (slot ^ (row & 7)) << 3;
            int n = n0 + row;
            if (MODE == 1) {
                int tap = kt >> 9;
                int kc = (kt & 511) + scol;
                int dy = tap / 3 - 1, dx = tap % 3 - 1;
                int yy = (n >> 6) + dy, xx = (n & 63) + dx;
                rbB[u] = (yy >= 0 && yy < 64 && xx >= 0 && xx < 64)
                        ? *(const f16x8*)&actb[(long)((yy << 6) + xx) * Cact + kc]
                        : h8zero();
            } else {
                rbB[u] = *(const f16x8*)&actb[(long)n * Cact + kt + scol];
            }
        }
    };
    auto WRITEA = [&](int bufw) {
#pragma unroll
        for (int u = 0; u < 2; u++) {
            int idx = u * 256 + tid;
            int row = idx >> 3, slot = idx & 7;
            *(f16x8*)&As[bufw][(row * 8 + slot) * 8] = raA[u];
        }
#pragma unroll
        for (int u = 0; u < 4; u++) {
            int idx = u * 256 + tid;
            int row = idx >> 3, slot = idx & 7;
            *(f16x8*)&Bs[bufw][(row * 8 + slot) * 8] = rbA[u];
        }
    };
    auto WRITEB = [&](int bufw) {
#pragma unroll
        for (int u = 0; u < 2; u++) {
            int idx = u * 256 + tid;
            int row = idx >> 3, slot = idx & 7;
            *(f16x8*)&As[bufw][(row * 8 + slot) * 8] = raB[u];
        }
#pragma unroll
        for (int u = 0; u < 4; u++) {
            int idx = u * 256 + tid;
            int row = idx >> 3, slot = idx & 7;
            *(f16x8*)&Bs[bufw][(row * 8 + slot) * 8] = rbB[u];
        }
    };
    auto MFMA = [&](int bufr) {
#pragma unroll
        for (int s = 0; s < 2; s++) {
            f16x8 af[2], bf[4];
#pragma unroll
            for (int i = 0; i < 2; i++) {
                int r = wm + i * 16 + lr;
                af[i] = *(const f16x8*)&As[bufr][(r * 8 + ((s * 4 + lg) ^ (r & 7))) * 8];
            }
#pragma unroll
            for (int j = 0; j < 4; j++) {
                int r = wn + j * 16 + lr;
                bf[j] = *(const f16x8*)&Bs[bufr][(r * 8 + ((s * 4 + lg) ^ (r & 7))) * 8];
            }
#pragma unroll
            for (int i = 0; i < 2; i++)
#pragma unroll
                for (int j = 0; j < 4; j++)
                    acc[i][j] = __builtin_amdgcn_mfma_f32_16x16x32_f16(af[i], bf[j], acc[i][j], 0, 0, 0);
        }
    };

    LOADA(0); WRITEA(0); LOADB(1);
    __syncthreads();
    int buf = 0;
    for (int t = 0; t < nt; t += 2) {
        if (t + 2 < nt) LOADA(t + 2);
        MFMA(buf);
        WRITEB(buf ^ 1);
        __syncthreads();
        buf ^= 1;
        if (t + 3 < nt) LOADB(t + 3);
        MFMA(buf);
        if (t + 2 < nt) WRITEA(buf ^ 1);
        __syncthreads();
        buf ^= 1;
    }

    if (MODE == 2) {
        float* outp = (float*)outv + (long)b * outStride;
#pragma unroll
        for (int i = 0; i < 2; i++)
#pragma unroll
            for (int j = 0; j < 4; j++) {
                int n = n0 + wn + j * 16 + lr;
#pragma unroll
                for (int r = 0; r < 4; r++) {
                    int m = m0 + wm + i * 16 + lg * 4 + r;
                    if (m < M) outp[(long)m * N + n] = acc[i][j][r] + bias[m];
                }
            }
    } else {
        f16* outp = (f16*)outv + (long)b * outStride;
#pragma unroll
        for (int i = 0; i < 2; i++)
#pragma unroll
            for (int j = 0; j < 4; j++) {
                int n = n0 + wn + j * 16 + lr;
                int mb = m0 + wm + i * 16 + lg * 4;
                if (mb < M) {
                    f16x4 hv;
#pragma unroll
                    for (int r = 0; r < 4; r++) hv[r] = (f16)acc[i][j][r];
                    *(f16x4*)&outp[(long)n * M + mb] = hv;
                }
            }
        if (sums) {
#pragma unroll
            for (int i = 0; i < 2; i++)
#pragma unroll
                for (int r = 0; r < 4; r++) {
                    int m = m0 + wm + i * 16 + lg * 4 + r;
                    float s = 0.f, s2 = 0.f;
#pragma unroll
                    for (int j = 0; j < 4; j++) {
                        float v = (float)(f16)acc[i][j][r];   // rounded value
                        s += v; s2 += v * v;
                    }
#pragma unroll
                    for (int msk = 1; msk < 16; msk <<= 1) {
                        s += __shfl_xor(s, msk);
                        s2 += __shfl_xor(s2, msk);
                    }
                    if (lr == 0 && m < M) {
                        atomicAdd(&sums[2 * m], s);
                        atomicAdd(&sums[2 * m + 1], s2);
                    }
                }
        }
    }
}

// CHW f32 -> NHWC f16 tiled transpose (C, HW multiples of 32)
__global__ __launch_bounds__(256)
void chw2nhwc_k(const float* __restrict__ in, f16* __restrict__ out, int C, int HW)
{
    int b = blockIdx.z;
    int l0 = blockIdx.x * 32, c0 = blockIdx.y * 32;
    __shared__ float t[32][33];
    int tx = threadIdx.x & 31, ty = threadIdx.x >> 5;
    const float* ib = in + (long)b * C * HW;
#pragma unroll
    for (int j = 0; j < 4; j++) {
        int c = c0 + ty + j * 8;
        t[ty + j * 8][tx] = ib[(long)c * HW + l0 + tx];
    }
    __syncthreads();
    f16* ob = out + (long)b * HW * C;
#pragma unroll
    for (int j = 0; j < 4; j++) {
        int l = l0 + ty + j * 8;
        ob[(long)l * C + c0 + tx] = (f16)t[tx][ty + j * 8];
    }
}

// flat f32 -> f16
__global__ void f2h_k(const float* __restrict__ src, f16* __restrict__ dst, long n)
{
    long i = blockIdx.x * 256L + threadIdx.x;
    if (i < n) dst[i] = (f16)src[i];
}

// w5 (O,C,3,3) f32 -> w5r[O][tap][C] f16  (K ordered taps-outer, c-inner)
__global__ void w5r_k(const float* __restrict__ src, f16* __restrict__ dst)
{
    long i = blockIdx.x * 256L + threadIdx.x;
    if (i >= 9L * 512 * 512) return;
    int c = (int)(i % 512); long t2 = i / 512;
    int t = (int)(t2 % 9); int o = (int)(t2 / 9);
    dst[i] = (f16)src[(long)o * 4608 + c * 9 + t];
}

__global__ void zero_k(float* __restrict__ p, int n)
{
    int i = blockIdx.x * 256 + threadIdx.x;
    if (i < n) p[i] = 0.f;
}

// apply BN (from raw sums) elementwise, f16 in/out, 8 elems/thread
__global__ __launch_bounds__(256)
void bnapply_k(f16* __restrict__ x, const float* __restrict__ mv,
               const float* __restrict__ g, const float* __restrict__ bta,
               int C, long total, float inv, int dorelu)
{
    long i8 = (blockIdx.x * 256L + threadIdx.x) * 8;
    if (i8 >= total) return;
    int c0 = (int)(i8 % C);
    f16x8 v = *(f16x8*)&x[i8];
#pragma unroll
    for (int j = 0; j < 8; j++) {
        int c = c0 + j;
        float m = mv[2 * c] * inv;
        float var = mv[2 * c + 1] * inv - m * m;
        float r = ((float)v[j] - m) * rsqrtf(var + EPSBN) * g[c] + bta[c];
        if (dorelu) r = fmaxf(r, 0.f);
        v[j] = (f16)r;
    }
    *(f16x8*)&x[i8] = v;
}

// bilinear upsample align_corners=True, NHWC f16, 8 channels/thread
__global__ __launch_bounds__(256)
void upsample_h8(const f16* __restrict__ in, f16* __restrict__ out,
                 int C8, int H, int W, int OH, int OW)
{
    long total = 2L * C8 * OH * OW;
    float ry = (float)(H - 1) / (float)(OH - 1);
    float rx = (float)(W - 1) / (float)(OW - 1);
    int C = C8 * 8;
    for (long i = blockIdx.x * 256L + threadIdx.x; i < total; i += (long)gridDim.x * 256) {
        int c8 = (int)(i % C8); long t = i / C8;
        int l = (int)(t % (OH * OW)); int bb = (int)(t / (OH * OW));
        int oy = l / OW, ox = l % OW;
        float fy = oy * ry, fx = ox * rx;
        int y0 = (int)fy, x0 = (int)fx;
        int y1 = min(y0 + 1, H - 1), x1 = min(x0 + 1, W - 1);
        float wy = fy - y0, wx = fx - x0;
        const f16* p = in + (long)bb * H * W * C + c8 * 8;
        f16x8 v00 = *(const f16x8*)&p[(long)(y0 * W + x0) * C];
        f16x8 v01 = *(const f16x8*)&p[(long)(y0 * W + x1) * C];
        f16x8 v10 = *(const f16x8*)&p[(long)(y1 * W + x0) * C];
        f16x8 v11 = *(const f16x8*)&p[(long)(y1 * W + x1) * C];
        f16x8 o;
#pragma unroll
        for (int j = 0; j < 8; j++) {
            float top = (float)v00[j] * (1.f - wx) + (float)v01[j] * wx;
            float bot = (float)v10[j] * (1.f - wx) + (float)v11[j] * wx;
            o[j] = (f16)(top * (1.f - wy) + bot * wy);
        }
        *(f16x8*)&out[((long)bb * OH * OW + l) * C + c8 * 8] = o;
    }
}

// Wave-per-pixel energy+softmax over 9 dilated-2 taps (r11-proven).
template<int C, int WDIM>
__global__ __launch_bounds__(256)
void att_hw(const f16* __restrict__ q, const f16* __restrict__ k,
            float* __restrict__ att)
{
    const int HW = WDIM * WDIM;
    const int wave = threadIdx.x >> 6, lane = threadIdx.x & 63;
    const int l = blockIdx.x * 4 + wave;
    const int bb = blockIdx.y;
    const int y = l / WDIM, x = l % WDIM;
    int offs[9]; bool val[9];
#pragma unroll
    for (int t = 0; t < 9; t++) {
        int aa = t / 3, bj = t % 3;
        int yy = y + 2 * aa - 2, xx = x + 2 * bj - 2;
        val[t] = (yy >= 0 && yy < WDIM && xx >= 0 && xx < WDIM);
        offs[t] = val[t] ? yy * WDIM + xx : 0;
    }
    const int NC = C / 64;
    float qv[NC];
    const f16* qr = q + ((long)bb * HW + l) * C;
#pragma unroll
    for (int ch = 0; ch < NC; ch++) qv[ch] = (float)qr[lane + ch * 64];
    const f16* kb = k + (long)bb * HW * C;
    float e[9];
#pragma unroll
    for (int t = 0; t < 9; t++) {
        float s = 0.f;
        if (val[t]) {
            const f16* kr = kb + (long)offs[t] * C;
#pragma unroll
            for (int ch = 0; ch < NC; ch++)
                s = fmaf(qv[ch], (float)kr[lane + ch * 64], s);
#pragma unroll
            for (int msk = 1; msk < 64; msk <<= 1) s += __shfl_xor(s, msk);
        }
        e[t] = s;
    }
    float mx = e[0];
#pragma unroll
    for (int t = 1; t < 9; t++) mx = fmaxf(mx, e[t]);
    float ssum = 0.f; float a[9];
#pragma unroll
    for (int t = 0; t < 9; t++) { a[t] = expf(e[t] - mx); ssum += a[t]; }
    float inv = 1.f / ssum;
    long base = ((long)bb * HW + l) * 9;
    if (lane < 9) att[base + lane] = a[lane] * inv;
}

// out[b,l,c] = sum_t att * v[neigh] (NHWC f16) (r11-proven)
__global__ __launch_bounds__(256)
void attout_h(const float* __restrict__ att, const f16* __restrict__ v,
              f16* __restrict__ out, int C, int H, int W)
{
    int HW = H * W;
    long total = 2L * HW * C;
    for (long i = blockIdx.x * 256L + threadIdx.x; i < total; i += (long)gridDim.x * 256) {
        int c = (int)(i % C); long t2 = i / C;
        int l = (int)(t2 % HW); int bb = (int)(t2 / HW);
        int y = l / W, x = l % W;
        long abase = ((long)bb * HW + l) * 9;
        const f16* vb = v + (long)bb * HW * C + c;
        float s = 0.f;
#pragma unroll
        for (int t = 0; t < 9; t++) {
            int aa = t / 3, bj = t % 3;
            int yy = y + 2 * aa - 2, xx = x + 2 * bj - 2;
            if (yy >= 0 && yy < H && xx >= 0 && xx < W)
                s = fmaf(att[abase + t], (float)vb[(long)(yy * W + xx) * C], s);
        }
        out[i] = (f16)s;
    }
}

// codeword squared norms — wave per codeword, shuffle reduce
__global__ void cc_k(const float* __restrict__ cw, float* __restrict__ cc, int D)
{
    int k = blockIdx.x;
    int lane = threadIdx.x;
    float s = 0.f;
    for (int d = lane; d < D; d += 64) { float v = cw[(long)k * D + d]; s += v * v; }
#pragma unroll
    for (int msk = 1; msk < 64; msk <<= 1) s += __shfl_xor(s, msk);
    if (lane == 0) cc[k] = s;
}

// soft-assign: x f16 NHWC, xc f16 [l][32] -> A f32 [l][32]
__global__ __launch_bounds__(256)
void assign_h(const f16* __restrict__ x, const f16* __restrict__ xc,
              const float* __restrict__ cc, const float* __restrict__ scale,
              float* __restrict__ A)
{
    int l = blockIdx.x * 256 + threadIdx.x;
    int bb = blockIdx.y;
    if (l >= 4096) return;
    const f16* xr = x + ((long)bb * 4096 + l) * 512;
    float xx = 0.f;
    for (int d = 0; d < 512; d += 8) {
        f16x8 v = *(const f16x8*)&xr[d];
#pragma unroll
        for (int j = 0; j < 8; j++) { float f = (float)v[j]; xx = fmaf(f, f, xx); }
    }
    const f16* xcr = xc + ((long)bb * 4096 + l) * 32;
    float e[32]; float mx = -1e30f;
#pragma unroll
    for (int k2 = 0; k2 < 32; k2++) {
        float dist = xx + cc[k2] - 2.f * (float)xcr[k2];
        float en = -scale[k2] * dist;
        e[k2] = en; mx = fmaxf(mx, en);
    }
    float s = 0.f;
#pragma unroll
    for (int k2 = 0; k2 < 32; k2++) { e[k2] = expf(e[k2] - mx); s += e[k2]; }
    float inv = 1.f / s;
    long base = ((long)bb * 4096 + l) * 32;
#pragma unroll
    for (int k2 = 0; k2 < 32; k2++) A[base + k2] = e[k2] * inv;
}

__global__ __launch_bounds__(256)
void asum_k(const float* __restrict__ A, float* __restrict__ Asum, int HW)
{
    int k2 = blockIdx.x, b = blockIdx.y;
    float s = 0.f;
    for (int l = threadIdx.x; l < HW; l += 256) s += A[((long)b * HW + l) * 32 + k2];
    __shared__ float sh[256];
    sh[threadIdx.x] = s;
    __syncthreads();
    for (int o = 128; o > 0; o >>= 1) {
        if (threadIdx.x < o) sh[threadIdx.x] += sh[threadIdx.x + o];
        __syncthreads();
    }
    if (threadIdx.x == 0) Asum[b * 32 + k2] = sh[0];
}

// Et partial GEMM: Etp[z][k2][d] = sum_{l in chunk} A[l][k2] * X[l][d]
__global__ __launch_bounds__(256)
void etg_k(const float* __restrict__ Af, const f16* __restrict__ Xh, float* __restrict__ Etp)
{
    int z = blockIdx.z; int b = z >> 4; int ch = z & 15;
    int kbase = ch * 256;
    const float* Ab = Af + (long)b * 4096 * 32;
    const f16* Xb = Xh + (long)b * 4096 * 512;
    int n0 = blockIdx.x * 64;
    __shared__ float As[16][65];
    __shared__ float Bs[16][64];
    int tid = threadIdx.x; int tx = tid & 15, ty = tid >> 4;
    float acc[4][4];
#pragma unroll
    for (int i = 0; i < 4; i++)
#pragma unroll
        for (int j = 0; j < 4; j++) acc[i][j] = 0.f;
    for (int k0 = 0; k0 < 256; k0 += 16) {
#pragma unroll
        for (int i = 0; i < 4; i++) {
            int idx = tid + i * 256;
            int kk = idx & 15, mm = idx >> 4;
            float vv = 0.f;
            if (mm < 32) vv = Ab[(long)(kbase + k0 + kk) * 32 + mm];
            As[kk][mm] = vv;
        }
#pragma unroll
        for (int i = 0; i < 4; i++) {
            int idx = tid + i * 256;
            int nn = idx & 63, kk = idx >> 6;
            Bs[kk][nn] = (float)Xb[(long)(kbase + k0 + kk) * 512 + n0 + nn];
        }
        __syncthreads();
#pragma unroll
        for (int kk = 0; kk < 16; kk++) {
            float a[4], bb2[4];
#pragma unroll
            for (int i = 0; i < 4; i++) a[i] = As[kk][ty + i * 16];
#pragma unroll
            for (int j = 0; j < 4; j++) bb2[j] = Bs[kk][tx + j * 16];
#pragma unroll
            for (int i = 0; i < 4; i++)
#pragma unroll
                for (int j = 0; j < 4; j++)
                    acc[i][j] = fmaf(a[i], bb2[j], acc[i][j]);
        }
        __syncthreads();
    }
    float* Ob = Etp + (long)z * 32 * 512;
#pragma unroll
    for (int i = 0; i < 4; i++) {
        int m = ty + i * 16;
        if (m >= 32) continue;
#pragma unroll
        for (int j = 0; j < 4; j++) Ob[(long)m * 512 + n0 + tx + j * 16] = acc[i][j];
    }
}

// E[b,k,d] = sum_chunks Etp - Asum*cw
__global__ void efix2_k(const float* __restrict__ Etp, const float* __restrict__ asumf,
                        const float* __restrict__ cwf, float* __restrict__ Ef)
{
    int i = blockIdx.x * 256 + threadIdx.x;
    if (i >= 2 * 32 * 512) return;
    int d = i % 512; int k2 = (i / 512) % 32; int bb = i / (512 * 32);
    float s = 0.f;
#pragma unroll
    for (int c2 = 0; c2 < 16; c2++) s += Etp[((long)(bb * 16 + c2) * 32 + k2) * 512 + d];
    Ef[i] = s - asumf[bb * 32 + k2] * cwf[k2 * 512 + d];
}

// BN stats (mean/var) per channel, f32 input (for E)
__global__ __launch_bounds__(256)
void bn_stats_k(const float* __restrict__ x, float* __restrict__ mv,
                int HW, int Nb, long strideN)
{
    int c = blockIdx.x;
    long total = (long)Nb * HW;
    float s = 0.f, s2 = 0.f;
    for (long i = threadIdx.x; i < total; i += 256) {
        int n = (int)(i / HW); int l = (int)(i % HW);
        float v = x[(long)n * strideN + (long)c * HW + l];
        s += v; s2 += v * v;
    }
    __shared__ float sh0[256], sh1[256];
    sh0[threadIdx.x] = s; sh1[threadIdx.x] = s2;
    __syncthreads();
    for (int o = 128; o > 0; o >>= 1) {
        if (threadIdx.x < o) { sh0[threadIdx.x] += sh0[threadIdx.x + o]; sh1[threadIdx.x] += sh1[threadIdx.x + o]; }
        __syncthreads();
    }
    if (threadIdx.x == 0) {
        float inv = 1.f / (float)total;
        float m = sh0[0] * inv;
        mv[2 * c] = m;
        mv[2 * c + 1] = sh1[0] * inv - m * m;
    }
}

// en[b,d] = mean_k relu(BN1d(E[b,k,d]))
__global__ __launch_bounds__(256)
void en_k(const float* __restrict__ E, const float* __restrict__ mv,
          const float* __restrict__ gK, const float* __restrict__ bK,
          float* __restrict__ en, int D)
{
    int i = blockIdx.x * 256 + threadIdx.x;
    if (i >= 2 * D) return;
    int b = i / D, d = i % D;
    float s = 0.f;
#pragma unroll
    for (int k2 = 0; k2 < 32; k2++) {
        float m = mv[2 * k2], vv = mv[2 * k2 + 1];
        float r = (E[((long)b * 32 + k2) * D + d] - m) * rsqrtf(vv + EPSBN) * gK[k2] + bK[k2];
        s += fmaxf(r, 0.f);
    }
    en[i] = s * (1.f / 32.f);
}

__global__ __launch_bounds__(256)
void fc_k(const float* __restrict__ W, const float* __restrict__ bias,
          const float* __restrict__ in, float* __restrict__ out,
          int O, int D, int mode)
{
    int o = blockIdx.x * 256 + threadIdx.x;
    int b = blockIdx.y;
    if (o >= O) return;
    const float* ib = in + (long)b * D;
    float s = bias[o];
    for (int d = 0; d < D; d++) s += W[(long)o * D + d] * ib[d];
    if (mode == 1) s = 1.f / (1.f + expf(-s));
    out[(long)b * O + o] = s;
}

// y = relu(feat * (1+gamma)), f16 NHWC, 8/thread
__global__ __launch_bounds__(256)
void ymul_h(const f16* __restrict__ feat, const float* __restrict__ gamma,
            f16* __restrict__ y)
{
    long i8 = (blockIdx.x * 256L + threadIdx.x) * 8;
    if (i8 >= 2L * 4096 * 512) return;
    int c0 = (int)(i8 % 512);
    int bb = (int)(i8 / (4096L * 512));
    f16x8 v = *(const f16x8*)&feat[i8];
    f16x8 o;
#pragma unroll
    for (int j = 0; j < 8; j++)
        o[j] = (f16)fmaxf((float)v[j] * (1.f + gamma[bb * 512 + c0 + j]), 0.f);
    *(f16x8*)&y[i8] = o;
}

static inline dim3 hgrid(int M, int N) { return dim3((N + 127) / 128, (M + 63) / 64, 2); }

extern "C" void kernel_launch(void* const* d_in, const int* in_sizes, int n_in,
                              void* d_out, int out_size, void* d_ws, size_t ws_size,
                              hipStream_t stream)
{
    (void)in_sizes; (void)n_in; (void)out_size; (void)ws_size;
    const float* c2  = (const float*)d_in[1];
    const float* c3  = (const float*)d_in[2];
    const float* c4  = (const float*)d_in[3];
    const float* wq4 = (const float*)d_in[7];
    const float* gq4 = (const float*)d_in[8];
    const float* bq4 = (const float*)d_in[9];
    const float* wk4 = (const float*)d_in[10];
    const float* gk4 = (const float*)d_in[11];
    const float* bk4 = (const float*)d_in[12];
    const float* wv4 = (const float*)d_in[13];
    const float* wq3 = (const float*)d_in[14];
    const float* gq3 = (const float*)d_in[15];
    const float* bq3 = (const float*)d_in[16];
    const float* wk3 = (const float*)d_in[17];
    const float* gk3 = (const float*)d_in[18];
    const float* bk3 = (const float*)d_in[19];
    const float* wv3 = (const float*)d_in[20];
    const float* w5  = (const float*)d_in[21];
    const float* g5  = (const float*)d_in[22];
    const float* b5  = (const float*)d_in[23];
    const float* we  = (const float*)d_in[24];
    const float* ge  = (const float*)d_in[25];
    const float* be  = (const float*)d_in[26];
    const float* cw  = (const float*)d_in[27];
    const float* scl = (const float*)d_in[28];
    const float* gK  = (const float*)d_in[29];
    const float* bK  = (const float*)d_in[30];
    const float* wfc = (const float*)d_in[31];
    const float* bfc = (const float*)d_in[32];
    const float* wse = (const float*)d_in[33];
    const float* bse = (const float*)d_in[34];
    const float* w6  = (const float*)d_in[35];
    const float* b6  = (const float*)d_in[36];
    float* outp = (float*)d_out;
    char* ws = (char*)d_ws;

    // ---- workspace (byte offsets), liveness-checked overlays ----
    auto H = [&](long off) { return (f16*)(ws + off); };
    auto F = [&](long off) { return (float*)(ws + off); };
    const long O_wq4h = 0;
    const long O_wk4h = 262144;
    const long O_wv4h = 786432;
    const long O_wq3h = 4980736;
    const long O_wk3h = 5046272;
    const long O_wv3h = 5177344;
    const long O_w5r  = 6225920;
    const long O_weh  = 10944512;
    const long O_cwh  = 11468800;
    const long O_w6h  = 11501568;
    const long O_c3h  = 11665408;
    const long O_Xh   = 11665408;
    const long O_c4h  = 20054016;
    const long O_cku4h= 22151168;
    const long O_v3h  = 22151168;
    const long O_q4h  = 30539776;
    const long O_k4h  = 31064064;
    const long O_v4h  = 31588352;
    const long O_att3 = 30539776;
    const long O_xch  = 30834688;
    const long O_Af   = 31358976;
    const long O_Etp  = 32407552;
    const long O_Ef   = 34504704;
    const long O_asum = 34635776;
    const long O_cc   = 34636032;
    const long O_en   = 34636160;
    const long O_gam  = 34640256;
    const long O_mv   = 34644352;
    const long O_att4 = 35782656;
    const long O_out4h= 35856384;
    const long O_yh   = 35856384;
    const long O_c2h  = 40050688;
    const long O_cku3h= 48439296;
    const long O_feath= 48439296;
    const long O_out3h= 56827904;
    const long O_q3h  = 65216512;
    const long O_k3h  = 66265088;

    float* mv = F(O_mv);

    // ---- conversions ----
    chw2nhwc_k<<<dim3(128, 16, 2), 256, 0, stream>>>(c2, H(O_c2h), 512, 4096);
    chw2nhwc_k<<<dim3(32, 32, 2), 256, 0, stream>>>(c3, H(O_c3h), 1024, 1024);
    chw2nhwc_k<<<dim3(8, 64, 2), 256, 0, stream>>>(c4, H(O_c4h), 2048, 256);
    auto cvt = [&](const float* s, long o, long n) {
        f2h_k<<<(int)((n + 255) / 256), 256, 0, stream>>>(s, H(o), n);
    };
    cvt(wq4, O_wq4h, 128L * 1024); cvt(wk4, O_wk4h, 128L * 2048);
    cvt(wv4, O_wv4h, 1024L * 2048); cvt(wq3, O_wq3h, 64L * 512);
    cvt(wk3, O_wk3h, 64L * 1024); cvt(wv3, O_wv3h, 512L * 1024);
    cvt(we, O_weh, 512L * 512); cvt(cw, O_cwh, 32L * 512);
    cvt(w6, O_w6h, 150L * 512);
    w5r_k<<<9216, 256, 0, stream>>>(w5, H(O_w5r));
    zero_k<<<11, 256, 0, stream>>>(mv, 2816);

    // ---- Stage A: local_up(c3, c4) -> out4h (NHWC 2x1024x1024) ----
    hgemm_k<0><<<hgrid(128, 1024), 256, 0, stream>>>(H(O_wq4h), H(O_c3h), H(O_q4h), nullptr,
        128, 1024, 1024, 1024, 1024L * 1024, 1024L * 128, 0, 0, mv + 0);
    bnapply_k<<<128, 256, 0, stream>>>(H(O_q4h), mv + 0, gq4, bq4, 128, 2L * 1024 * 128, 1.f / 2048.f, 0);
    upsample_h8<<<2048, 256, 0, stream>>>(H(O_c4h), H(O_cku4h), 256, 16, 16, 32, 32);
    hgemm_k<0><<<hgrid(128, 1024), 256, 0, stream>>>(H(O_wk4h), H(O_cku4h), H(O_k4h), nullptr,
        128, 2048, 1024, 2048, 1024L * 2048, 1024L * 128, 0, 0, mv + 256);
    bnapply_k<<<128, 256, 0, stream>>>(H(O_k4h), mv + 256, gk4, bk4, 128, 2L * 1024 * 128, 1.f / 2048.f, 0);
    hgemm_k<0><<<hgrid(1024, 1024), 256, 0, stream>>>(H(O_wv4h), H(O_cku4h), H(O_v4h), nullptr,
        1024, 2048, 1024, 2048, 1024L * 2048, 1024L * 1024, 0, 0, nullptr);
    att_hw<128, 32><<<dim3(256, 2), 256, 0, stream>>>(H(O_q4h), H(O_k4h), F(O_att4));
    attout_h<<<8192, 256, 0, stream>>>(F(O_att4), H(O_v4h), H(O_out4h), 1024, 32, 32);

    // ---- Stage B: local_up(c2, out4) -> out3h (NHWC 2x4096x512) ----
    hgemm_k<0><<<hgrid(64, 4096), 256, 0, stream>>>(H(O_wq3h), H(O_c2h), H(O_q3h), nullptr,
        64, 512, 4096, 512, 4096L * 512, 4096L * 64, 0, 0, mv + 512);
    bnapply_k<<<256, 256, 0, stream>>>(H(O_q3h), mv + 512, gq3, bq3, 64, 2L * 4096 * 64, 1.f / 8192.f, 0);
    upsample_h8<<<4096, 256, 0, stream>>>(H(O_out4h), H(O_cku3h), 128, 32, 32, 64, 64);
    hgemm_k<0><<<hgrid(64, 4096), 256, 0, stream>>>(H(O_wk3h), H(O_cku3h), H(O_k3h), nullptr,
        64, 1024, 4096, 1024, 4096L * 1024, 4096L * 64, 0, 0, mv + 640);
    bnapply_k<<<256, 256, 0, stream>>>(H(O_k3h), mv + 640, gk3, bk3, 64, 2L * 4096 * 64, 1.f / 8192.f, 0);
    hgemm_k<0><<<hgrid(512, 4096), 256, 0, stream>>>(H(O_wv3h), H(O_cku3h), H(O_v3h), nullptr,
        512, 1024, 4096, 1024, 4096L * 1024, 4096L * 512, 0, 0, nullptr);
    att_hw<64, 64><<<dim3(1024, 2), 256, 0, stream>>>(H(O_q3h), H(O_k3h), F(O_att3));
    attout_h<<<16384, 256, 0, stream>>>(F(O_att3), H(O_v3h), H(O_out3h), 512, 64, 64);

    // ---- Stage C: feat = relu(BN(conv3x3(out3))) ----
    hgemm_k<1><<<hgrid(512, 4096), 256, 0, stream>>>(H(O_w5r), H(O_out3h), H(O_feath), nullptr,
        512, 4608, 4096, 512, 4096L * 512, 4096L * 512, 64, 64, mv + 768);
    bnapply_k<<<2048, 256, 0, stream>>>(H(O_feath), mv + 768, g5, b5, 512, 2L * 4096 * 512, 1.f / 8192.f, 1);

    // ---- Stage D: enc_module ----
    hgemm_k<0><<<hgrid(512, 4096), 256, 0, stream>>>(H(O_weh), H(O_feath), H(O_Xh), nullptr,
        512, 512, 4096, 512, 4096L * 512, 4096L * 512, 0, 0, mv + 1792);
    bnapply_k<<<2048, 256, 0, stream>>>(H(O_Xh), mv + 1792, ge, be, 512, 2L * 4096 * 512, 1.f / 8192.f, 1);
    hgemm_k<0><<<hgrid(32, 4096), 256, 0, stream>>>(H(O_cwh), H(O_Xh), H(O_xch), nullptr,
        32, 512, 4096, 512, 4096L * 512, 4096L * 32, 0, 0, nullptr);
    cc_k<<<32, 64, 0, stream>>>(cw, F(O_cc), 512);
    assign_h<<<dim3(16, 2), 256, 0, stream>>>(H(O_Xh), H(O_xch), F(O_cc), scl, F(O_Af));
    asum_k<<<dim3(32, 2), 256, 0, stream>>>(F(O_Af), F(O_asum), 4096);
    etg_k<<<dim3(8, 1, 32), 256, 0, stream>>>(F(O_Af), H(O_Xh), F(O_Etp));
    efix2_k<<<128, 256, 0, stream>>>(F(O_Etp), F(O_asum), cw, F(O_Ef));
    bn_stats_k<<<32, 256, 0, stream>>>(F(O_Ef), mv + 2816, 512, 2, 32L * 512);
    en_k<<<4, 256, 0, stream>>>(F(O_Ef), mv + 2816, gK, bK, F(O_en), 512);
    fc_k<<<dim3(2, 2), 256, 0, stream>>>(wfc, bfc, F(O_en), F(O_gam), 512, 512, 1);
    fc_k<<<dim3(1, 2), 256, 0, stream>>>(wse, bse, F(O_en), outp + 1228800, 150, 512, 0);
    ymul_h<<<2048, 256, 0, stream>>>(H(O_feath), F(O_gam), H(O_yh));

    // ---- Stage E: seg = w6 @ y + b6 -> d_out (CHW f32) ----
    hgemm_k<2><<<hgrid(150, 4096), 256, 0, stream>>>(H(O_w6h), H(O_yh), outp, b6,
        150, 512, 4096, 512, 4096L * 512, 150L * 4096, 0, 0, nullptr);
}

// Round 15
// 573.780 us; speedup vs baseline: 6.1948x; 1.0347x over previous
//
#include <hip/hip_runtime.h>
#include <math.h>

#define EPSBN 1e-5f

typedef _Float16 f16;
typedef _Float16 f16x8 __attribute__((ext_vector_type(8)));
typedef _Float16 f16x4 __attribute__((ext_vector_type(4)));
typedef _Float16 f16x2 __attribute__((ext_vector_type(2)));
typedef float f32x4 __attribute__((ext_vector_type(4)));

static __device__ inline f16x8 h8zero() {
    f16x8 v;
#pragma unroll
    for (int j = 0; j < 8; j++) v[j] = (f16)0.f;
    return v;
}

// ---------------------------------------------------------------------------
// MFMA f16 GEMM (r11-proven, byte-identical). BM=64, BN=128, BK=64.
// 2-DEEP register pipeline, pre-swizzled source + linear LDS write + swizzled
// read. Optional fused BN column sums via shfl+atomicAdd.
// MODE 0: out f16 NHWC; MODE 1: conv3x3-d1 (spatial hardcoded 64x64);
// MODE 2: out f32 CHW + bias.
// ---------------------------------------------------------------------------
template<int MODE>
__global__ __launch_bounds__(256)
void hgemm_k(const f16* __restrict__ Wh, const f16* __restrict__ act,
             void* __restrict__ outv, const float* __restrict__ bias,
             int M, int K, int N, int Cact, long actStride, long outStride,
             int IW, int IH, float* __restrict__ sums)
{
    const int b = blockIdx.z;
    const int n0 = blockIdx.x * 128, m0 = blockIdx.y * 64;
    const f16* actb = act + (long)b * actStride;
    __shared__ __align__(16) f16 As[2][64 * 64];
    __shared__ __align__(16) f16 Bs[2][128 * 64];
    const int tid = threadIdx.x;
    const int wave = tid >> 6, lane = tid & 63;
    const int wm = (wave >> 1) * 32, wn = (wave & 1) * 64;
    const int lr = lane & 15, lg = lane >> 4;
    f32x4 acc[2][4];
#pragma unroll
    for (int i = 0; i < 2; i++)
#pragma unroll
        for (int j = 0; j < 4; j++)
#pragma unroll
            for (int r = 0; r < 4; r++) acc[i][j][r] = 0.f;

    const int nt = K >> 6;           // EVEN for all shapes used
    f16x8 raA[2], rbA[4], raB[2], rbB[4];

    auto LOADA = [&](int t) {
        const int kt = t << 6;
#pragma unroll
        for (int u = 0; u < 2; u++) {
            int idx = u * 256 + tid;
            int row = idx >> 3, slot = idx & 7;
            int col = kt + ((slot ^ (row & 7)) << 3);
            int m = m0 + row;
            raA[u] = (m < M) ? *(const f16x8*)&Wh[(long)m * K + col] : h8zero();
        }
#pragma unroll
        for (int u = 0; u < 4; u++) {
            int idx = u * 256 + tid;
            int row = idx >> 3, slot = idx & 7;
            int scol = (slot ^ (row & 7)) << 3;
            int n = n0 + row;
            if (MODE == 1) {
                int tap = kt >> 9;
                int kc = (kt & 511) + scol;
                int dy = tap / 3 - 1, dx = tap % 3 - 1;
                int yy = (n >> 6) + dy, xx = (n & 63) + dx;   // 64x64 spatial
                rbA[u] = (yy >= 0 && yy < 64 && xx >= 0 && xx < 64)
                        ? *(const f16x8*)&actb[(long)((yy << 6) + xx) * Cact + kc]
                        : h8zero();
            } else {
                rbA[u] = *(const f16x8*)&actb[(long)n * Cact + kt + scol];
            }
        }
    };
    auto LOADB = [&](int t) {
        const int kt = t << 6;
#pragma unroll
        for (int u = 0; u < 2; u++) {
            int idx = u * 256 + tid;
            int row = idx >> 3, slot = idx & 7;
            int col = kt + ((slot ^ (row & 7)) << 3);
            int m = m0 + row;
            raB[u] = (m < M) ? *(const f16x8*)&Wh[(long)m * K + col] : h8zero();
        }
#pragma unroll
        for (int u = 0; u < 4; u++) {
            int idx = u * 256 + tid;
            int row = idx >> 3, slot = idx & 7;
            int scol = (slot ^ (row & 7)) << 3;
            int n = n0 + row;
            if (MODE == 1) {
                int tap = kt >> 9;
                int kc = (kt & 511) + scol;
                int dy = tap / 3 - 1, dx = tap % 3 - 1;
                int yy = (n >> 6) + dy, xx = (n & 63) + dx;
                rbB[u] = (yy >= 0 && yy < 64 && xx >= 0 && xx < 64)
                        ? *(const f16x8*)&actb[(long)((yy << 6) + xx) * Cact + kc]
                        : h8zero();
            } else {
                rbB[u] = *(const f16x8*)&actb[(long)n * Cact + kt + scol];
            }
        }
    };
    auto WRITEA = [&](int bufw) {
#pragma unroll
        for (int u = 0; u < 2; u++) {
            int idx = u * 256 + tid;
            int row = idx >> 3, slot = idx & 7;
            *(f16x8*)&As[bufw][(row * 8 + slot) * 8] = raA[u];
        }
#pragma unroll
        for (int u = 0; u < 4; u++) {
            int idx = u * 256 + tid;
            int row = idx >> 3, slot = idx & 7;
            *(f16x8*)&Bs[bufw][(row * 8 + slot) * 8] = rbA[u];
        }
    };
    auto WRITEB = [&](int bufw) {
#pragma unroll
        for (int u = 0; u < 2; u++) {
            int idx = u * 256 + tid;
            int row = idx >> 3, slot = idx & 7;
            *(f16x8*)&As[bufw][(row * 8 + slot) * 8] = raB[u];
        }
#pragma unroll
        for (int u = 0; u < 4; u++) {
            int idx = u * 256 + tid;
            int row = idx >> 3, slot = idx & 7;
            *(f16x8*)&Bs[bufw][(row * 8 + slot) * 8] = rbB[u];
        }
    };
    auto MFMA = [&](int bufr) {
#pragma unroll
        for (int s = 0; s < 2; s++) {
            f16x8 af[2], bf[4];
#pragma unroll
            for (int i = 0; i < 2; i++) {
                int r = wm + i * 16 + lr;
                af[i] = *(const f16x8*)&As[bufr][(r * 8 + ((s * 4 + lg) ^ (r & 7))) * 8];
            }
#pragma unroll
            for (int j = 0; j < 4; j++) {
                int r = wn + j * 16 + lr;
                bf[j] = *(const f16x8*)&Bs[bufr][(r * 8 + ((s * 4 + lg) ^ (r & 7))) * 8];
            }
#pragma unroll
            for (int i = 0; i < 2; i++)
#pragma unroll
                for (int j = 0; j < 4; j++)
                    acc[i][j] = __builtin_amdgcn_mfma_f32_16x16x32_f16(af[i], bf[j], acc[i][j], 0, 0, 0);
        }
    };

    LOADA(0); WRITEA(0); LOADB(1);
    __syncthreads();
    int buf = 0;
    for (int t = 0; t < nt; t += 2) {
        if (t + 2 < nt) LOADA(t + 2);
        MFMA(buf);
        WRITEB(buf ^ 1);
        __syncthreads();
        buf ^= 1;
        if (t + 3 < nt) LOADB(t + 3);
        MFMA(buf);
        if (t + 2 < nt) WRITEA(buf ^ 1);
        __syncthreads();
        buf ^= 1;
    }

    if (MODE == 2) {
        float* outp = (float*)outv + (long)b * outStride;
#pragma unroll
        for (int i = 0; i < 2; i++)
#pragma unroll
            for (int j = 0; j < 4; j++) {
                int n = n0 + wn + j * 16 + lr;
#pragma unroll
                for (int r = 0; r < 4; r++) {
                    int m = m0 + wm + i * 16 + lg * 4 + r;
                    if (m < M) outp[(long)m * N + n] = acc[i][j][r] + bias[m];
                }
            }
    } else {
        f16* outp = (f16*)outv + (long)b * outStride;
#pragma unroll
        for (int i = 0; i < 2; i++)
#pragma unroll
            for (int j = 0; j < 4; j++) {
                int n = n0 + wn + j * 16 + lr;
                int mb = m0 + wm + i * 16 + lg * 4;
                if (mb < M) {
                    f16x4 hv;
#pragma unroll
                    for (int r = 0; r < 4; r++) hv[r] = (f16)acc[i][j][r];
                    *(f16x4*)&outp[(long)n * M + mb] = hv;
                }
            }
        if (sums) {
#pragma unroll
            for (int i = 0; i < 2; i++)
#pragma unroll
                for (int r = 0; r < 4; r++) {
                    int m = m0 + wm + i * 16 + lg * 4 + r;
                    float s = 0.f, s2 = 0.f;
#pragma unroll
                    for (int j = 0; j < 4; j++) {
                        float v = (float)(f16)acc[i][j][r];   // rounded value
                        s += v; s2 += v * v;
                    }
#pragma unroll
                    for (int msk = 1; msk < 16; msk <<= 1) {
                        s += __shfl_xor(s, msk);
                        s2 += __shfl_xor(s2, msk);
                    }
                    if (lr == 0 && m < M) {
                        atomicAdd(&sums[2 * m], s);
                        atomicAdd(&sums[2 * m + 1], s2);
                    }
                }
        }
    }
}

// CHW f32 -> NHWC f16 tiled transpose (C, HW multiples of 32)
__global__ __launch_bounds__(256)
void chw2nhwc_k(const float* __restrict__ in, f16* __restrict__ out, int C, int HW)
{
    int b = blockIdx.z;
    int l0 = blockIdx.x * 32, c0 = blockIdx.y * 32;
    __shared__ float t[32][33];
    int tx = threadIdx.x & 31, ty = threadIdx.x >> 5;
    const float* ib = in + (long)b * C * HW;
#pragma unroll
    for (int j = 0; j < 4; j++) {
        int c = c0 + ty + j * 8;
        t[ty + j * 8][tx] = ib[(long)c * HW + l0 + tx];
    }
    __syncthreads();
    f16* ob = out + (long)b * HW * C;
#pragma unroll
    for (int j = 0; j < 4; j++) {
        int l = l0 + ty + j * 8;
        ob[(long)l * C + c0 + tx] = (f16)t[tx][ty + j * 8];
    }
}

// flat f32 -> f16
__global__ void f2h_k(const float* __restrict__ src, f16* __restrict__ dst, long n)
{
    long i = blockIdx.x * 256L + threadIdx.x;
    if (i < n) dst[i] = (f16)src[i];
}

// w5 (O,C,3,3) f32 -> w5r[O][tap][C] f16  (K ordered taps-outer, c-inner)
__global__ void w5r_k(const float* __restrict__ src, f16* __restrict__ dst)
{
    long i = blockIdx.x * 256L + threadIdx.x;
    if (i >= 9L * 512 * 512) return;
    int c = (int)(i % 512); long t2 = i / 512;
    int t = (int)(t2 % 9); int o = (int)(t2 / 9);
    dst[i] = (f16)src[(long)o * 4608 + c * 9 + t];
}

__global__ void zero_k(float* __restrict__ p, int n)
{
    int i = blockIdx.x * 256 + threadIdx.x;
    if (i < n) p[i] = 0.f;
}

// apply BN (from raw sums) elementwise, f16 in/out, 8 elems/thread
__global__ __launch_bounds__(256)
void bnapply_k(f16* __restrict__ x, const float* __restrict__ mv,
               const float* __restrict__ g, const float* __restrict__ bta,
               int C, long total, float inv, int dorelu)
{
    long i8 = (blockIdx.x * 256L + threadIdx.x) * 8;
    if (i8 >= total) return;
    int c0 = (int)(i8 % C);
    f16x8 v = *(f16x8*)&x[i8];
#pragma unroll
    for (int j = 0; j < 8; j++) {
        int c = c0 + j;
        float m = mv[2 * c] * inv;
        float var = mv[2 * c + 1] * inv - m * m;
        float r = ((float)v[j] - m) * rsqrtf(var + EPSBN) * g[c] + bta[c];
        if (dorelu) r = fmaxf(r, 0.f);
        v[j] = (f16)r;
    }
    *(f16x8*)&x[i8] = v;
}

// bilinear upsample align_corners=True, NHWC f16, 8 channels/thread
__global__ __launch_bounds__(256)
void upsample_h8(const f16* __restrict__ in, f16* __restrict__ out,
                 int C8, int H, int W, int OH, int OW)
{
    long total = 2L * C8 * OH * OW;
    float ry = (float)(H - 1) / (float)(OH - 1);
    float rx = (float)(W - 1) / (float)(OW - 1);
    int C = C8 * 8;
    for (long i = blockIdx.x * 256L + threadIdx.x; i < total; i += (long)gridDim.x * 256) {
        int c8 = (int)(i % C8); long t = i / C8;
        int l = (int)(t % (OH * OW)); int bb = (int)(t / (OH * OW));
        int oy = l / OW, ox = l % OW;
        float fy = oy * ry, fx = ox * rx;
        int y0 = (int)fy, x0 = (int)fx;
        int y1 = min(y0 + 1, H - 1), x1 = min(x0 + 1, W - 1);
        float wy = fy - y0, wx = fx - x0;
        const f16* p = in + (long)bb * H * W * C + c8 * 8;
        f16x8 v00 = *(const f16x8*)&p[(long)(y0 * W + x0) * C];
        f16x8 v01 = *(const f16x8*)&p[(long)(y0 * W + x1) * C];
        f16x8 v10 = *(const f16x8*)&p[(long)(y1 * W + x0) * C];
        f16x8 v11 = *(const f16x8*)&p[(long)(y1 * W + x1) * C];
        f16x8 o;
#pragma unroll
        for (int j = 0; j < 8; j++) {
            float top = (float)v00[j] * (1.f - wx) + (float)v01[j] * wx;
            float bot = (float)v10[j] * (1.f - wx) + (float)v11[j] * wx;
            o[j] = (f16)(top * (1.f - wy) + bot * wy);
        }
        *(f16x8*)&out[((long)bb * OH * OW + l) * C + c8 * 8] = o;
    }
}

// ---------------------------------------------------------------------------
// Fused energy+softmax+PV: att_hw's proven energy/softmax (q/k read POST-BN,
// no inline BN) + attout_h's PV math appended (f16x2 reads, all lanes hold
// identical a[] after the full shfl_xor butterfly). Wave per pixel.
// ---------------------------------------------------------------------------
template<int C, int CV, int WDIM>
__global__ __launch_bounds__(256)
void attpv_k(const f16* __restrict__ q, const f16* __restrict__ k,
             const f16* __restrict__ v, f16* __restrict__ out)
{
    const int HW = WDIM * WDIM;
    const int wave = threadIdx.x >> 6, lane = threadIdx.x & 63;
    const int l = blockIdx.x * 4 + wave;
    const int bb = blockIdx.y;
    const int y = l / WDIM, x = l % WDIM;
    int offs[9]; bool val[9];
#pragma unroll
    for (int t = 0; t < 9; t++) {
        int aa = t / 3, bj = t % 3;
        int yy = y + 2 * aa - 2, xx = x + 2 * bj - 2;
        val[t] = (yy >= 0 && yy < WDIM && xx >= 0 && xx < WDIM);
        offs[t] = val[t] ? yy * WDIM + xx : 0;
    }
    const int NC = C / 64;
    float qv[NC];
    const f16* qr = q + ((long)bb * HW + l) * C;
#pragma unroll
    for (int ch = 0; ch < NC; ch++) qv[ch] = (float)qr[lane + ch * 64];
    const f16* kb = k + (long)bb * HW * C;
    float e[9];
#pragma unroll
    for (int t = 0; t < 9; t++) {
        float s = 0.f;
        if (val[t]) {
            const f16* kr = kb + (long)offs[t] * C;
#pragma unroll
            for (int ch = 0; ch < NC; ch++)
                s = fmaf(qv[ch], (float)kr[lane + ch * 64], s);
#pragma unroll
            for (int msk = 1; msk < 64; msk <<= 1) s += __shfl_xor(s, msk);
        }
        e[t] = s;
    }
    float mx = e[0];
#pragma unroll
    for (int t = 1; t < 9; t++) mx = fmaxf(mx, e[t]);
    float ssum = 0.f; float a[9];
#pragma unroll
    for (int t = 0; t < 9; t++) { a[t] = expf(e[t] - mx); ssum += a[t]; }
    float inv = 1.f / ssum;
#pragma unroll
    for (int t = 0; t < 9; t++) a[t] *= inv;
    // PV: out[(bb*HW+l)*CV + c] = sum_t a[t] * v[(bb*HW+offs[t])*CV + c]
    const f16* vb = v + (long)bb * HW * CV;
    f16* ob = out + ((long)bb * HW + l) * CV;
#pragma unroll
    for (int ch = 0; ch < CV / 128; ch++) {
        int c = lane * 2 + ch * 128;
        float s0 = 0.f, s1 = 0.f;
#pragma unroll
        for (int t = 0; t < 9; t++) {
            if (!val[t]) continue;
            f16x2 vv = *(const f16x2*)&vb[(long)offs[t] * CV + c];
            s0 = fmaf(a[t], (float)vv[0], s0);
            s1 = fmaf(a[t], (float)vv[1], s1);
        }
        f16x2 o2; o2[0] = (f16)s0; o2[1] = (f16)s1;
        *(f16x2*)&ob[c] = o2;
    }
}

// codeword squared norms — wave per codeword, shuffle reduce
__global__ void cc_k(const float* __restrict__ cw, float* __restrict__ cc, int D)
{
    int k = blockIdx.x;
    int lane = threadIdx.x;
    float s = 0.f;
    for (int d = lane; d < D; d += 64) { float v = cw[(long)k * D + d]; s += v * v; }
#pragma unroll
    for (int msk = 1; msk < 64; msk <<= 1) s += __shfl_xor(s, msk);
    if (lane == 0) cc[k] = s;
}

// soft-assign: x f16 NHWC, xc f16 [l][32] -> A f32 [l][32]
__global__ __launch_bounds__(256)
void assign_h(const f16* __restrict__ x, const f16* __restrict__ xc,
              const float* __restrict__ cc, const float* __restrict__ scale,
              float* __restrict__ A)
{
    int l = blockIdx.x * 256 + threadIdx.x;
    int bb = blockIdx.y;
    if (l >= 4096) return;
    const f16* xr = x + ((long)bb * 4096 + l) * 512;
    float xx = 0.f;
    for (int d = 0; d < 512; d += 8) {
        f16x8 v = *(const f16x8*)&xr[d];
#pragma unroll
        for (int j = 0; j < 8; j++) { float f = (float)v[j]; xx = fmaf(f, f, xx); }
    }
    const f16* xcr = xc + ((long)bb * 4096 + l) * 32;
    float e[32]; float mx = -1e30f;
#pragma unroll
    for (int k2 = 0; k2 < 32; k2++) {
        float dist = xx + cc[k2] - 2.f * (float)xcr[k2];
        float en = -scale[k2] * dist;
        e[k2] = en; mx = fmaxf(mx, en);
    }
    float s = 0.f;
#pragma unroll
    for (int k2 = 0; k2 < 32; k2++) { e[k2] = expf(e[k2] - mx); s += e[k2]; }
    float inv = 1.f / s;
    long base = ((long)bb * 4096 + l) * 32;
#pragma unroll
    for (int k2 = 0; k2 < 32; k2++) A[base + k2] = e[k2] * inv;
}

__global__ __launch_bounds__(256)
void asum_k(const float* __restrict__ A, float* __restrict__ Asum, int HW)
{
    int k2 = blockIdx.x, b = blockIdx.y;
    float s = 0.f;
    for (int l = threadIdx.x; l < HW; l += 256) s += A[((long)b * HW + l) * 32 + k2];
    __shared__ float sh[256];
    sh[threadIdx.x] = s;
    __syncthreads();
    for (int o = 128; o > 0; o >>= 1) {
        if (threadIdx.x < o) sh[threadIdx.x] += sh[threadIdx.x + o];
        __syncthreads();
    }
    if (threadIdx.x == 0) Asum[b * 32 + k2] = sh[0];
}

// Et partial GEMM: Etp[z][k2][d] = sum_{l in chunk} A[l][k2] * X[l][d]
__global__ __launch_bounds__(256)
void etg_k(const float* __restrict__ Af, const f16* __restrict__ Xh, float* __restrict__ Etp)
{
    int z = blockIdx.z; int b = z >> 4; int ch = z & 15;
    int kbase = ch * 256;
    const float* Ab = Af + (long)b * 4096 * 32;
    const f16* Xb = Xh + (long)b * 4096 * 512;
    int n0 = blockIdx.x * 64;
    __shared__ float As[16][65];
    __shared__ float Bs[16][64];
    int tid = threadIdx.x; int tx = tid & 15, ty = tid >> 4;
    float acc[4][4];
#pragma unroll
    for (int i = 0; i < 4; i++)
#pragma unroll
        for (int j = 0; j < 4; j++) acc[i][j] = 0.f;
    for (int k0 = 0; k0 < 256; k0 += 16) {
#pragma unroll
        for (int i = 0; i < 4; i++) {
            int idx = tid + i * 256;
            int kk = idx & 15, mm = idx >> 4;
            float vv = 0.f;
            if (mm < 32) vv = Ab[(long)(kbase + k0 + kk) * 32 + mm];
            As[kk][mm] = vv;
        }
#pragma unroll
        for (int i = 0; i < 4; i++) {
            int idx = tid + i * 256;
            int nn = idx & 63, kk = idx >> 6;
            Bs[kk][nn] = (float)Xb[(long)(kbase + k0 + kk) * 512 + n0 + nn];
        }
        __syncthreads();
#pragma unroll
        for (int kk = 0; kk < 16; kk++) {
            float a[4], bb2[4];
#pragma unroll
            for (int i = 0; i < 4; i++) a[i] = As[kk][ty + i * 16];
#pragma unroll
            for (int j = 0; j < 4; j++) bb2[j] = Bs[kk][tx + j * 16];
#pragma unroll
            for (int i = 0; i < 4; i++)
#pragma unroll
                for (int j = 0; j < 4; j++)
                    acc[i][j] = fmaf(a[i], bb2[j], acc[i][j]);
        }
        __syncthreads();
    }
    float* Ob = Etp + (long)z * 32 * 512;
#pragma unroll
    for (int i = 0; i < 4; i++) {
        int m = ty + i * 16;
        if (m >= 32) continue;
#pragma unroll
        for (int j = 0; j < 4; j++) Ob[(long)m * 512 + n0 + tx + j * 16] = acc[i][j];
    }
}

// E[b,k,d] = sum_chunks Etp - Asum*cw
__global__ void efix2_k(const float* __restrict__ Etp, const float* __restrict__ asumf,
                        const float* __restrict__ cwf, float* __restrict__ Ef)
{
    int i = blockIdx.x * 256 + threadIdx.x;
    if (i >= 2 * 32 * 512) return;
    int d = i % 512; int k2 = (i / 512) % 32; int bb = i / (512 * 32);
    float s = 0.f;
#pragma unroll
    for (int c2 = 0; c2 < 16; c2++) s += Etp[((long)(bb * 16 + c2) * 32 + k2) * 512 + d];
    Ef[i] = s - asumf[bb * 32 + k2] * cwf[k2 * 512 + d];
}

// BN stats (mean/var) per channel, f32 input (for E)
__global__ __launch_bounds__(256)
void bn_stats_k(const float* __restrict__ x, float* __restrict__ mv,
                int HW, int Nb, long strideN)
{
    int c = blockIdx.x;
    long total = (long)Nb * HW;
    float s = 0.f, s2 = 0.f;
    for (long i = threadIdx.x; i < total; i += 256) {
        int n = (int)(i / HW); int l = (int)(i % HW);
        float v = x[(long)n * strideN + (long)c * HW + l];
        s += v; s2 += v * v;
    }
    __shared__ float sh0[256], sh1[256];
    sh0[threadIdx.x] = s; sh1[threadIdx.x] = s2;
    __syncthreads();
    for (int o = 128; o > 0; o >>= 1) {
        if (threadIdx.x < o) { sh0[threadIdx.x] += sh0[threadIdx.x + o]; sh1[threadIdx.x] += sh1[threadIdx.x + o]; }
        __syncthreads();
    }
    if (threadIdx.x == 0) {
        float inv = 1.f / (float)total;
        float m = sh0[0] * inv;
        mv[2 * c] = m;
        mv[2 * c + 1] = sh1[0] * inv - m * m;
    }
}

// en[b,d] = mean_k relu(BN1d(E[b,k,d]))
__global__ __launch_bounds__(256)
void en_k(const float* __restrict__ E, const float* __restrict__ mv,
          const float* __restrict__ gK, const float* __restrict__ bK,
          float* __restrict__ en, int D)
{
    int i = blockIdx.x * 256 + threadIdx.x;
    if (i >= 2 * D) return;
    int b = i / D, d = i % D;
    float s = 0.f;
#pragma unroll
    for (int k2 = 0; k2 < 32; k2++) {
        float m = mv[2 * k2], vv = mv[2 * k2 + 1];
        float r = (E[((long)b * 32 + k2) * D + d] - m) * rsqrtf(vv + EPSBN) * gK[k2] + bK[k2];
        s += fmaxf(r, 0.f);
    }
    en[i] = s * (1.f / 32.f);
}

__global__ __launch_bounds__(256)
void fc_k(const float* __restrict__ W, const float* __restrict__ bias,
          const float* __restrict__ in, float* __restrict__ out,
          int O, int D, int mode)
{
    int o = blockIdx.x * 256 + threadIdx.x;
    int b = blockIdx.y;
    if (o >= O) return;
    const float* ib = in + (long)b * D;
    float s = bias[o];
    for (int d = 0; d < D; d++) s += W[(long)o * D + d] * ib[d];
    if (mode == 1) s = 1.f / (1.f + expf(-s));
    out[(long)b * O + o] = s;
}

// y = relu(feat * (1+gamma)), f16 NHWC, 8/thread
__global__ __launch_bounds__(256)
void ymul_h(const f16* __restrict__ feat, const float* __restrict__ gamma,
            f16* __restrict__ y)
{
    long i8 = (blockIdx.x * 256L + threadIdx.x) * 8;
    if (i8 >= 2L * 4096 * 512) return;
    int c0 = (int)(i8 % 512);
    int bb = (int)(i8 / (4096L * 512));
    f16x8 v = *(const f16x8*)&feat[i8];
    f16x8 o;
#pragma unroll
    for (int j = 0; j < 8; j++)
        o[j] = (f16)fmaxf((float)v[j] * (1.f + gamma[bb * 512 + c0 + j]), 0.f);
    *(f16x8*)&y[i8] = o;
}

static inline dim3 hgrid(int M, int N) { return dim3((N + 127) / 128, (M + 63) / 64, 2); }

extern "C" void kernel_launch(void* const* d_in, const int* in_sizes, int n_in,
                              void* d_out, int out_size, void* d_ws, size_t ws_size,
                              hipStream_t stream)
{
    (void)in_sizes; (void)n_in; (void)out_size; (void)ws_size;
    const float* c2  = (const float*)d_in[1];
    const float* c3  = (const float*)d_in[2];
    const float* c4  = (const float*)d_in[3];
    const float* wq4 = (const float*)d_in[7];
    const float* gq4 = (const float*)d_in[8];
    const float* bq4 = (const float*)d_in[9];
    const float* wk4 = (const float*)d_in[10];
    const float* gk4 = (const float*)d_in[11];
    const float* bk4 = (const float*)d_in[12];
    const float* wv4 = (const float*)d_in[13];
    const float* wq3 = (const float*)d_in[14];
    const float* gq3 = (const float*)d_in[15];
    const float* bq3 = (const float*)d_in[16];
    const float* wk3 = (const float*)d_in[17];
    const float* gk3 = (const float*)d_in[18];
    const float* bk3 = (const float*)d_in[19];
    const float* wv3 = (const float*)d_in[20];
    const float* w5  = (const float*)d_in[21];
    const float* g5  = (const float*)d_in[22];
    const float* b5  = (const float*)d_in[23];
    const float* we  = (const float*)d_in[24];
    const float* ge  = (const float*)d_in[25];
    const float* be  = (const float*)d_in[26];
    const float* cw  = (const float*)d_in[27];
    const float* scl = (const float*)d_in[28];
    const float* gK  = (const float*)d_in[29];
    const float* bK  = (const float*)d_in[30];
    const float* wfc = (const float*)d_in[31];
    const float* bfc = (const float*)d_in[32];
    const float* wse = (const float*)d_in[33];
    const float* bse = (const float*)d_in[34];
    const float* w6  = (const float*)d_in[35];
    const float* b6  = (const float*)d_in[36];
    float* outp = (float*)d_out;
    char* ws = (char*)d_ws;

    // ---- workspace (byte offsets), liveness-checked overlays ----
    auto H = [&](long off) { return (f16*)(ws + off); };
    auto F = [&](long off) { return (float*)(ws + off); };
    const long O_wq4h = 0;
    const long O_wk4h = 262144;
    const long O_wv4h = 786432;
    const long O_wq3h = 4980736;
    const long O_wk3h = 5046272;
    const long O_wv3h = 5177344;
    const long O_w5r  = 6225920;
    const long O_weh  = 10944512;
    const long O_cwh  = 11468800;
    const long O_w6h  = 11501568;
    const long O_c3h  = 11665408;
    const long O_Xh   = 11665408;
    const long O_c4h  = 20054016;
    const long O_cku4h= 22151168;
    const long O_v3h  = 22151168;
    const long O_q4h  = 30539776;
    const long O_k4h  = 31064064;
    const long O_v4h  = 31588352;
    const long O_xch  = 30834688;
    const long O_Af   = 31358976;
    const long O_Etp  = 32407552;
    const long O_Ef   = 34504704;
    const long O_asum = 34635776;
    const long O_cc   = 34636032;
    const long O_en   = 34636160;
    const long O_gam  = 34640256;
    const long O_mv   = 34644352;
    const long O_out4h= 35856384;
    const long O_yh   = 35856384;
    const long O_c2h  = 40050688;
    const long O_cku3h= 48439296;
    const long O_feath= 48439296;
    const long O_out3h= 56827904;
    const long O_q3h  = 65216512;
    const long O_k3h  = 66265088;

    float* mv = F(O_mv);

    // ---- conversions ----
    chw2nhwc_k<<<dim3(128, 16, 2), 256, 0, stream>>>(c2, H(O_c2h), 512, 4096);
    chw2nhwc_k<<<dim3(32, 32, 2), 256, 0, stream>>>(c3, H(O_c3h), 1024, 1024);
    chw2nhwc_k<<<dim3(8, 64, 2), 256, 0, stream>>>(c4, H(O_c4h), 2048, 256);
    auto cvt = [&](const float* s, long o, long n) {
        f2h_k<<<(int)((n + 255) / 256), 256, 0, stream>>>(s, H(o), n);
    };
    cvt(wq4, O_wq4h, 128L * 1024); cvt(wk4, O_wk4h, 128L * 2048);
    cvt(wv4, O_wv4h, 1024L * 2048); cvt(wq3, O_wq3h, 64L * 512);
    cvt(wk3, O_wk3h, 64L * 1024); cvt(wv3, O_wv3h, 512L * 1024);
    cvt(we, O_weh, 512L * 512); cvt(cw, O_cwh, 32L * 512);
    cvt(w6, O_w6h, 150L * 512);
    w5r_k<<<9216, 256, 0, stream>>>(w5, H(O_w5r));
    zero_k<<<11, 256, 0, stream>>>(mv, 2816);

    // ---- Stage A: local_up(c3, c4) -> out4h (NHWC 2x1024x1024) ----
    hgemm_k<0><<<hgrid(128, 1024), 256, 0, stream>>>(H(O_wq4h), H(O_c3h), H(O_q4h), nullptr,
        128, 1024, 1024, 1024, 1024L * 1024, 1024L * 128, 0, 0, mv + 0);
    bnapply_k<<<128, 256, 0, stream>>>(H(O_q4h), mv + 0, gq4, bq4, 128, 2L * 1024 * 128, 1.f / 2048.f, 0);
    upsample_h8<<<2048, 256, 0, stream>>>(H(O_c4h), H(O_cku4h), 256, 16, 16, 32, 32);
    hgemm_k<0><<<hgrid(128, 1024), 256, 0, stream>>>(H(O_wk4h), H(O_cku4h), H(O_k4h), nullptr,
        128, 2048, 1024, 2048, 1024L * 2048, 1024L * 128, 0, 0, mv + 256);
    bnapply_k<<<128, 256, 0, stream>>>(H(O_k4h), mv + 256, gk4, bk4, 128, 2L * 1024 * 128, 1.f / 2048.f, 0);
    hgemm_k<0><<<hgrid(1024, 1024), 256, 0, stream>>>(H(O_wv4h), H(O_cku4h), H(O_v4h), nullptr,
        1024, 2048, 1024, 2048, 1024L * 2048, 1024L * 1024, 0, 0, nullptr);
    attpv_k<128, 1024, 32><<<dim3(256, 2), 256, 0, stream>>>(
        H(O_q4h), H(O_k4h), H(O_v4h), H(O_out4h));

    // ---- Stage B: local_up(c2, out4) -> out3h (NHWC 2x4096x512) ----
    hgemm_k<0><<<hgrid(64, 4096), 256, 0, stream>>>(H(O_wq3h), H(O_c2h), H(O_q3h), nullptr,
        64, 512, 4096, 512, 4096L * 512, 4096L * 64, 0, 0, mv + 512);
    bnapply_k<<<256, 256, 0, stream>>>(H(O_q3h), mv + 512, gq3, bq3, 64, 2L * 4096 * 64, 1.f / 8192.f, 0);
    upsample_h8<<<4096, 256, 0, stream>>>(H(O_out4h), H(O_cku3h), 128, 32, 32, 64, 64);
    hgemm_k<0><<<hgrid(64, 4096), 256, 0, stream>>>(H(O_wk3h), H(O_cku3h), H(O_k3h), nullptr,
        64, 1024, 4096, 1024, 4096L * 1024, 4096L * 64, 0, 0, mv + 640);
    bnapply_k<<<256, 256, 0, stream>>>(H(O_k3h), mv + 640, gk3, bk3, 64, 2L * 4096 * 64, 1.f / 8192.f, 0);
    hgemm_k<0><<<hgrid(512, 4096), 256, 0, stream>>>(H(O_wv3h), H(O_cku3h), H(O_v3h), nullptr,
        512, 1024, 4096, 1024, 4096L * 1024, 4096L * 512, 0, 0, nullptr);
    attpv_k<64, 512, 64><<<dim3(1024, 2), 256, 0, stream>>>(
        H(O_q3h), H(O_k3h), H(O_v3h), H(O_out3h));

    // ---- Stage C: feat = relu(BN(conv3x3(out3))) ----
    hgemm_k<1><<<hgrid(512, 4096), 256, 0, stream>>>(H(O_w5r), H(O_out3h), H(O_feath), nullptr,
        512, 4608, 4096, 512, 4096L * 512, 4096L * 512, 64, 64, mv + 768);
    bnapply_k<<<2048, 256, 0, stream>>>(H(O_feath), mv + 768, g5, b5, 512, 2L * 4096 * 512, 1.f / 8192.f, 1);

    // ---- Stage D: enc_module ----
    hgemm_k<0><<<hgrid(512, 4096), 256, 0, stream>>>(H(O_weh), H(O_feath), H(O_Xh), nullptr,
        512, 512, 4096, 512, 4096L * 512, 4096L * 512, 0, 0, mv + 1792);
    bnapply_k<<<2048, 256, 0, stream>>>(H(O_Xh), mv + 1792, ge, be, 512, 2L * 4096 * 512, 1.f / 8192.f, 1);
    hgemm_k<0><<<hgrid(32, 4096), 256, 0, stream>>>(H(O_cwh), H(O_Xh), H(O_xch), nullptr,
        32, 512, 4096, 512, 4096L * 512, 4096L * 32, 0, 0, nullptr);
    cc_k<<<32, 64, 0, stream>>>(cw, F(O_cc), 512);
    assign_h<<<dim3(16, 2), 256, 0, stream>>>(H(O_Xh), H(O_xch), F(O_cc), scl, F(O_Af));
    asum_k<<<dim3(32, 2), 256, 0, stream>>>(F(O_Af), F(O_asum), 4096);
    etg_k<<<dim3(8, 1, 32), 256, 0, stream>>>(F(O_Af), H(O_Xh), F(O_Etp));
    efix2_k<<<128, 256, 0, stream>>>(F(O_Etp), F(O_asum), cw, F(O_Ef));
    bn_stats_k<<<32, 256, 0, stream>>>(F(O_Ef), mv + 2816, 512, 2, 32L * 512);
    en_k<<<4, 256, 0, stream>>>(F(O_Ef), mv + 2816, gK, bK, F(O_en), 512);
    fc_k<<<dim3(2, 2), 256, 0, stream>>>(wfc, bfc, F(O_en), F(O_gam), 512, 512, 1);
    fc_k<<<dim3(1, 2), 256, 0, stream>>>(wse, bse, F(O_en), outp + 1228800, 150, 512, 0);
    ymul_h<<<2048, 256, 0, stream>>>(H(O_feath), F(O_gam), H(O_yh));

    // ---- Stage E: seg = w6 @ y + b6 -> d_out (CHW f32) ----
    hgemm_k<2><<<hgrid(150, 4096), 256, 0, stream>>>(H(O_w6h), H(O_yh), outp, b6,
        150, 512, 4096, 512, 4096L * 512, 150L * 4096, 0, 0, nullptr);
}